// Round 1
// baseline (13285.350 us; speedup 1.0000x reference)
//
#include <hip/hip_runtime.h>
#include <hip/hip_bf16.h>
#include <math.h>

#define B_ 32
#define S_ 512
#define D_ 512
#define H_ 8
#define DK_ 64
#define DFF_ 2048
#define L_ 4

// ---------- block reduce helpers (256 threads = 4 waves of 64) ----------
__device__ __forceinline__ float blockReduceSum256(float v, float* red) {
  #pragma unroll
  for (int off = 32; off > 0; off >>= 1) v += __shfl_down(v, off, 64);
  int lane = threadIdx.x & 63, wid = threadIdx.x >> 6;
  __syncthreads();
  if (lane == 0) red[wid] = v;
  __syncthreads();
  return red[0] + red[1] + red[2] + red[3];
}

__device__ __forceinline__ float blockReduceMax256(float v, float* red) {
  #pragma unroll
  for (int off = 32; off > 0; off >>= 1) v = fmaxf(v, __shfl_down(v, off, 64));
  int lane = threadIdx.x & 63, wid = threadIdx.x >> 6;
  __syncthreads();
  if (lane == 0) red[wid] = v;
  __syncthreads();
  return fmaxf(fmaxf(red[0], red[1]), fmaxf(red[2], red[3]));
}

// ---------- GEMM: C[M,N] = A[M,K] @ W[N,K]^T + bias[N], optional relu ----------
// M,N multiples of 64; K multiple of 16.
__global__ __launch_bounds__(256) void gemm_nt_f32(
    const float* __restrict__ A, const float* __restrict__ W,
    const float* __restrict__ bias, float* __restrict__ C,
    int M, int N, int K, int relu)
{
  __shared__ float As[16][65];  // +1 pad: avoids 16-way bank conflict on store
  __shared__ float Ws[16][65];
  int tid = threadIdx.x;
  int bm = blockIdx.y * 64, bn = blockIdx.x * 64;
  int tx = tid & 15, ty = tid >> 4;
  float c[4][4];
  #pragma unroll
  for (int i = 0; i < 4; ++i)
    #pragma unroll
    for (int j = 0; j < 4; ++j) c[i][j] = 0.f;

  for (int k0 = 0; k0 < K; k0 += 16) {
    #pragma unroll
    for (int r = 0; r < 4; ++r) {
      int m = ty + r * 16;  // 0..63
      As[tx][m] = A[(size_t)(bm + m) * K + k0 + tx];
      Ws[tx][m] = W[(size_t)(bn + m) * K + k0 + tx];
    }
    __syncthreads();
    #pragma unroll
    for (int k = 0; k < 16; ++k) {
      float a[4], w[4];
      #pragma unroll
      for (int i = 0; i < 4; ++i) a[i] = As[k][ty * 4 + i];
      #pragma unroll
      for (int j = 0; j < 4; ++j) w[j] = Ws[k][tx * 4 + j];
      #pragma unroll
      for (int i = 0; i < 4; ++i)
        #pragma unroll
        for (int j = 0; j < 4; ++j) c[i][j] = fmaf(a[i], w[j], c[i][j]);
    }
    __syncthreads();
  }
  #pragma unroll
  for (int i = 0; i < 4; ++i) {
    int row = bm + ty * 4 + i;
    #pragma unroll
    for (int j = 0; j < 4; ++j) {
      int col = bn + tx * 4 + j;
      float val = c[i][j] + bias[col];
      if (relu) val = fmaxf(val, 0.f);
      C[(size_t)row * N + col] = val;
    }
  }
}

// ---------- fused attention: one block per (b,h,i) row ----------
// q==k (shared projection). maskType 0: valid j<i (strict past); 1: valid j<=i.
// zeroPad: row i==0 output forced to zero (only used with maskType 0).
__global__ __launch_bounds__(256) void attn_fused(
    const float* __restrict__ qk, const float* __restrict__ v,
    const float* __restrict__ gammas, float* __restrict__ out,
    int maskType, int zeroPad)
{
  int bid = blockIdx.x;
  int i = bid % S_;
  int h = (bid / S_) % H_;
  int b = bid / (S_ * H_);
  int tid = threadIdx.x;
  float* orow = out + ((size_t)(b * S_ + i)) * D_ + h * DK_;
  int nv = (maskType == 0) ? i : (i + 1);
  if (zeroPad && i == 0) { if (tid < DK_) orow[tid] = 0.f; return; }
  // here nv >= 1

  __shared__ float qs[DK_];
  __shared__ float sc[S_];
  __shared__ float at[S_];
  __shared__ float scan[256];
  __shared__ float red[4];
  __shared__ float pv[4][DK_];

  const float* qrow = qk + ((size_t)(b * S_ + i)) * D_ + h * DK_;
  if (tid < DK_) qs[tid] = qrow[tid];
  __syncthreads();

  // scores (only lower triangle needed), scaled by 1/sqrt(64)
  for (int j = tid; j < nv; j += 256) {
    const float4* kp = (const float4*)(qk + ((size_t)(b * S_ + j)) * D_ + h * DK_);
    float sx = 0.f, sy = 0.f, sz = 0.f, sw = 0.f;
    #pragma unroll
    for (int dd = 0; dd < 16; ++dd) {
      float4 kv = kp[dd];
      float4 qv = ((const float4*)qs)[dd];
      sx += kv.x * qv.x; sy += kv.y * qv.y; sz += kv.z * qv.z; sw += kv.w * qv.w;
    }
    sc[j] = (sx + sy + sz + sw) * 0.125f;
  }
  for (int j = nv + tid; j < S_; j += 256) sc[j] = 0.f;
  __syncthreads();

  // softmax #1 over valid -> sm stored in at[] (zero beyond nv)
  float lmax = -1e30f;
  for (int j = tid; j < nv; j += 256) lmax = fmaxf(lmax, sc[j]);
  lmax = blockReduceMax256(lmax, red);
  float lsum = 0.f;
  for (int j = tid; j < nv; j += 256) { float e = __expf(sc[j] - lmax); at[j] = e; lsum += e; }
  lsum = blockReduceSum256(lsum, red);
  float inv = 1.f / lsum;
  for (int j = tid; j < S_; j += 256) at[j] = (j < nv) ? at[j] * inv : 0.f;
  __syncthreads();

  // inclusive cumsum of at[0..511]: 2 elements per thread + Hillis-Steele over 256
  int j0 = 2 * tid, j1 = 2 * tid + 1;
  float e0 = at[j0], e1 = at[j1];
  float sown = e0 + e1;
  scan[tid] = sown;
  __syncthreads();
  float acc = sown;
  for (int off = 1; off < 256; off <<= 1) {
    float prev = (tid >= off) ? scan[tid - off] : 0.f;
    __syncthreads();
    acc += prev;
    scan[tid] = acc;
    __syncthreads();
  }
  float total = scan[255];
  float excl = acc - sown;
  float dc0 = excl + e0;
  float dc1 = excl + e0 + e1;
  float gam = gammas[h];
  float gneg = -((gam > 20.f) ? gam : log1pf(__expf(gam)));  // -softplus
  float p0 = fabsf((float)(j0 - i));
  float p1 = fabsf((float)(j1 - i));
  float dd0 = sqrtf(fmaxf((total - dc0) * p0, 0.f));
  float dd1 = sqrtf(fmaxf((total - dc1) * p1, 0.f));
  float te0 = fminf(fmaxf(__expf(dd0 * gneg), 1e-5f), 1e5f);
  float te1 = fminf(fmaxf(__expf(dd1 * gneg), 1e-5f), 1e5f);
  float s2_0 = sc[j0] * te0;
  float s2_1 = sc[j1] * te1;
  __syncthreads();          // all sc reads done before overwrite
  sc[j0] = s2_0;
  sc[j1] = s2_1;
  __syncthreads();

  // softmax #2 over valid -> attn in at[]
  lmax = -1e30f;
  for (int j = tid; j < nv; j += 256) lmax = fmaxf(lmax, sc[j]);
  lmax = blockReduceMax256(lmax, red);
  lsum = 0.f;
  for (int j = tid; j < nv; j += 256) { float e = __expf(sc[j] - lmax); at[j] = e; lsum += e; }
  lsum = blockReduceSum256(lsum, red);
  inv = 1.f / lsum;
  for (int j = tid; j < nv; j += 256) at[j] *= inv;
  __syncthreads();

  // PV: out[d] = sum_j attn[j] * v[b,j,h*64+d]
  int d = tid & 63, part = tid >> 6;
  float accv = 0.f;
  for (int j = part; j < nv; j += 4)
    accv += at[j] * v[((size_t)(b * S_ + j)) * D_ + h * DK_ + d];
  pv[part][d] = accv;
  __syncthreads();
  if (tid < DK_) orow[tid] = pv[0][tid] + pv[1][tid] + pv[2][tid] + pv[3][tid];
}

// ---------- fused residual + layernorm (in-place on x): x = LN(x + r)*g + b ----------
__global__ __launch_bounds__(256) void add_ln(
    float* __restrict__ x, const float* __restrict__ r,
    const float* __restrict__ g, const float* __restrict__ b)
{
  int row = blockIdx.x;
  int t = threadIdx.x;
  float* xr = x + (size_t)row * D_;
  const float* rr = r + (size_t)row * D_;
  float v0 = xr[t] + rr[t];
  float v1 = xr[t + 256] + rr[t + 256];
  __shared__ float red[4];
  float s = blockReduceSum256(v0 + v1, red);
  float mu = s * (1.0f / 512.0f);
  float d0 = v0 - mu, d1 = v1 - mu;
  float sq = blockReduceSum256(d0 * d0 + d1 * d1, red);
  float rstd = rsqrtf(sq * (1.0f / 512.0f) + 1e-5f);
  xr[t] = d0 * rstd * g[t] + b[t];
  xr[t + 256] = d1 * rstd * g[t + 256] + b[t + 256];
}

extern "C" void kernel_launch(void* const* d_in, const int* in_sizes, int n_in,
                              void* d_out, int out_size, void* d_ws, size_t ws_size,
                              hipStream_t stream) {
  const float* q_embed  = (const float*)d_in[0];
  const float* qa_embed = (const float*)d_in[1];
  const float* Wk = (const float*)d_in[2];
  const float* bk = (const float*)d_in[3];
  const float* Wv = (const float*)d_in[4];
  const float* bv = (const float*)d_in[5];
  const float* Wo = (const float*)d_in[6];
  const float* bo = (const float*)d_in[7];
  const float* gammas = (const float*)d_in[8];
  const float* ln1_g = (const float*)d_in[9];
  const float* ln1_b = (const float*)d_in[10];
  const float* W1 = (const float*)d_in[11];
  const float* b1 = (const float*)d_in[12];
  const float* W2 = (const float*)d_in[13];
  const float* b2 = (const float*)d_in[14];
  const float* ln2_g = (const float*)d_in[15];
  const float* ln2_b = (const float*)d_in[16];

  float* x = (float*)d_out;                 // x lives in d_out
  float* ws = (float*)d_ws;
  const size_t NTOK = (size_t)B_ * S_;      // 16384
  float* qkbuf = ws;                        // NTOK*D  (also reused as q2/ffn-out)
  float* vbuf  = qkbuf + NTOK * D_;         // NTOK*D
  float* ao    = vbuf + NTOK * D_;          // NTOK*D
  float* ffn   = ao + NTOK * D_;            // NTOK*DFF
  // total ws use: (3*D + DFF)*NTOK*4B = 235 MB

  hipMemcpyAsync(x, q_embed, NTOK * D_ * sizeof(float),
                 hipMemcpyDeviceToDevice, stream);

  dim3 gproj(D_ / 64, NTOK / 64);   // (8, 256)
  dim3 gf1(DFF_ / 64, NTOK / 64);   // (32, 256)
  dim3 gf2(D_ / 64, NTOK / 64);

  for (int l = 0; l < L_; ++l) {
    int first = (l % 2 == 0);
    const float* vals = first ? qa_embed : x;
    // q/k projection (shared weights -> q==k) and v projection
    gemm_nt_f32<<<gproj, 256, 0, stream>>>(x, Wk + (size_t)l * D_ * D_, bk + l * D_,
                                           qkbuf, (int)NTOK, D_, D_, 0);
    gemm_nt_f32<<<gproj, 256, 0, stream>>>(vals, Wv + (size_t)l * D_ * D_, bv + l * D_,
                                           vbuf, (int)NTOK, D_, D_, 0);
    attn_fused<<<B_ * H_ * S_, 256, 0, stream>>>(qkbuf, vbuf, gammas + l * H_, ao,
                                                 first ? 0 : 1, first ? 1 : 0);
    // output projection (qkbuf reused as q2)
    gemm_nt_f32<<<gproj, 256, 0, stream>>>(ao, Wo + (size_t)l * D_ * D_, bo + l * D_,
                                           qkbuf, (int)NTOK, D_, D_, 0);
    add_ln<<<(int)NTOK, 256, 0, stream>>>(x, qkbuf, ln1_g + l * D_, ln1_b + l * D_);
    if (first) {
      gemm_nt_f32<<<gf1, 256, 0, stream>>>(x, W1 + (size_t)l * DFF_ * D_, b1 + l * DFF_,
                                           ffn, (int)NTOK, DFF_, D_, 1);
      gemm_nt_f32<<<gf2, 256, 0, stream>>>(ffn, W2 + (size_t)l * D_ * DFF_, b2 + l * D_,
                                           qkbuf, (int)NTOK, D_, DFF_, 0);
      add_ln<<<(int)NTOK, 256, 0, stream>>>(x, qkbuf, ln2_g + l * D_, ln2_b + l * D_);
    }
  }
}

// Round 2
// 8045.499 us; speedup vs baseline: 1.6513x; 1.6513x over previous
//
#include <hip/hip_runtime.h>
#include <hip/hip_bf16.h>
#include <math.h>

#define B_ 32
#define S_ 512
#define D_ 512
#define H_ 8
#define DK_ 64
#define DFF_ 2048
#define L_ 4

// ---------- wave-level reduce helpers (width 64) ----------
__device__ __forceinline__ float waveSum64(float v) {
  #pragma unroll
  for (int off = 1; off < 64; off <<= 1) v += __shfl_xor(v, off, 64);
  return v;
}
__device__ __forceinline__ float waveMax64(float v) {
  #pragma unroll
  for (int off = 1; off < 64; off <<= 1) v = fmaxf(v, __shfl_xor(v, off, 64));
  return v;
}
__device__ __forceinline__ float blockReduceSum256(float v, float* red) {
  #pragma unroll
  for (int off = 32; off > 0; off >>= 1) v += __shfl_down(v, off, 64);
  int lane = threadIdx.x & 63, wid = threadIdx.x >> 6;
  __syncthreads();
  if (lane == 0) red[wid] = v;
  __syncthreads();
  return red[0] + red[1] + red[2] + red[3];
}

// ---------- GEMM: C[M,N] = A[M,K] @ W[N,K]^T + bias[N], optional relu ----------
__global__ __launch_bounds__(256) void gemm_nt_f32(
    const float* __restrict__ A, const float* __restrict__ W,
    const float* __restrict__ bias, float* __restrict__ C,
    int M, int N, int K, int relu)
{
  __shared__ float As[16][65];
  __shared__ float Ws[16][65];
  int tid = threadIdx.x;
  int bm = blockIdx.y * 64, bn = blockIdx.x * 64;
  int tx = tid & 15, ty = tid >> 4;
  float c[4][4];
  #pragma unroll
  for (int i = 0; i < 4; ++i)
    #pragma unroll
    for (int j = 0; j < 4; ++j) c[i][j] = 0.f;

  for (int k0 = 0; k0 < K; k0 += 16) {
    #pragma unroll
    for (int r = 0; r < 4; ++r) {
      int m = ty + r * 16;
      As[tx][m] = A[(size_t)(bm + m) * K + k0 + tx];
      Ws[tx][m] = W[(size_t)(bn + m) * K + k0 + tx];
    }
    __syncthreads();
    #pragma unroll
    for (int k = 0; k < 16; ++k) {
      float a[4], w[4];
      #pragma unroll
      for (int i = 0; i < 4; ++i) a[i] = As[k][ty * 4 + i];
      #pragma unroll
      for (int j = 0; j < 4; ++j) w[j] = Ws[k][tx * 4 + j];
      #pragma unroll
      for (int i = 0; i < 4; ++i)
        #pragma unroll
        for (int j = 0; j < 4; ++j) c[i][j] = fmaf(a[i], w[j], c[i][j]);
    }
    __syncthreads();
  }
  #pragma unroll
  for (int i = 0; i < 4; ++i) {
    int row = bm + ty * 4 + i;
    #pragma unroll
    for (int j = 0; j < 4; ++j) {
      int col = bn + tx * 4 + j;
      float val = c[i][j] + bias[col];
      if (relu) val = fmaxf(val, 0.f);
      C[(size_t)row * N + col] = val;
    }
  }
}

// ---------- per-head transpose: qk[b][j][h*64+d] -> kT[b][h][d][j] ----------
__global__ __launch_bounds__(256) void transpose_heads(
    const float* __restrict__ qk, float* __restrict__ kT)
{
  __shared__ float t[64][65];
  int jt = blockIdx.x, h = blockIdx.y, b = blockIdx.z;
  int lane = threadIdx.x & 63, w = threadIdx.x >> 6;
  #pragma unroll
  for (int r = 0; r < 16; ++r) {
    int j = w + r * 4;
    t[j][lane] = qk[((size_t)(b * S_ + jt * 64 + j)) * D_ + h * DK_ + lane];
  }
  __syncthreads();
  #pragma unroll
  for (int r = 0; r < 16; ++r) {
    int d = w + r * 4;
    kT[((size_t)((b * H_ + h) * DK_ + d)) * S_ + jt * 64 + lane] = t[lane][d];
  }
}

// ---------- attention: one WAVE per (b,h,i) row; 4 rows/block, no block syncs ----------
// maskType 0: valid j<i (strict past); 1: valid j<=i. zeroPad: row i==0 -> 0.
__global__ __launch_bounds__(256) void attn_wave(
    const float* __restrict__ qk,   // q rows: [b][i][h*64+d]
    const float* __restrict__ kT,   // [b][h][d][j]
    const float* __restrict__ v,    // [b][j][h*64+d]
    const float* __restrict__ gammas,
    float* __restrict__ out,        // [b][i][h*64+d]
    int maskType, int zeroPad)
{
  __shared__ float at_sh[4][S_];    // per-wave attn row
  int tid = threadIdx.x;
  int lane = tid & 63, w = tid >> 6;
  int grp = blockIdx.x;                    // ((b*H + h)*(S/4) + igrp)
  int igrp = grp & (S_ / 4 - 1);
  int h = (grp / (S_ / 4)) & (H_ - 1);
  int b = grp / ((S_ / 4) * H_);
  int i = igrp * 4 + w;
  int nv = (maskType == 0) ? i : (i + 1);
  float* orow = out + ((size_t)(b * S_ + i)) * D_ + h * DK_;
  if (zeroPad && i == 0) { orow[lane] = 0.f; return; }
  // nv >= 1 from here

  // ---- scores: lane owns j in [lane*8, lane*8+8) ----
  float qv = qk[((size_t)(b * S_ + i)) * D_ + h * DK_ + lane];
  const float* kTd = kT + ((size_t)((b * H_ + h) * DK_)) * S_ + lane * 8;
  int j0 = lane * 8;
  bool act = j0 < nv;
  float s[8] = {0.f, 0.f, 0.f, 0.f, 0.f, 0.f, 0.f, 0.f};
  #pragma unroll 4
  for (int d = 0; d < DK_; ++d) {
    float qd = __shfl(qv, d, 64);
    if (act) {
      const float4* kp = (const float4*)kTd;
      float4 k0 = kp[0], k1 = kp[1];
      s[0] = fmaf(qd, k0.x, s[0]); s[1] = fmaf(qd, k0.y, s[1]);
      s[2] = fmaf(qd, k0.z, s[2]); s[3] = fmaf(qd, k0.w, s[3]);
      s[4] = fmaf(qd, k1.x, s[4]); s[5] = fmaf(qd, k1.y, s[5]);
      s[6] = fmaf(qd, k1.z, s[6]); s[7] = fmaf(qd, k1.w, s[7]);
    }
    kTd += S_;
  }
  #pragma unroll
  for (int t = 0; t < 8; ++t) s[t] *= 0.125f;   // 1/sqrt(64)

  // ---- softmax #1 (valid only) ----
  float m1 = -1e30f;
  #pragma unroll
  for (int t = 0; t < 8; ++t) if (j0 + t < nv) m1 = fmaxf(m1, s[t]);
  m1 = waveMax64(m1);
  float e[8], sum = 0.f;
  #pragma unroll
  for (int t = 0; t < 8; ++t) {
    e[t] = (j0 + t < nv) ? __expf(s[t] - m1) : 0.f;
    sum += e[t];
  }
  sum = waveSum64(sum);
  float inv = 1.f / sum;    // sm[t] = e[t]*inv (deferred)

  // ---- inclusive cumsum of sm over the row ----
  float c[8], p = 0.f;
  #pragma unroll
  for (int t = 0; t < 8; ++t) { p += e[t]; c[t] = p; }
  float tot = p, scn = p;
  #pragma unroll
  for (int off = 1; off < 64; off <<= 1) {
    float n = __shfl_up(scn, off, 64);
    if (lane >= off) scn += n;
  }
  float excl = scn - tot;
  float grand = __shfl(scn, 63, 64);

  // ---- distance decay + rescored ----
  float gam = gammas[h];
  float gneg = -((gam > 20.f) ? gam : log1pf(__expf(gam)));  // -softplus
  float s2[8];
  #pragma unroll
  for (int t = 0; t < 8; ++t) {
    float pos = fabsf((float)(j0 + t - i));
    float dd = sqrtf(fmaxf((grand - excl - c[t]) * inv * pos, 0.f));
    float te = fminf(fmaxf(__expf(dd * gneg), 1e-5f), 1e5f);
    s2[t] = s[t] * te;
  }

  // ---- softmax #2 (valid only) ----
  float m2 = -1e30f;
  #pragma unroll
  for (int t = 0; t < 8; ++t) if (j0 + t < nv) m2 = fmaxf(m2, s2[t]);
  m2 = waveMax64(m2);
  float a[8], sum2 = 0.f;
  #pragma unroll
  for (int t = 0; t < 8; ++t) {
    a[t] = (j0 + t < nv) ? __expf(s2[t] - m2) : 0.f;
    sum2 += a[t];
  }
  sum2 = waveSum64(sum2);
  float inv2 = 1.f / sum2;
  #pragma unroll
  for (int t = 0; t < 8; ++t) a[t] *= inv2;

  // ---- redistribute attn via LDS (same wave produces & consumes) ----
  float4* dst = (float4*)&at_sh[w][j0];
  dst[0] = make_float4(a[0], a[1], a[2], a[3]);
  dst[1] = make_float4(a[4], a[5], a[6], a[7]);

  // ---- PV: lane owns output dim d=lane ----
  float acc = 0.f;
  const float* vr = v + ((size_t)(b * S_)) * D_ + h * DK_ + lane;
  int j = 0;
  for (; j + 4 <= nv; j += 4) {
    float4 av = *(const float4*)&at_sh[w][j];
    acc = fmaf(av.x, vr[0], acc);
    acc = fmaf(av.y, vr[D_], acc);
    acc = fmaf(av.z, vr[2 * D_], acc);
    acc = fmaf(av.w, vr[3 * D_], acc);
    vr += 4 * D_;
  }
  for (; j < nv; ++j) { acc = fmaf(at_sh[w][j], vr[0], acc); vr += D_; }
  orow[lane] = acc;
}

// ---------- fused residual + layernorm (in-place on x) ----------
__global__ __launch_bounds__(256) void add_ln(
    float* __restrict__ x, const float* __restrict__ r,
    const float* __restrict__ g, const float* __restrict__ b)
{
  int row = blockIdx.x;
  int t = threadIdx.x;
  float* xr = x + (size_t)row * D_;
  const float* rr = r + (size_t)row * D_;
  float v0 = xr[t] + rr[t];
  float v1 = xr[t + 256] + rr[t + 256];
  __shared__ float red[4];
  float s = blockReduceSum256(v0 + v1, red);
  float mu = s * (1.0f / 512.0f);
  float d0 = v0 - mu, d1 = v1 - mu;
  float sq = blockReduceSum256(d0 * d0 + d1 * d1, red);
  float rstd = rsqrtf(sq * (1.0f / 512.0f) + 1e-5f);
  xr[t] = d0 * rstd * g[t] + b[t];
  xr[t + 256] = d1 * rstd * g[t + 256] + b[t + 256];
}

extern "C" void kernel_launch(void* const* d_in, const int* in_sizes, int n_in,
                              void* d_out, int out_size, void* d_ws, size_t ws_size,
                              hipStream_t stream) {
  const float* q_embed  = (const float*)d_in[0];
  const float* qa_embed = (const float*)d_in[1];
  const float* Wk = (const float*)d_in[2];
  const float* bk = (const float*)d_in[3];
  const float* Wv = (const float*)d_in[4];
  const float* bv = (const float*)d_in[5];
  const float* Wo = (const float*)d_in[6];
  const float* bo = (const float*)d_in[7];
  const float* gammas = (const float*)d_in[8];
  const float* ln1_g = (const float*)d_in[9];
  const float* ln1_b = (const float*)d_in[10];
  const float* W1 = (const float*)d_in[11];
  const float* b1 = (const float*)d_in[12];
  const float* W2 = (const float*)d_in[13];
  const float* b2 = (const float*)d_in[14];
  const float* ln2_g = (const float*)d_in[15];
  const float* ln2_b = (const float*)d_in[16];

  float* x = (float*)d_out;
  float* ws = (float*)d_ws;
  const size_t NTOK = (size_t)B_ * S_;      // 16384
  float* qkbuf = ws;                        // NTOK*D  (also reused as q2/ffn-out)
  float* vbuf  = qkbuf + NTOK * D_;         // NTOK*D
  float* ao    = vbuf + NTOK * D_;          // NTOK*D
  float* ffn   = ao + NTOK * D_;            // NTOK*DFF (attn phase: holds kT)
  float* kT    = ffn;                       // B*H*DK*S = NTOK*D floats (33.5MB)

  hipMemcpyAsync(x, q_embed, NTOK * D_ * sizeof(float),
                 hipMemcpyDeviceToDevice, stream);

  dim3 gproj(D_ / 64, NTOK / 64);
  dim3 gf1(DFF_ / 64, NTOK / 64);
  dim3 gf2(D_ / 64, NTOK / 64);
  dim3 gtr(S_ / 64, H_, B_);
  int gattn = B_ * H_ * (S_ / 4);

  for (int l = 0; l < L_; ++l) {
    int first = (l % 2 == 0);
    const float* vals = first ? qa_embed : x;
    gemm_nt_f32<<<gproj, 256, 0, stream>>>(x, Wk + (size_t)l * D_ * D_, bk + l * D_,
                                           qkbuf, (int)NTOK, D_, D_, 0);
    gemm_nt_f32<<<gproj, 256, 0, stream>>>(vals, Wv + (size_t)l * D_ * D_, bv + l * D_,
                                           vbuf, (int)NTOK, D_, D_, 0);
    transpose_heads<<<gtr, 256, 0, stream>>>(qkbuf, kT);
    attn_wave<<<gattn, 256, 0, stream>>>(qkbuf, kT, vbuf, gammas + l * H_, ao,
                                         first ? 0 : 1, first ? 1 : 0);
    gemm_nt_f32<<<gproj, 256, 0, stream>>>(ao, Wo + (size_t)l * D_ * D_, bo + l * D_,
                                           qkbuf, (int)NTOK, D_, D_, 0);
    add_ln<<<(int)NTOK, 256, 0, stream>>>(x, qkbuf, ln1_g + l * D_, ln1_b + l * D_);
    if (first) {
      gemm_nt_f32<<<gf1, 256, 0, stream>>>(x, W1 + (size_t)l * DFF_ * D_, b1 + l * DFF_,
                                           ffn, (int)NTOK, DFF_, D_, 1);
      gemm_nt_f32<<<gf2, 256, 0, stream>>>(ffn, W2 + (size_t)l * D_ * DFF_, b2 + l * D_,
                                           qkbuf, (int)NTOK, D_, DFF_, 0);
      add_ln<<<(int)NTOK, 256, 0, stream>>>(x, qkbuf, ln2_g + l * D_, ln2_b + l * D_);
    }
  }
}

// Round 3
// 4084.030 us; speedup vs baseline: 3.2530x; 1.9700x over previous
//
#include <hip/hip_runtime.h>
#include <hip/hip_bf16.h>
#include <math.h>

#define B_ 32
#define S_ 512
#define D_ 512
#define H_ 8
#define DK_ 64
#define DFF_ 2048
#define L_ 4

typedef __attribute__((ext_vector_type(8))) short bf16x8;
typedef __attribute__((ext_vector_type(4))) float f32x4;

__device__ __forceinline__ unsigned short f2bf(float x) {
  union { float f; unsigned u; } v; v.f = x;
  unsigned r = v.u + 0x7fff + ((v.u >> 16) & 1);   // round-nearest-even
  return (unsigned short)(r >> 16);
}

__device__ __forceinline__ void load_lds16(const void* g, void* l) {
  __builtin_amdgcn_global_load_lds(
      (const __attribute__((address_space(1))) void*)g,
      (__attribute__((address_space(3))) void*)l, 16, 0, 0);
}

// ---------- f32 -> bf16 convert (8 elems/thread/iter) ----------
__global__ __launch_bounds__(256) void cvt_f32_bf16(
    const float* __restrict__ in, unsigned short* __restrict__ out, size_t n8)
{
  size_t idx = (size_t)blockIdx.x * 256 + threadIdx.x;
  size_t stride = (size_t)gridDim.x * 256;
  for (size_t i = idx; i < n8; i += stride) {
    const float4* p = (const float4*)(in + i * 8);
    float4 a = p[0], b = p[1];
    union { unsigned short u[8]; int4 v; } o;
    o.u[0] = f2bf(a.x); o.u[1] = f2bf(a.y); o.u[2] = f2bf(a.z); o.u[3] = f2bf(a.w);
    o.u[4] = f2bf(b.x); o.u[5] = f2bf(b.y); o.u[6] = f2bf(b.z); o.u[7] = f2bf(b.w);
    *(int4*)(out + i * 8) = o.v;
  }
}

// ---------- bf16 MFMA GEMM: C[M,N] = A[M,K] @ W[N,K]^T + bias ----------
// m97 structure: 128x128 tile, BK=32, 4 waves (2x2 of 64x64), global_load_lds.
// Cf!=null -> f32 out; else Cb bf16 out. Optional relu.
__global__ __launch_bounds__(256) void gemm_bt_bf16(
    const unsigned short* __restrict__ A,   // [M][K] bf16
    const unsigned short* __restrict__ W,   // [N][K] bf16
    const float* __restrict__ bias,         // [N]
    float* __restrict__ Cf, unsigned short* __restrict__ Cb,
    int M, int N, int K, int relu)
{
  __shared__ __align__(16) short As[128 * 32];
  __shared__ __align__(16) short Ws[128 * 32];
  int tid = threadIdx.x;
  int lane = tid & 63, w = tid >> 6;
  int wr = w >> 1, wc = w & 1;
  int bm = blockIdx.y * 128, bn = blockIdx.x * 128;

  f32x4 acc[4][4];
  #pragma unroll
  for (int m = 0; m < 4; ++m)
    #pragma unroll
    for (int n = 0; n < 4; ++n) acc[m][n] = (f32x4){0.f, 0.f, 0.f, 0.f};

  // staging source: thread covers row=tid/4 (then +64), 16B at k-slot tid%4
  int srow = tid >> 2;
  int skB  = (tid & 3) * 16;                 // byte offset within 64B row chunk
  const char* pa0 = (const char*)(A + (size_t)(bm + srow) * K) + skB;
  const char* pa1 = (const char*)(A + (size_t)(bm + 64 + srow) * K) + skB;
  const char* pw0 = (const char*)(W + (size_t)(bn + srow) * K) + skB;
  const char* pw1 = (const char*)(W + (size_t)(bn + 64 + srow) * K) + skB;
  char* lA0 = (char*)As + w * 1024;
  char* lA1 = (char*)As + 4096 + w * 1024;
  char* lW0 = (char*)Ws + w * 1024;
  char* lW1 = (char*)Ws + 4096 + w * 1024;

  int r = lane & 15, k8 = lane >> 4;
  const bf16x8* Arow = (const bf16x8*)As;    // 4 bf16x8 per 32-elem row
  const bf16x8* Wrow = (const bf16x8*)Ws;

  for (int k0 = 0; k0 < K; k0 += 32) {
    load_lds16(pa0, lA0);
    load_lds16(pa1, lA1);
    load_lds16(pw0, lW0);
    load_lds16(pw1, lW1);
    pa0 += 64; pa1 += 64; pw0 += 64; pw1 += 64;
    __syncthreads();
    bf16x8 aF[4], bF[4];
    #pragma unroll
    for (int m = 0; m < 4; ++m) aF[m] = Arow[(wr * 64 + m * 16 + r) * 4 + k8];
    #pragma unroll
    for (int n = 0; n < 4; ++n) bF[n] = Wrow[(wc * 64 + n * 16 + r) * 4 + k8];
    #pragma unroll
    for (int m = 0; m < 4; ++m)
      #pragma unroll
      for (int n = 0; n < 4; ++n)
        acc[m][n] = __builtin_amdgcn_mfma_f32_16x16x32_bf16(aF[m], bF[n], acc[m][n], 0, 0, 0);
    __syncthreads();
  }

  // epilogue: C/D layout col=lane&15, row=(lane>>4)*4+j  [m89-verified]
  int orow0 = bm + wr * 64 + (lane >> 4) * 4;
  int ocol0 = bn + wc * 64 + (lane & 15);
  #pragma unroll
  for (int n = 0; n < 4; ++n) {
    int col = ocol0 + n * 16;
    float bv = bias[col];
    #pragma unroll
    for (int m = 0; m < 4; ++m) {
      int row = orow0 + m * 16;
      #pragma unroll
      for (int j = 0; j < 4; ++j) {
        float val = acc[m][n][j] + bv;
        if (relu) val = fmaxf(val, 0.f);
        size_t off = (size_t)(row + j) * N + col;
        if (Cf) Cf[off] = val; else Cb[off] = f2bf(val);
      }
    }
  }
}

// ---------- wave-level reduce helpers ----------
__device__ __forceinline__ float waveSum64(float v) {
  #pragma unroll
  for (int off = 1; off < 64; off <<= 1) v += __shfl_xor(v, off, 64);
  return v;
}
__device__ __forceinline__ float waveMax64(float v) {
  #pragma unroll
  for (int off = 1; off < 64; off <<= 1) v = fmaxf(v, __shfl_xor(v, off, 64));
  return v;
}
__device__ __forceinline__ float blockReduceSum256(float v, float* red) {
  #pragma unroll
  for (int off = 32; off > 0; off >>= 1) v += __shfl_down(v, off, 64);
  int lane = threadIdx.x & 63, wid = threadIdx.x >> 6;
  __syncthreads();
  if (lane == 0) red[wid] = v;
  __syncthreads();
  return red[0] + red[1] + red[2] + red[3];
}

// ---------- per-head transpose: qk[b][j][h*64+d] -> kT[b][h][d][j] ----------
__global__ __launch_bounds__(256) void transpose_heads(
    const float* __restrict__ qk, float* __restrict__ kT)
{
  __shared__ float t[64][65];
  int jt = blockIdx.x, h = blockIdx.y, b = blockIdx.z;
  int lane = threadIdx.x & 63, w = threadIdx.x >> 6;
  #pragma unroll
  for (int r = 0; r < 16; ++r) {
    int j = w + r * 4;
    t[j][lane] = qk[((size_t)(b * S_ + jt * 64 + j)) * D_ + h * DK_ + lane];
  }
  __syncthreads();
  #pragma unroll
  for (int r = 0; r < 16; ++r) {
    int d = w + r * 4;
    kT[((size_t)((b * H_ + h) * DK_ + d)) * S_ + jt * 64 + lane] = t[lane][d];
  }
}

// ---------- attention: one WAVE per (b,h,i) row ----------
__global__ __launch_bounds__(256) void attn_wave(
    const float* __restrict__ qk, const float* __restrict__ kT,
    const float* __restrict__ v, const float* __restrict__ gammas,
    float* __restrict__ out, int maskType, int zeroPad)
{
  __shared__ float at_sh[4][S_];
  int tid = threadIdx.x;
  int lane = tid & 63, w = tid >> 6;
  int grp = blockIdx.x;
  int igrp = grp & (S_ / 4 - 1);
  int h = (grp / (S_ / 4)) & (H_ - 1);
  int b = grp / ((S_ / 4) * H_);
  int i = igrp * 4 + w;
  int nv = (maskType == 0) ? i : (i + 1);
  float* orow = out + ((size_t)(b * S_ + i)) * D_ + h * DK_;
  if (zeroPad && i == 0) { orow[lane] = 0.f; return; }

  float qv = qk[((size_t)(b * S_ + i)) * D_ + h * DK_ + lane];
  const float* kTd = kT + ((size_t)((b * H_ + h) * DK_)) * S_ + lane * 8;
  int j0 = lane * 8;
  bool act = j0 < nv;
  float s[8] = {0.f, 0.f, 0.f, 0.f, 0.f, 0.f, 0.f, 0.f};
  #pragma unroll 4
  for (int d = 0; d < DK_; ++d) {
    float qd = __shfl(qv, d, 64);
    if (act) {
      const float4* kp = (const float4*)kTd;
      float4 k0 = kp[0], k1 = kp[1];
      s[0] = fmaf(qd, k0.x, s[0]); s[1] = fmaf(qd, k0.y, s[1]);
      s[2] = fmaf(qd, k0.z, s[2]); s[3] = fmaf(qd, k0.w, s[3]);
      s[4] = fmaf(qd, k1.x, s[4]); s[5] = fmaf(qd, k1.y, s[5]);
      s[6] = fmaf(qd, k1.z, s[6]); s[7] = fmaf(qd, k1.w, s[7]);
    }
    kTd += S_;
  }
  #pragma unroll
  for (int t = 0; t < 8; ++t) s[t] *= 0.125f;

  float m1 = -1e30f;
  #pragma unroll
  for (int t = 0; t < 8; ++t) if (j0 + t < nv) m1 = fmaxf(m1, s[t]);
  m1 = waveMax64(m1);
  float e[8], sum = 0.f;
  #pragma unroll
  for (int t = 0; t < 8; ++t) {
    e[t] = (j0 + t < nv) ? __expf(s[t] - m1) : 0.f;
    sum += e[t];
  }
  sum = waveSum64(sum);
  float inv = 1.f / sum;

  float c[8], p = 0.f;
  #pragma unroll
  for (int t = 0; t < 8; ++t) { p += e[t]; c[t] = p; }
  float tot = p, scn = p;
  #pragma unroll
  for (int off = 1; off < 64; off <<= 1) {
    float n = __shfl_up(scn, off, 64);
    if (lane >= off) scn += n;
  }
  float excl = scn - tot;
  float grand = __shfl(scn, 63, 64);

  float gam = gammas[h];
  float gneg = -((gam > 20.f) ? gam : log1pf(__expf(gam)));
  float s2[8];
  #pragma unroll
  for (int t = 0; t < 8; ++t) {
    float pos = fabsf((float)(j0 + t - i));
    float dd = sqrtf(fmaxf((grand - excl - c[t]) * inv * pos, 0.f));
    float te = fminf(fmaxf(__expf(dd * gneg), 1e-5f), 1e5f);
    s2[t] = s[t] * te;
  }

  float m2 = -1e30f;
  #pragma unroll
  for (int t = 0; t < 8; ++t) if (j0 + t < nv) m2 = fmaxf(m2, s2[t]);
  m2 = waveMax64(m2);
  float a[8], sum2 = 0.f;
  #pragma unroll
  for (int t = 0; t < 8; ++t) {
    a[t] = (j0 + t < nv) ? __expf(s2[t] - m2) : 0.f;
    sum2 += a[t];
  }
  sum2 = waveSum64(sum2);
  float inv2 = 1.f / sum2;
  #pragma unroll
  for (int t = 0; t < 8; ++t) a[t] *= inv2;

  float4* dst = (float4*)&at_sh[w][j0];
  dst[0] = make_float4(a[0], a[1], a[2], a[3]);
  dst[1] = make_float4(a[4], a[5], a[6], a[7]);

  float acc = 0.f;
  const float* vr = v + ((size_t)(b * S_)) * D_ + h * DK_ + lane;
  int j = 0;
  for (; j + 4 <= nv; j += 4) {
    float4 av = *(const float4*)&at_sh[w][j];
    acc = fmaf(av.x, vr[0], acc);
    acc = fmaf(av.y, vr[D_], acc);
    acc = fmaf(av.z, vr[2 * D_], acc);
    acc = fmaf(av.w, vr[3 * D_], acc);
    vr += 4 * D_;
  }
  for (; j < nv; ++j) { acc = fmaf(at_sh[w][j], vr[0], acc); vr += D_; }
  orow[lane] = acc;
}

// ---------- fused residual + layernorm (in-place on x) ----------
__global__ __launch_bounds__(256) void add_ln(
    float* __restrict__ x, const float* __restrict__ r,
    const float* __restrict__ g, const float* __restrict__ b)
{
  int row = blockIdx.x;
  int t = threadIdx.x;
  float* xr = x + (size_t)row * D_;
  const float* rr = r + (size_t)row * D_;
  float v0 = xr[t] + rr[t];
  float v1 = xr[t + 256] + rr[t + 256];
  __shared__ float red[4];
  float s = blockReduceSum256(v0 + v1, red);
  float mu = s * (1.0f / 512.0f);
  float d0 = v0 - mu, d1 = v1 - mu;
  float sq = blockReduceSum256(d0 * d0 + d1 * d1, red);
  float rstd = rsqrtf(sq * (1.0f / 512.0f) + 1e-5f);
  xr[t] = d0 * rstd * g[t] + b[t];
  xr[t + 256] = d1 * rstd * g[t + 256] + b[t + 256];
}

static inline void cvt(const float* in, unsigned short* out, size_t n, hipStream_t s) {
  size_t n8 = n / 8;
  int blocks = (int)((n8 + 255) / 256);
  if (blocks > 2048) blocks = 2048;
  cvt_f32_bf16<<<blocks, 256, 0, s>>>(in, out, n8);
}

extern "C" void kernel_launch(void* const* d_in, const int* in_sizes, int n_in,
                              void* d_out, int out_size, void* d_ws, size_t ws_size,
                              hipStream_t stream) {
  const float* q_embed  = (const float*)d_in[0];
  const float* qa_embed = (const float*)d_in[1];
  const float* Wk = (const float*)d_in[2];
  const float* bk = (const float*)d_in[3];
  const float* Wv = (const float*)d_in[4];
  const float* bv = (const float*)d_in[5];
  const float* Wo = (const float*)d_in[6];
  const float* bo = (const float*)d_in[7];
  const float* gammas = (const float*)d_in[8];
  const float* ln1_g = (const float*)d_in[9];
  const float* ln1_b = (const float*)d_in[10];
  const float* W1 = (const float*)d_in[11];
  const float* b1 = (const float*)d_in[12];
  const float* W2 = (const float*)d_in[13];
  const float* b2 = (const float*)d_in[14];
  const float* ln2_g = (const float*)d_in[15];
  const float* ln2_b = (const float*)d_in[16];

  float* x = (float*)d_out;
  const size_t NTOK = (size_t)B_ * S_;      // 16384
  const size_t ND = NTOK * D_;              // 8.39M floats

  float* qkbuf = (float*)d_ws;              // f32 [NTOK*D]
  float* vbuf  = qkbuf + ND;                // f32
  float* ao    = vbuf + ND;                 // f32
  float* kT    = ao + ND;                   // f32
  unsigned short* xb    = (unsigned short*)(kT + ND);       // bf16 [NTOK*D]
  unsigned short* valsb = xb + ND;                          // bf16 (also aob)
  unsigned short* aob   = valsb;
  unsigned short* wkb   = valsb + ND;                       // L*D*D
  unsigned short* wvb   = wkb + (size_t)L_ * D_ * D_;
  unsigned short* wob   = wvb + (size_t)L_ * D_ * D_;
  unsigned short* w1b   = wob + (size_t)L_ * D_ * D_;       // L*DFF*D
  unsigned short* w2b   = w1b + (size_t)L_ * DFF_ * D_;
  unsigned short* ffnb  = (unsigned short*)vbuf;            // bf16 [NTOK*DFF], aliases vbuf+ao

  hipMemcpyAsync(x, q_embed, ND * sizeof(float), hipMemcpyDeviceToDevice, stream);

  // weights -> bf16 (per call; deterministic)
  cvt(Wk, wkb, (size_t)L_ * D_ * D_, stream);
  cvt(Wv, wvb, (size_t)L_ * D_ * D_, stream);
  cvt(Wo, wob, (size_t)L_ * D_ * D_, stream);
  cvt(W1, w1b, (size_t)L_ * DFF_ * D_, stream);
  cvt(W2, w2b, (size_t)L_ * DFF_ * D_, stream);

  dim3 gproj(D_ / 128, NTOK / 128);     // (4, 128)
  dim3 gf1(DFF_ / 128, NTOK / 128);     // (16, 128)
  dim3 gf2(D_ / 128, NTOK / 128);
  dim3 gtr(S_ / 64, H_, B_);
  int gattn = B_ * H_ * (S_ / 4);

  for (int l = 0; l < L_; ++l) {
    int first = (l % 2 == 0);
    cvt(x, xb, ND, stream);
    const unsigned short* vA = xb;
    if (first) { cvt(qa_embed, valsb, ND, stream); vA = valsb; }

    gemm_bt_bf16<<<gproj, 256, 0, stream>>>(xb, wkb + (size_t)l * D_ * D_, bk + l * D_,
                                            qkbuf, nullptr, (int)NTOK, D_, D_, 0);
    gemm_bt_bf16<<<gproj, 256, 0, stream>>>(vA, wvb + (size_t)l * D_ * D_, bv + l * D_,
                                            vbuf, nullptr, (int)NTOK, D_, D_, 0);
    transpose_heads<<<gtr, 256, 0, stream>>>(qkbuf, kT);
    attn_wave<<<gattn, 256, 0, stream>>>(qkbuf, kT, vbuf, gammas + l * H_, ao,
                                         first ? 0 : 1, first ? 1 : 0);
    cvt(ao, aob, ND, stream);
    gemm_bt_bf16<<<gproj, 256, 0, stream>>>(aob, wob + (size_t)l * D_ * D_, bo + l * D_,
                                            qkbuf, nullptr, (int)NTOK, D_, D_, 0);
    add_ln<<<(int)NTOK, 256, 0, stream>>>(x, qkbuf, ln1_g + l * D_, ln1_b + l * D_);
    if (first) {
      cvt(x, xb, ND, stream);
      gemm_bt_bf16<<<gf1, 256, 0, stream>>>(xb, w1b + (size_t)l * DFF_ * D_, b1 + l * DFF_,
                                            nullptr, ffnb, (int)NTOK, DFF_, D_, 1);
      gemm_bt_bf16<<<gf2, 256, 0, stream>>>(ffnb, w2b + (size_t)l * D_ * DFF_, b2 + l * D_,
                                            qkbuf, nullptr, (int)NTOK, D_, DFF_, 0);
      add_ln<<<(int)NTOK, 256, 0, stream>>>(x, qkbuf, ln2_g + l * D_, ln2_b + l * D_);
    }
  }
}

// Round 4
// 3719.858 us; speedup vs baseline: 3.5715x; 1.0979x over previous
//
#include <hip/hip_runtime.h>
#include <hip/hip_bf16.h>
#include <math.h>

#define B_ 32
#define S_ 512
#define D_ 512
#define H_ 8
#define DK_ 64
#define DFF_ 2048
#define L_ 4

typedef __attribute__((ext_vector_type(8))) short bf16x8;
typedef __attribute__((ext_vector_type(4))) float f32x4;

__device__ __forceinline__ unsigned short f2bf(float x) {
  union { float f; unsigned u; } v; v.f = x;
  unsigned r = v.u + 0x7fff + ((v.u >> 16) & 1);   // round-nearest-even
  return (unsigned short)(r >> 16);
}

__device__ __forceinline__ void load_lds16(const void* g, void* l) {
  __builtin_amdgcn_global_load_lds(
      (const __attribute__((address_space(1))) void*)g,
      (__attribute__((address_space(3))) void*)l, 16, 0, 0);
}

// ---------- f32 -> bf16 convert ----------
__global__ __launch_bounds__(256) void cvt_f32_bf16(
    const float* __restrict__ in, unsigned short* __restrict__ out, size_t n8)
{
  size_t idx = (size_t)blockIdx.x * 256 + threadIdx.x;
  size_t stride = (size_t)gridDim.x * 256;
  for (size_t i = idx; i < n8; i += stride) {
    const float4* p = (const float4*)(in + i * 8);
    float4 a = p[0], b = p[1];
    union { unsigned short u[8]; int4 v; } o;
    o.u[0] = f2bf(a.x); o.u[1] = f2bf(a.y); o.u[2] = f2bf(a.z); o.u[3] = f2bf(a.w);
    o.u[4] = f2bf(b.x); o.u[5] = f2bf(b.y); o.u[6] = f2bf(b.z); o.u[7] = f2bf(b.w);
    *(int4*)(out + i * 8) = o.v;
  }
}

// ---------- bf16 MFMA GEMM: C[M,N] = A[M,K] @ W[N,K]^T + bias ----------
__global__ __launch_bounds__(256) void gemm_bt_bf16(
    const unsigned short* __restrict__ A, const unsigned short* __restrict__ W,
    const float* __restrict__ bias,
    float* __restrict__ Cf, unsigned short* __restrict__ Cb,
    int M, int N, int K, int relu)
{
  __shared__ __align__(16) short As[128 * 32];
  __shared__ __align__(16) short Ws[128 * 32];
  int tid = threadIdx.x;
  int lane = tid & 63, w = tid >> 6;
  int wr = w >> 1, wc = w & 1;
  int bm = blockIdx.y * 128, bn = blockIdx.x * 128;

  f32x4 acc[4][4];
  #pragma unroll
  for (int m = 0; m < 4; ++m)
    #pragma unroll
    for (int n = 0; n < 4; ++n) acc[m][n] = (f32x4){0.f, 0.f, 0.f, 0.f};

  int srow = tid >> 2;
  int skB  = (tid & 3) * 16;
  const char* pa0 = (const char*)(A + (size_t)(bm + srow) * K) + skB;
  const char* pa1 = (const char*)(A + (size_t)(bm + 64 + srow) * K) + skB;
  const char* pw0 = (const char*)(W + (size_t)(bn + srow) * K) + skB;
  const char* pw1 = (const char*)(W + (size_t)(bn + 64 + srow) * K) + skB;
  char* lA0 = (char*)As + w * 1024;
  char* lA1 = (char*)As + 4096 + w * 1024;
  char* lW0 = (char*)Ws + w * 1024;
  char* lW1 = (char*)Ws + 4096 + w * 1024;

  int r = lane & 15, k8 = lane >> 4;
  const bf16x8* Arow = (const bf16x8*)As;
  const bf16x8* Wrow = (const bf16x8*)Ws;

  for (int k0 = 0; k0 < K; k0 += 32) {
    load_lds16(pa0, lA0);
    load_lds16(pa1, lA1);
    load_lds16(pw0, lW0);
    load_lds16(pw1, lW1);
    pa0 += 64; pa1 += 64; pw0 += 64; pw1 += 64;
    __syncthreads();
    bf16x8 aF[4], bF[4];
    #pragma unroll
    for (int m = 0; m < 4; ++m) aF[m] = Arow[(wr * 64 + m * 16 + r) * 4 + k8];
    #pragma unroll
    for (int n = 0; n < 4; ++n) bF[n] = Wrow[(wc * 64 + n * 16 + r) * 4 + k8];
    #pragma unroll
    for (int m = 0; m < 4; ++m)
      #pragma unroll
      for (int n = 0; n < 4; ++n)
        acc[m][n] = __builtin_amdgcn_mfma_f32_16x16x32_bf16(aF[m], bF[n], acc[m][n], 0, 0, 0);
    __syncthreads();
  }

  int orow0 = bm + wr * 64 + (lane >> 4) * 4;
  int ocol0 = bn + wc * 64 + (lane & 15);
  #pragma unroll
  for (int n = 0; n < 4; ++n) {
    int col = ocol0 + n * 16;
    float bv = bias[col];
    #pragma unroll
    for (int m = 0; m < 4; ++m) {
      int row = orow0 + m * 16;
      #pragma unroll
      for (int j = 0; j < 4; ++j) {
        float val = acc[m][n][j] + bv;
        if (relu) val = fmaxf(val, 0.f);
        size_t off = (size_t)(row + j) * N + col;
        if (Cf) Cf[off] = val; else Cb[off] = f2bf(val);
      }
    }
  }
}

// ---------- per-head transpose (bf16): v[b][j][h*64+d] -> vt[b][h][d][j] ----------
__global__ __launch_bounds__(256) void transpose_heads_bf16(
    const unsigned short* __restrict__ v, unsigned short* __restrict__ vt)
{
  __shared__ unsigned short t[64][65];
  int jt = blockIdx.x, h = blockIdx.y, b = blockIdx.z;
  int lane = threadIdx.x & 63, w = threadIdx.x >> 6;
  #pragma unroll
  for (int r = 0; r < 16; ++r) {
    int j = w + r * 4;
    t[j][lane] = v[((size_t)(b * S_ + jt * 64 + j)) * D_ + h * DK_ + lane];
  }
  __syncthreads();
  #pragma unroll
  for (int r = 0; r < 16; ++r) {
    int d = w + r * 4;
    vt[((size_t)((b * H_ + h) * DK_ + d)) * S_ + jt * 64 + lane] = t[lane][d];
  }
}

// ---------- MFMA fused attention ----------
// One wave per 16-row q-tile. qkb: q==k bf16 [b][s][D]; vtb: V^T bf16 [b][h][64][S].
// maskType 0: valid j<i, zero row0; 1: valid j<=i.
__global__ __launch_bounds__(256) void attn_mfma(
    const unsigned short* __restrict__ qkb,
    const unsigned short* __restrict__ vtb,
    const float* __restrict__ gammas,
    unsigned short* __restrict__ ao,
    int maskType)
{
  int tid = threadIdx.x;
  int lane = tid & 63, w = tid >> 6;
  int wid = blockIdx.x * 4 + w;
  int qt = wid & 31;                 // q-tile within sequence (S/16 = 32)
  int h = (wid >> 5) & (H_ - 1);
  int b = wid >> 8;
  int i0 = qt * 16;
  int c15 = lane & 15, g = lane >> 4;

  __shared__ __align__(16) unsigned short P_all[4][16][48];  // per-wave P scratch
  unsigned short (*P_lds)[48] = P_all[w];

  // ---- Q A-frags (held whole kernel) ----
  const unsigned short* qbase =
      qkb + ((size_t)(b * S_ + i0 + c15)) * D_ + h * DK_ + g * 8;
  bf16x8 aQ0 = *(const bf16x8*)(qbase);
  bf16x8 aQ1 = *(const bf16x8*)(qbase + 32);

  // ---- QK^T: tiles kt=0..qt (uniform guard -> triangle skip) ----
  f32x4 sreg[32];
  const unsigned short* kbase = qkb + ((size_t)b * S_) * D_ + h * DK_ + g * 8;
  float m1[4] = {-1e30f, -1e30f, -1e30f, -1e30f};
  #pragma unroll
  for (int kt = 0; kt < 32; ++kt) {
    if (kt <= qt) {
      const unsigned short* kr = kbase + (size_t)(kt * 16 + c15) * D_;
      bf16x8 bK0 = *(const bf16x8*)(kr);
      bf16x8 bK1 = *(const bf16x8*)(kr + 32);
      f32x4 c = (f32x4){0.f, 0.f, 0.f, 0.f};
      c = __builtin_amdgcn_mfma_f32_16x16x32_bf16(aQ0, bK0, c, 0, 0, 0);
      c = __builtin_amdgcn_mfma_f32_16x16x32_bf16(aQ1, bK1, c, 0, 0, 0);
      #pragma unroll
      for (int r = 0; r < 4; ++r) c[r] *= 0.125f;
      if (kt == qt) {     // only boundary tile needs per-element mask
        int j = kt * 16 + c15;
        #pragma unroll
        for (int r = 0; r < 4; ++r) {
          int i = i0 + 4 * g + r;
          bool valid = maskType ? (j <= i) : (j < i);
          if (!valid) c[r] = -1e30f;
        }
      }
      sreg[kt] = c;
      #pragma unroll
      for (int r = 0; r < 4; ++r) m1[r] = fmaxf(m1[r], c[r]);
    }
  }
  #pragma unroll
  for (int r = 0; r < 4; ++r)
    #pragma unroll
    for (int off = 1; off < 16; off <<= 1)
      m1[r] = fmaxf(m1[r], __shfl_xor(m1[r], off, 64));

  // ---- softmax #1 denominator ----
  float sum1[4] = {0.f, 0.f, 0.f, 0.f};
  #pragma unroll
  for (int kt = 0; kt < 32; ++kt) {
    if (kt <= qt) {
      #pragma unroll
      for (int r = 0; r < 4; ++r) sum1[r] += __expf(sreg[kt][r] - m1[r]);
    }
  }
  #pragma unroll
  for (int r = 0; r < 4; ++r)
    #pragma unroll
    for (int off = 1; off < 16; off <<= 1)
      sum1[r] += __shfl_xor(sum1[r], off, 64);
  float inv1[4];
  #pragma unroll
  for (int r = 0; r < 4; ++r) inv1[r] = (sum1[r] > 0.f) ? 1.f / sum1[r] : 0.f;

  // ---- ordered cumsum + distance decay + rescore (in place) ----
  float gam = gammas[h];
  float gneg = -((gam > 20.f) ? gam : log1pf(__expf(gam)));   // -softplus
  float carry[4] = {0.f, 0.f, 0.f, 0.f};
  float m2[4] = {-1e30f, -1e30f, -1e30f, -1e30f};
  #pragma unroll
  for (int kt = 0; kt < 32; ++kt) {
    if (kt <= qt) {
      f32x4 s = sreg[kt];
      #pragma unroll
      for (int r = 0; r < 4; ++r) {
        float e = __expf(s[r] - m1[r]);
        float p = e;                       // inclusive scan over 16 lanes (j-order)
        #pragma unroll
        for (int off = 1; off < 16; off <<= 1) {
          float t = __shfl_up(p, off, 16);
          if (c15 >= off) p += t;
        }
        float tot = __shfl(p, lane | 15, 64);   // tile total (lane15 of group)
        float cum = carry[r] + p;
        carry[r] += tot;
        float suffix = sum1[r] - cum;
        int i = i0 + 4 * g + r;
        float pos = fabsf((float)(kt * 16 + c15 - i));
        float dist = sqrtf(fmaxf(suffix * inv1[r] * pos, 0.f));
        float te = fminf(fmaxf(__expf(dist * gneg), 1e-5f), 1e5f);
        float s2 = s[r] * te;
        s[r] = s2;
        m2[r] = fmaxf(m2[r], s2);
      }
      sreg[kt] = s;
    }
  }
  #pragma unroll
  for (int r = 0; r < 4; ++r)
    #pragma unroll
    for (int off = 1; off < 16; off <<= 1)
      m2[r] = fmaxf(m2[r], __shfl_xor(m2[r], off, 64));

  // ---- softmax #2 (unnormalized) fused with PV ----
  f32x4 acc[4];
  #pragma unroll
  for (int dt = 0; dt < 4; ++dt) acc[dt] = (f32x4){0.f, 0.f, 0.f, 0.f};
  float sum2[4] = {0.f, 0.f, 0.f, 0.f};
  const unsigned short* vbase =
      vtb + (((size_t)(b * H_ + h) * DK_) + c15) * S_ + g * 8;

  #pragma unroll
  for (int jc = 0; jc < 16; ++jc) {
    if (jc * 2 <= qt) {
      #pragma unroll
      for (int t2 = 0; t2 < 2; ++t2) {
        int kt = jc * 2 + t2;
        if (kt <= qt) {
          f32x4 s = sreg[kt];
          #pragma unroll
          for (int r = 0; r < 4; ++r) {
            float e2 = __expf(s[r] - m2[r]);
            sum2[r] += e2;
            P_lds[4 * g + r][t2 * 16 + c15] = f2bf(e2);
          }
        } else {
          #pragma unroll
          for (int r = 0; r < 4; ++r) P_lds[4 * g + r][t2 * 16 + c15] = 0;
        }
      }
      asm volatile("s_waitcnt lgkmcnt(0)" ::: "memory");
      __builtin_amdgcn_sched_barrier(0);
      bf16x8 aP = *(const bf16x8*)&P_lds[c15][g * 8];
      const unsigned short* vr = vbase + (size_t)jc * 32;
      #pragma unroll
      for (int dt = 0; dt < 4; ++dt) {
        bf16x8 bV = *(const bf16x8*)(vr + (size_t)dt * 16 * S_);
        acc[dt] = __builtin_amdgcn_mfma_f32_16x16x32_bf16(aP, bV, acc[dt], 0, 0, 0);
      }
      asm volatile("s_waitcnt lgkmcnt(0)" ::: "memory");  // MFMA reads done before next overwrite
      __builtin_amdgcn_sched_barrier(0);
    }
  }
  #pragma unroll
  for (int r = 0; r < 4; ++r)
    #pragma unroll
    for (int off = 1; off < 16; off <<= 1)
      sum2[r] += __shfl_xor(sum2[r], off, 64);

  // ---- epilogue: normalize by row, zeroPad row0 (mask0), store bf16 ----
  int zp = (maskType == 0 && qt == 0);
  #pragma unroll
  for (int dt = 0; dt < 4; ++dt) {
    #pragma unroll
    for (int r = 0; r < 4; ++r) {
      int i = i0 + 4 * g + r;
      float val = acc[dt][r] / sum2[r];
      if (zp && (4 * g + r) == 0) val = 0.f;
      ao[((size_t)(b * S_ + i)) * D_ + h * DK_ + dt * 16 + c15] = f2bf(val);
    }
  }
}

// ---------- wave/block reduce + residual LN ----------
__device__ __forceinline__ float blockReduceSum256(float v, float* red) {
  #pragma unroll
  for (int off = 32; off > 0; off >>= 1) v += __shfl_down(v, off, 64);
  int lane = threadIdx.x & 63, wid = threadIdx.x >> 6;
  __syncthreads();
  if (lane == 0) red[wid] = v;
  __syncthreads();
  return red[0] + red[1] + red[2] + red[3];
}

__global__ __launch_bounds__(256) void add_ln(
    float* __restrict__ x, const float* __restrict__ r,
    const float* __restrict__ g, const float* __restrict__ b)
{
  int row = blockIdx.x;
  int t = threadIdx.x;
  float* xr = x + (size_t)row * D_;
  const float* rr = r + (size_t)row * D_;
  float v0 = xr[t] + rr[t];
  float v1 = xr[t + 256] + rr[t + 256];
  __shared__ float red[4];
  float s = blockReduceSum256(v0 + v1, red);
  float mu = s * (1.0f / 512.0f);
  float d0 = v0 - mu, d1 = v1 - mu;
  float sq = blockReduceSum256(d0 * d0 + d1 * d1, red);
  float rstd = rsqrtf(sq * (1.0f / 512.0f) + 1e-5f);
  xr[t] = d0 * rstd * g[t] + b[t];
  xr[t + 256] = d1 * rstd * g[t + 256] + b[t + 256];
}

static inline void cvt(const float* in, unsigned short* out, size_t n, hipStream_t s) {
  size_t n8 = n / 8;
  int blocks = (int)((n8 + 255) / 256);
  if (blocks > 2048) blocks = 2048;
  cvt_f32_bf16<<<blocks, 256, 0, s>>>(in, out, n8);
}

extern "C" void kernel_launch(void* const* d_in, const int* in_sizes, int n_in,
                              void* d_out, int out_size, void* d_ws, size_t ws_size,
                              hipStream_t stream) {
  const float* q_embed  = (const float*)d_in[0];
  const float* qa_embed = (const float*)d_in[1];
  const float* Wk = (const float*)d_in[2];
  const float* bk = (const float*)d_in[3];
  const float* Wv = (const float*)d_in[4];
  const float* bv = (const float*)d_in[5];
  const float* Wo = (const float*)d_in[6];
  const float* bo = (const float*)d_in[7];
  const float* gammas = (const float*)d_in[8];
  const float* ln1_g = (const float*)d_in[9];
  const float* ln1_b = (const float*)d_in[10];
  const float* W1 = (const float*)d_in[11];
  const float* b1 = (const float*)d_in[12];
  const float* W2 = (const float*)d_in[13];
  const float* b2 = (const float*)d_in[14];
  const float* ln2_g = (const float*)d_in[15];
  const float* ln2_b = (const float*)d_in[16];

  float* x = (float*)d_out;
  const size_t NTOK = (size_t)B_ * S_;      // 16384
  const size_t ND = NTOK * D_;

  float* qkf = (float*)d_ws;                               // f32 scratch [ND]
  unsigned short* xb    = (unsigned short*)(qkf + ND);     // bf16 [ND]
  unsigned short* valsb = xb + ND;
  unsigned short* qkb   = valsb + ND;
  unsigned short* vb    = qkb + ND;
  unsigned short* vtb   = vb + ND;
  unsigned short* aob   = vtb + ND;
  unsigned short* wkb   = aob + ND;
  unsigned short* wvb   = wkb + (size_t)L_ * D_ * D_;
  unsigned short* wob   = wvb + (size_t)L_ * D_ * D_;
  unsigned short* w1b   = wob + (size_t)L_ * D_ * D_;
  unsigned short* w2b   = w1b + (size_t)L_ * DFF_ * D_;
  unsigned short* ffnb  = qkb;   // [NTOK*DFF] aliases qkb+vb+vtb+aob (dead in FFN phase)

  hipMemcpyAsync(x, q_embed, ND * sizeof(float), hipMemcpyDeviceToDevice, stream);

  cvt(Wk, wkb, (size_t)L_ * D_ * D_, stream);
  cvt(Wv, wvb, (size_t)L_ * D_ * D_, stream);
  cvt(Wo, wob, (size_t)L_ * D_ * D_, stream);
  cvt(W1, w1b, (size_t)L_ * DFF_ * D_, stream);
  cvt(W2, w2b, (size_t)L_ * DFF_ * D_, stream);
  cvt(qa_embed, valsb, ND, stream);

  dim3 gproj(D_ / 128, NTOK / 128);
  dim3 gf1(DFF_ / 128, NTOK / 128);
  dim3 gf2(D_ / 128, NTOK / 128);
  dim3 gtr(S_ / 64, H_, B_);
  int gattn = B_ * H_ * (S_ / 16) / 4;   // 2048 blocks, 1 wave per q-tile

  for (int l = 0; l < L_; ++l) {
    int first = (l % 2 == 0);
    cvt(x, xb, ND, stream);
    const unsigned short* vA = first ? valsb : xb;

    gemm_bt_bf16<<<gproj, 256, 0, stream>>>(xb, wkb + (size_t)l * D_ * D_, bk + l * D_,
                                            nullptr, qkb, (int)NTOK, D_, D_, 0);
    gemm_bt_bf16<<<gproj, 256, 0, stream>>>(vA, wvb + (size_t)l * D_ * D_, bv + l * D_,
                                            nullptr, vb, (int)NTOK, D_, D_, 0);
    transpose_heads_bf16<<<gtr, 256, 0, stream>>>(vb, vtb);
    attn_mfma<<<gattn, 256, 0, stream>>>(qkb, vtb, gammas + l * H_, aob, first ? 0 : 1);
    gemm_bt_bf16<<<gproj, 256, 0, stream>>>(aob, wob + (size_t)l * D_ * D_, bo + l * D_,
                                            qkf, nullptr, (int)NTOK, D_, D_, 0);
    add_ln<<<(int)NTOK, 256, 0, stream>>>(x, qkf, ln1_g + l * D_, ln1_b + l * D_);
    if (first) {
      cvt(x, xb, ND, stream);
      gemm_bt_bf16<<<gf1, 256, 0, stream>>>(xb, w1b + (size_t)l * DFF_ * D_, b1 + l * DFF_,
                                            nullptr, ffnb, (int)NTOK, DFF_, D_, 1);
      gemm_bt_bf16<<<gf2, 256, 0, stream>>>(ffnb, w2b + (size_t)l * D_ * DFF_, b2 + l * D_,
                                            qkf, nullptr, (int)NTOK, D_, DFF_, 0);
      add_ln<<<(int)NTOK, 256, 0, stream>>>(x, qkf, ln2_g + l * D_, ln2_b + l * D_);
    }
  }
}

// Round 8
// 2203.778 us; speedup vs baseline: 6.0284x; 1.6879x over previous
//
#include <hip/hip_runtime.h>
#include <hip/hip_bf16.h>
#include <math.h>

#define B_ 32
#define S_ 512
#define D_ 512
#define H_ 8
#define DK_ 64
#define DFF_ 2048
#define L_ 4

typedef __attribute__((ext_vector_type(8))) short bf16x8;
typedef __attribute__((ext_vector_type(4))) float f32x4;

__device__ __forceinline__ unsigned short f2bf(float x) {
  union { float f; unsigned u; } v; v.f = x;
  unsigned r = v.u + 0x7fff + ((v.u >> 16) & 1);   // round-nearest-even
  return (unsigned short)(r >> 16);
}

__device__ __forceinline__ void load_lds16(const void* g, void* l) {
  __builtin_amdgcn_global_load_lds(
      (const __attribute__((address_space(1))) void*)g,
      (__attribute__((address_space(3))) void*)l, 16, 0, 0);
}

// ---------- f32 -> bf16 convert ----------
__global__ __launch_bounds__(256) void cvt_f32_bf16(
    const float* __restrict__ in, unsigned short* __restrict__ out, size_t n8)
{
  size_t idx = (size_t)blockIdx.x * 256 + threadIdx.x;
  size_t stride = (size_t)gridDim.x * 256;
  for (size_t i = idx; i < n8; i += stride) {
    const float4* p = (const float4*)(in + i * 8);
    float4 a = p[0], b = p[1];
    union { unsigned short u[8]; int4 v; } o;
    o.u[0] = f2bf(a.x); o.u[1] = f2bf(a.y); o.u[2] = f2bf(a.z); o.u[3] = f2bf(a.w);
    o.u[4] = f2bf(b.x); o.u[5] = f2bf(b.y); o.u[6] = f2bf(b.z); o.u[7] = f2bf(b.w);
    *(int4*)(out + i * 8) = o.v;
  }
}

// ---------- bf16 MFMA GEMM: C[M,N] = A[M,K] @ W[N,K]^T + bias ----------
__global__ __launch_bounds__(256) void gemm_bt_bf16(
    const unsigned short* __restrict__ A, const unsigned short* __restrict__ W,
    const float* __restrict__ bias,
    float* __restrict__ Cf, unsigned short* __restrict__ Cb,
    int M, int N, int K, int relu)
{
  __shared__ __align__(16) short As[128 * 32];
  __shared__ __align__(16) short Ws[128 * 32];
  int tid = threadIdx.x;
  int lane = tid & 63, w = tid >> 6;
  int wr = w >> 1, wc = w & 1;
  int bm = blockIdx.y * 128, bn = blockIdx.x * 128;

  f32x4 acc[4][4];
  #pragma unroll
  for (int m = 0; m < 4; ++m)
    #pragma unroll
    for (int n = 0; n < 4; ++n) acc[m][n] = (f32x4){0.f, 0.f, 0.f, 0.f};

  int srow = tid >> 2;
  int skB  = (tid & 3) * 16;
  const char* pa0 = (const char*)(A + (size_t)(bm + srow) * K) + skB;
  const char* pa1 = (const char*)(A + (size_t)(bm + 64 + srow) * K) + skB;
  const char* pw0 = (const char*)(W + (size_t)(bn + srow) * K) + skB;
  const char* pw1 = (const char*)(W + (size_t)(bn + 64 + srow) * K) + skB;
  char* lA0 = (char*)As + w * 1024;
  char* lA1 = (char*)As + 4096 + w * 1024;
  char* lW0 = (char*)Ws + w * 1024;
  char* lW1 = (char*)Ws + 4096 + w * 1024;

  int r = lane & 15, k8 = lane >> 4;
  const bf16x8* Arow = (const bf16x8*)As;
  const bf16x8* Wrow = (const bf16x8*)Ws;

  for (int k0 = 0; k0 < K; k0 += 32) {
    load_lds16(pa0, lA0);
    load_lds16(pa1, lA1);
    load_lds16(pw0, lW0);
    load_lds16(pw1, lW1);
    pa0 += 64; pa1 += 64; pw0 += 64; pw1 += 64;
    __syncthreads();
    bf16x8 aF[4], bF[4];
    #pragma unroll
    for (int m = 0; m < 4; ++m) aF[m] = Arow[(wr * 64 + m * 16 + r) * 4 + k8];
    #pragma unroll
    for (int n = 0; n < 4; ++n) bF[n] = Wrow[(wc * 64 + n * 16 + r) * 4 + k8];
    #pragma unroll
    for (int m = 0; m < 4; ++m)
      #pragma unroll
      for (int n = 0; n < 4; ++n)
        acc[m][n] = __builtin_amdgcn_mfma_f32_16x16x32_bf16(aF[m], bF[n], acc[m][n], 0, 0, 0);
    __syncthreads();
  }

  int orow0 = bm + wr * 64 + (lane >> 4) * 4;
  int ocol0 = bn + wc * 64 + (lane & 15);
  #pragma unroll
  for (int n = 0; n < 4; ++n) {
    int col = ocol0 + n * 16;
    float bv = bias[col];
    #pragma unroll
    for (int m = 0; m < 4; ++m) {
      int row = orow0 + m * 16;
      #pragma unroll
      for (int j = 0; j < 4; ++j) {
        float val = acc[m][n][j] + bv;
        if (relu) val = fmaxf(val, 0.f);
        size_t off = (size_t)(row + j) * N + col;
        if (Cf) Cf[off] = val; else Cb[off] = f2bf(val);
      }
    }
  }
}

// ---------- per-head transpose (bf16): v[b][j][h*64+d] -> vt[b][h][d][j] ----------
__global__ __launch_bounds__(256) void transpose_heads_bf16(
    const unsigned short* __restrict__ v, unsigned short* __restrict__ vt)
{
  __shared__ unsigned short t[64][65];
  int jt = blockIdx.x, h = blockIdx.y, b = blockIdx.z;
  int lane = threadIdx.x & 63, w = threadIdx.x >> 6;
  #pragma unroll
  for (int r = 0; r < 16; ++r) {
    int j = w + r * 4;
    t[j][lane] = v[((size_t)(b * S_ + jt * 64 + j)) * D_ + h * DK_ + lane];
  }
  __syncthreads();
  #pragma unroll
  for (int r = 0; r < 16; ++r) {
    int d = w + r * 4;
    vt[((size_t)((b * H_ + h) * DK_ + d)) * S_ + jt * 64 + lane] = t[lane][d];
  }
}

// ---------- R4-verbatim QK tile: scores scaled + boundary-masked ----------
__device__ __forceinline__ f32x4 qk_tile(
    int kt, int qt, int i0, int g, int c15, int maskType,
    const unsigned short* kbase, bf16x8 aQ0, bf16x8 aQ1)
{
  const unsigned short* kr = kbase + (size_t)(kt * 16 + c15) * D_;
  bf16x8 bK0 = *(const bf16x8*)(kr);
  bf16x8 bK1 = *(const bf16x8*)(kr + 32);
  f32x4 c = (f32x4){0.f, 0.f, 0.f, 0.f};
  c = __builtin_amdgcn_mfma_f32_16x16x32_bf16(aQ0, bK0, c, 0, 0, 0);
  c = __builtin_amdgcn_mfma_f32_16x16x32_bf16(aQ1, bK1, c, 0, 0, 0);
  #pragma unroll
  for (int r = 0; r < 4; ++r) c[r] *= 0.125f;
  if (kt == qt) {     // only boundary tile needs per-element mask (R4-verbatim)
    int j = kt * 16 + c15;
    #pragma unroll
    for (int r = 0; r < 4; ++r) {
      int i = i0 + 4 * g + r;
      bool valid = maskType ? (j <= i) : (j < i);
      if (!valid) c[r] = -1e30f;
    }
  }
  return c;
}

// ---------- MFMA attention: R4 dataflow, recompute instead of sreg store ----------
// One wave per 16-row q-tile; 4 QK passes (m1 / sum1 / m2+cumsum / P+PV).
// All math identical to R4's passing kernel (fixed m1/m2, no online rescale).
__global__ __launch_bounds__(256) void attn_mfma2(
    const unsigned short* __restrict__ qkb,   // q==k bf16 [b][s][D]
    const unsigned short* __restrict__ vtb,   // V^T bf16 [b][h][64][S]
    const float* __restrict__ gammas,
    unsigned short* __restrict__ ao,
    int maskType)
{
  __shared__ __align__(16) unsigned short P_all[4][16][48];  // R4-verbatim
  int tid = threadIdx.x;
  int lane = tid & 63, w = tid >> 6;
  unsigned short (*P_lds)[48] = P_all[w];
  int wid = blockIdx.x * 4 + w;
  int qt = wid & 31;                 // q-tile within sequence (S/16 = 32)
  int h = (wid >> 5) & (H_ - 1);
  int b = wid >> 8;
  int i0 = qt * 16;
  int c15 = lane & 15, g = lane >> 4;

  // ---- Q A-frags (R4-verbatim) ----
  const unsigned short* qbase =
      qkb + ((size_t)(b * S_ + i0 + c15)) * D_ + h * DK_ + g * 8;
  bf16x8 aQ0 = *(const bf16x8*)(qbase);
  bf16x8 aQ1 = *(const bf16x8*)(qbase + 32);
  const unsigned short* kbase = qkb + ((size_t)b * S_) * D_ + h * DK_ + g * 8;

  float gam = gammas[h];
  float gneg = -((gam > 20.f) ? gam : log1pf(__expf(gam)));   // -softplus

  // ---- phase 1: global row max m1 ----
  float m1[4] = {-1e30f, -1e30f, -1e30f, -1e30f};
  for (int kt = 0; kt <= qt; ++kt) {
    f32x4 c = qk_tile(kt, qt, i0, g, c15, maskType, kbase, aQ0, aQ1);
    #pragma unroll
    for (int r = 0; r < 4; ++r) m1[r] = fmaxf(m1[r], c[r]);
  }
  #pragma unroll
  for (int r = 0; r < 4; ++r)
    #pragma unroll
    for (int off = 1; off < 16; off <<= 1)
      m1[r] = fmaxf(m1[r], __shfl_xor(m1[r], off, 64));

  // ---- phase 2: sum1 with fixed m1 (R4-verbatim math) ----
  float sum1[4] = {0.f, 0.f, 0.f, 0.f};
  for (int kt = 0; kt <= qt; ++kt) {
    f32x4 c = qk_tile(kt, qt, i0, g, c15, maskType, kbase, aQ0, aQ1);
    #pragma unroll
    for (int r = 0; r < 4; ++r) sum1[r] += __expf(c[r] - m1[r]);
  }
  #pragma unroll
  for (int r = 0; r < 4; ++r)
    #pragma unroll
    for (int off = 1; off < 16; off <<= 1)
      sum1[r] += __shfl_xor(sum1[r], off, 64);
  float inv1[4];
  #pragma unroll
  for (int r = 0; r < 4; ++r) inv1[r] = (sum1[r] > 0.f) ? 1.f / sum1[r] : 0.f;

  // ---- phase 3: cumsum dry-run -> global m2 (R4-verbatim math) ----
  float m2[4] = {-1e30f, -1e30f, -1e30f, -1e30f};
  {
    float carry[4] = {0.f, 0.f, 0.f, 0.f};
    for (int kt = 0; kt <= qt; ++kt) {
      f32x4 c = qk_tile(kt, qt, i0, g, c15, maskType, kbase, aQ0, aQ1);
      #pragma unroll
      for (int r = 0; r < 4; ++r) {
        float e = __expf(c[r] - m1[r]);
        float p = e;
        #pragma unroll
        for (int off = 1; off < 16; off <<= 1) {
          float t = __shfl_up(p, off, 16);
          if (c15 >= off) p += t;
        }
        float tot = __shfl(p, lane | 15, 64);
        float cum = carry[r] + p;
        carry[r] += tot;
        float suffix = sum1[r] - cum;
        int i = i0 + 4 * g + r;
        float pos = fabsf((float)(kt * 16 + c15 - i));
        float dist = sqrtf(fmaxf(suffix * inv1[r] * pos, 0.f));
        float te = fminf(fmaxf(__expf(dist * gneg), 1e-5f), 1e5f);
        float s2 = c[r] * te;
        m2[r] = fmaxf(m2[r], s2);
      }
    }
  }
  #pragma unroll
  for (int r = 0; r < 4; ++r)
    #pragma unroll
    for (int off = 1; off < 16; off <<= 1)
      m2[r] = fmaxf(m2[r], __shfl_xor(m2[r], off, 64));

  // ---- phase 4: recompute cumsum, P = exp(s2 - m2), fused PV (R4-verbatim) ----
  f32x4 acc[4];
  #pragma unroll
  for (int dt = 0; dt < 4; ++dt) acc[dt] = (f32x4){0.f, 0.f, 0.f, 0.f};
  float sum2[4] = {0.f, 0.f, 0.f, 0.f};
  {
    float carry[4] = {0.f, 0.f, 0.f, 0.f};
    const unsigned short* vbase =
        vtb + (((size_t)(b * H_ + h) * DK_) + c15) * S_ + g * 8;

    #pragma unroll
    for (int jc = 0; jc < 16; ++jc) {
      if (jc * 2 <= qt) {
        #pragma unroll
        for (int t2 = 0; t2 < 2; ++t2) {
          int kt = jc * 2 + t2;
          if (kt <= qt) {
            f32x4 c = qk_tile(kt, qt, i0, g, c15, maskType, kbase, aQ0, aQ1);
            #pragma unroll
            for (int r = 0; r < 4; ++r) {
              float e = __expf(c[r] - m1[r]);
              float p = e;
              #pragma unroll
              for (int off = 1; off < 16; off <<= 1) {
                float t = __shfl_up(p, off, 16);
                if (c15 >= off) p += t;
              }
              float tot = __shfl(p, lane | 15, 64);
              float cum = carry[r] + p;
              carry[r] += tot;
              float suffix = sum1[r] - cum;
              int i = i0 + 4 * g + r;
              float pos = fabsf((float)(kt * 16 + c15 - i));
              float dist = sqrtf(fmaxf(suffix * inv1[r] * pos, 0.f));
              float te = fminf(fmaxf(__expf(dist * gneg), 1e-5f), 1e5f);
              float s2 = c[r] * te;
              float e2 = __expf(s2 - m2[r]);
              sum2[r] += e2;
              P_lds[4 * g + r][t2 * 16 + c15] = f2bf(e2);
            }
          } else {
            #pragma unroll
            for (int r = 0; r < 4; ++r) P_lds[4 * g + r][t2 * 16 + c15] = 0;
          }
        }
        asm volatile("s_waitcnt lgkmcnt(0)" ::: "memory");
        __builtin_amdgcn_sched_barrier(0);
        bf16x8 aP = *(const bf16x8*)&P_lds[c15][g * 8];
        const unsigned short* vr = vbase + (size_t)jc * 32;
        #pragma unroll
        for (int dt = 0; dt < 4; ++dt) {
          bf16x8 bV = *(const bf16x8*)(vr + (size_t)dt * 16 * S_);
          acc[dt] = __builtin_amdgcn_mfma_f32_16x16x32_bf16(aP, bV, acc[dt], 0, 0, 0);
        }
        asm volatile("s_waitcnt lgkmcnt(0)" ::: "memory");
        __builtin_amdgcn_sched_barrier(0);
      }
    }
  }
  #pragma unroll
  for (int r = 0; r < 4; ++r)
    #pragma unroll
    for (int off = 1; off < 16; off <<= 1)
      sum2[r] += __shfl_xor(sum2[r], off, 64);

  // ---- epilogue (R4-verbatim): normalize by row, zeroPad row0, store bf16 ----
  int zp = (maskType == 0 && qt == 0);
  #pragma unroll
  for (int dt = 0; dt < 4; ++dt) {
    #pragma unroll
    for (int r = 0; r < 4; ++r) {
      int i = i0 + 4 * g + r;
      float val = acc[dt][r] / sum2[r];
      if (zp && (4 * g + r) == 0) val = 0.f;
      ao[((size_t)(b * S_ + i)) * D_ + h * DK_ + dt * 16 + c15] = f2bf(val);
    }
  }
}

// ---------- wave/block reduce + residual LN ----------
__device__ __forceinline__ float blockReduceSum256(float v, float* red) {
  #pragma unroll
  for (int off = 32; off > 0; off >>= 1) v += __shfl_down(v, off, 64);
  int lane = threadIdx.x & 63, wid = threadIdx.x >> 6;
  __syncthreads();
  if (lane == 0) red[wid] = v;
  __syncthreads();
  return red[0] + red[1] + red[2] + red[3];
}

__global__ __launch_bounds__(256) void add_ln(
    float* __restrict__ x, const float* __restrict__ r,
    const float* __restrict__ g, const float* __restrict__ b)
{
  int row = blockIdx.x;
  int t = threadIdx.x;
  float* xr = x + (size_t)row * D_;
  const float* rr = r + (size_t)row * D_;
  float v0 = xr[t] + rr[t];
  float v1 = xr[t + 256] + rr[t + 256];
  __shared__ float red[4];
  float s = blockReduceSum256(v0 + v1, red);
  float mu = s * (1.0f / 512.0f);
  float d0 = v0 - mu, d1 = v1 - mu;
  float sq = blockReduceSum256(d0 * d0 + d1 * d1, red);
  float rstd = rsqrtf(sq * (1.0f / 512.0f) + 1e-5f);
  xr[t] = d0 * rstd * g[t] + b[t];
  xr[t + 256] = d1 * rstd * g[t + 256] + b[t + 256];
}

static inline void cvt(const float* in, unsigned short* out, size_t n, hipStream_t s) {
  size_t n8 = n / 8;
  int blocks = (int)((n8 + 255) / 256);
  if (blocks > 2048) blocks = 2048;
  cvt_f32_bf16<<<blocks, 256, 0, s>>>(in, out, n8);
}

extern "C" void kernel_launch(void* const* d_in, const int* in_sizes, int n_in,
                              void* d_out, int out_size, void* d_ws, size_t ws_size,
                              hipStream_t stream) {
  const float* q_embed  = (const float*)d_in[0];
  const float* qa_embed = (const float*)d_in[1];
  const float* Wk = (const float*)d_in[2];
  const float* bk = (const float*)d_in[3];
  const float* Wv = (const float*)d_in[4];
  const float* bv = (const float*)d_in[5];
  const float* Wo = (const float*)d_in[6];
  const float* bo = (const float*)d_in[7];
  const float* gammas = (const float*)d_in[8];
  const float* ln1_g = (const float*)d_in[9];
  const float* ln1_b = (const float*)d_in[10];
  const float* W1 = (const float*)d_in[11];
  const float* b1 = (const float*)d_in[12];
  const float* W2 = (const float*)d_in[13];
  const float* b2 = (const float*)d_in[14];
  const float* ln2_g = (const float*)d_in[15];
  const float* ln2_b = (const float*)d_in[16];

  float* x = (float*)d_out;
  const size_t NTOK = (size_t)B_ * S_;      // 16384
  const size_t ND = NTOK * D_;

  float* qkf = (float*)d_ws;                               // f32 scratch [ND]
  unsigned short* xb    = (unsigned short*)(qkf + ND);     // bf16 [ND]
  unsigned short* valsb = xb + ND;
  unsigned short* qkb   = valsb + ND;
  unsigned short* vb    = qkb + ND;
  unsigned short* vtb   = vb + ND;
  unsigned short* aob   = vtb + ND;
  unsigned short* wkb   = aob + ND;
  unsigned short* wvb   = wkb + (size_t)L_ * D_ * D_;
  unsigned short* wob   = wvb + (size_t)L_ * D_ * D_;
  unsigned short* w1b   = wob + (size_t)L_ * D_ * D_;
  unsigned short* w2b   = w1b + (size_t)L_ * DFF_ * D_;
  unsigned short* ffnb  = qkb;   // [NTOK*DFF] aliases qkb+vb+vtb+aob (dead in FFN phase)

  hipMemcpyAsync(x, q_embed, ND * sizeof(float), hipMemcpyDeviceToDevice, stream);

  cvt(Wk, wkb, (size_t)L_ * D_ * D_, stream);
  cvt(Wv, wvb, (size_t)L_ * D_ * D_, stream);
  cvt(Wo, wob, (size_t)L_ * D_ * D_, stream);
  cvt(W1, w1b, (size_t)L_ * DFF_ * D_, stream);
  cvt(W2, w2b, (size_t)L_ * DFF_ * D_, stream);
  cvt(qa_embed, valsb, ND, stream);

  dim3 gproj(D_ / 128, NTOK / 128);
  dim3 gf1(DFF_ / 128, NTOK / 128);
  dim3 gf2(D_ / 128, NTOK / 128);
  dim3 gtr(S_ / 64, H_, B_);
  int gattn = B_ * H_ * (S_ / 16) / 4;   // 2048 blocks, 1 wave per q-tile

  for (int l = 0; l < L_; ++l) {
    int first = (l % 2 == 0);
    cvt(x, xb, ND, stream);
    const unsigned short* vA = first ? valsb : xb;

    gemm_bt_bf16<<<gproj, 256, 0, stream>>>(xb, wkb + (size_t)l * D_ * D_, bk + l * D_,
                                            nullptr, qkb, (int)NTOK, D_, D_, 0);
    gemm_bt_bf16<<<gproj, 256, 0, stream>>>(vA, wvb + (size_t)l * D_ * D_, bv + l * D_,
                                            nullptr, vb, (int)NTOK, D_, D_, 0);
    transpose_heads_bf16<<<gtr, 256, 0, stream>>>(vb, vtb);
    attn_mfma2<<<gattn, 256, 0, stream>>>(qkb, vtb, gammas + l * H_, aob, first ? 0 : 1);
    gemm_bt_bf16<<<gproj, 256, 0, stream>>>(aob, wob + (size_t)l * D_ * D_, bo + l * D_,
                                            qkf, nullptr, (int)NTOK, D_, D_, 0);
    add_ln<<<(int)NTOK, 256, 0, stream>>>(x, qkf, ln1_g + l * D_, ln1_b + l * D_);
    if (first) {
      cvt(x, xb, ND, stream);
      gemm_bt_bf16<<<gf1, 256, 0, stream>>>(xb, w1b + (size_t)l * DFF_ * D_, b1 + l * DFF_,
                                            nullptr, ffnb, (int)NTOK, DFF_, D_, 1);
      gemm_bt_bf16<<<gf2, 256, 0, stream>>>(ffnb, w2b + (size_t)l * D_ * DFF_, b2 + l * D_,
                                            qkf, nullptr, (int)NTOK, D_, DFF_, 0);
      add_ln<<<(int)NTOK, 256, 0, stream>>>(x, qkf, ln2_g + l * D_, ln2_b + l * D_);
    }
  }
}

// Round 9
// 1595.204 us; speedup vs baseline: 8.3283x; 1.3815x over previous
//
#include <hip/hip_runtime.h>
#include <hip/hip_bf16.h>
#include <math.h>

#define B_ 32
#define S_ 512
#define D_ 512
#define H_ 8
#define DK_ 64
#define DFF_ 2048
#define L_ 4

typedef __attribute__((ext_vector_type(8))) short bf16x8;
typedef __attribute__((ext_vector_type(4))) float f32x4;

__device__ __forceinline__ unsigned short f2bf(float x) {
  union { float f; unsigned u; } v; v.f = x;
  unsigned r = v.u + 0x7fff + ((v.u >> 16) & 1);   // round-nearest-even
  return (unsigned short)(r >> 16);
}

__device__ __forceinline__ unsigned short f2h(float x) {
  union { _Float16 h; unsigned short u; } v;
  v.h = (_Float16)x;                 // overflow -> +-inf (RTNE)
  return v.u;
}
__device__ __forceinline__ float h2f(unsigned short u) {
  union { _Float16 h; unsigned short u; } v;
  v.u = u;
  return (float)v.h;
}

__device__ __forceinline__ void load_lds16(const void* g, void* l) {
  __builtin_amdgcn_global_load_lds(
      (const __attribute__((address_space(1))) void*)g,
      (__attribute__((address_space(3))) void*)l, 16, 0, 0);
}

// ---------- f32 -> bf16 convert ----------
__global__ __launch_bounds__(256) void cvt_f32_bf16(
    const float* __restrict__ in, unsigned short* __restrict__ out, size_t n8)
{
  size_t idx = (size_t)blockIdx.x * 256 + threadIdx.x;
  size_t stride = (size_t)gridDim.x * 256;
  for (size_t i = idx; i < n8; i += stride) {
    const float4* p = (const float4*)(in + i * 8);
    float4 a = p[0], b = p[1];
    union { unsigned short u[8]; int4 v; } o;
    o.u[0] = f2bf(a.x); o.u[1] = f2bf(a.y); o.u[2] = f2bf(a.z); o.u[3] = f2bf(a.w);
    o.u[4] = f2bf(b.x); o.u[5] = f2bf(b.y); o.u[6] = f2bf(b.z); o.u[7] = f2bf(b.w);
    *(int4*)(out + i * 8) = o.v;
  }
}

// ---------- bf16 MFMA GEMM: C[M,N] = A[M,K] @ W[N,K]^T + bias ----------
__global__ __launch_bounds__(256) void gemm_bt_bf16(
    const unsigned short* __restrict__ A, const unsigned short* __restrict__ W,
    const float* __restrict__ bias,
    float* __restrict__ Cf, unsigned short* __restrict__ Cb,
    int M, int N, int K, int relu)
{
  __shared__ __align__(16) short As[128 * 32];
  __shared__ __align__(16) short Ws[128 * 32];
  int tid = threadIdx.x;
  int lane = tid & 63, w = tid >> 6;
  int wr = w >> 1, wc = w & 1;
  int bm = blockIdx.y * 128, bn = blockIdx.x * 128;

  f32x4 acc[4][4];
  #pragma unroll
  for (int m = 0; m < 4; ++m)
    #pragma unroll
    for (int n = 0; n < 4; ++n) acc[m][n] = (f32x4){0.f, 0.f, 0.f, 0.f};

  int srow = tid >> 2;
  int skB  = (tid & 3) * 16;
  const char* pa0 = (const char*)(A + (size_t)(bm + srow) * K) + skB;
  const char* pa1 = (const char*)(A + (size_t)(bm + 64 + srow) * K) + skB;
  const char* pw0 = (const char*)(W + (size_t)(bn + srow) * K) + skB;
  const char* pw1 = (const char*)(W + (size_t)(bn + 64 + srow) * K) + skB;
  char* lA0 = (char*)As + w * 1024;
  char* lA1 = (char*)As + 4096 + w * 1024;
  char* lW0 = (char*)Ws + w * 1024;
  char* lW1 = (char*)Ws + 4096 + w * 1024;

  int r = lane & 15, k8 = lane >> 4;
  const bf16x8* Arow = (const bf16x8*)As;
  const bf16x8* Wrow = (const bf16x8*)Ws;

  for (int k0 = 0; k0 < K; k0 += 32) {
    load_lds16(pa0, lA0);
    load_lds16(pa1, lA1);
    load_lds16(pw0, lW0);
    load_lds16(pw1, lW1);
    pa0 += 64; pa1 += 64; pw0 += 64; pw1 += 64;
    __syncthreads();
    bf16x8 aF[4], bF[4];
    #pragma unroll
    for (int m = 0; m < 4; ++m) aF[m] = Arow[(wr * 64 + m * 16 + r) * 4 + k8];
    #pragma unroll
    for (int n = 0; n < 4; ++n) bF[n] = Wrow[(wc * 64 + n * 16 + r) * 4 + k8];
    #pragma unroll
    for (int m = 0; m < 4; ++m)
      #pragma unroll
      for (int n = 0; n < 4; ++n)
        acc[m][n] = __builtin_amdgcn_mfma_f32_16x16x32_bf16(aF[m], bF[n], acc[m][n], 0, 0, 0);
    __syncthreads();
  }

  int orow0 = bm + wr * 64 + (lane >> 4) * 4;
  int ocol0 = bn + wc * 64 + (lane & 15);
  #pragma unroll
  for (int n = 0; n < 4; ++n) {
    int col = ocol0 + n * 16;
    float bv = bias[col];
    #pragma unroll
    for (int m = 0; m < 4; ++m) {
      int row = orow0 + m * 16;
      #pragma unroll
      for (int j = 0; j < 4; ++j) {
        float val = acc[m][n][j] + bv;
        if (relu) val = fmaxf(val, 0.f);
        size_t off = (size_t)(row + j) * N + col;
        if (Cf) Cf[off] = val; else Cb[off] = f2bf(val);
      }
    }
  }
}

// ---------- per-head transpose (bf16): v[b][j][h*64+d] -> vt[b][h][d][j] ----------
__global__ __launch_bounds__(256) void transpose_heads_bf16(
    const unsigned short* __restrict__ v, unsigned short* __restrict__ vt)
{
  __shared__ unsigned short t[64][65];
  int jt = blockIdx.x, h = blockIdx.y, b = blockIdx.z;
  int lane = threadIdx.x & 63, w = threadIdx.x >> 6;
  #pragma unroll
  for (int r = 0; r < 16; ++r) {
    int j = w + r * 4;
    t[j][lane] = v[((size_t)(b * S_ + jt * 64 + j)) * D_ + h * DK_ + lane];
  }
  __syncthreads();
  #pragma unroll
  for (int r = 0; r < 16; ++r) {
    int d = w + r * 4;
    vt[((size_t)((b * H_ + h) * DK_ + d)) * S_ + jt * 64 + lane] = t[lane][d];
  }
}

// ---------- R4/R7-verbatim QK tile: scores scaled + boundary-masked ----------
__device__ __forceinline__ f32x4 qk_tile(
    int kt, int qt, int i0, int g, int c15, int maskType,
    const unsigned short* kbase, bf16x8 aQ0, bf16x8 aQ1)
{
  const unsigned short* kr = kbase + (size_t)(kt * 16 + c15) * D_;
  bf16x8 bK0 = *(const bf16x8*)(kr);
  bf16x8 bK1 = *(const bf16x8*)(kr + 32);
  f32x4 c = (f32x4){0.f, 0.f, 0.f, 0.f};
  c = __builtin_amdgcn_mfma_f32_16x16x32_bf16(aQ0, bK0, c, 0, 0, 0);
  c = __builtin_amdgcn_mfma_f32_16x16x32_bf16(aQ1, bK1, c, 0, 0, 0);
  #pragma unroll
  for (int r = 0; r < 4; ++r) c[r] *= 0.125f;
  if (kt == qt) {
    int j = kt * 16 + c15;
    #pragma unroll
    for (int r = 0; r < 4; ++r) {
      int i = i0 + 4 * g + r;
      bool valid = maskType ? (j <= i) : (j < i);
      if (!valid) c[r] = -1e30f;
    }
  }
  return c;
}

// ---------- MFMA attention: QK once + f16 score cache in LDS, 3 phases ----------
// Phase 1: QK (loads+MFMA), f16 scores -> LDS, running m1.
// Phase 2: sum1 from LDS scores (fixed m1).
// Phase 3: cumsum+decay+rescore from LDS scores; P = exp(s2 - max(m1,0)); PV.
// m2 bound: te = exp(dist * gneg) <= 1 since gneg = -softplus < 0, so
// s2 = cc*te <= max(m1, 0) -- no overflow, sum2 > 0 for any row with a valid j.
__global__ __launch_bounds__(256) void attn_mfma3(
    const unsigned short* __restrict__ qkb,   // q==k bf16 [b][s][D]
    const unsigned short* __restrict__ vtb,   // V^T bf16 [b][h][64][S]
    const float* __restrict__ gammas,
    unsigned short* __restrict__ ao,
    int maskType)
{
  __shared__ __align__(16) unsigned short scr_all[4][512][16];  // f16 scores [wave][j][row]
  __shared__ __align__(16) unsigned short P_all[4][16][48];     // R7-verbatim P scratch
  int tid = threadIdx.x;
  int lane = tid & 63, w = tid >> 6;
  unsigned short (*scr)[16] = scr_all[w];
  unsigned short (*P_lds)[48] = P_all[w];
  int wid = blockIdx.x * 4 + w;
  int qt = wid & 31;                 // q-tile within sequence (S/16 = 32)
  int h = (wid >> 5) & (H_ - 1);
  int b = wid >> 8;
  int i0 = qt * 16;
  int c15 = lane & 15, g = lane >> 4;

  // Q A-frags (R7-verbatim)
  const unsigned short* qbase =
      qkb + ((size_t)(b * S_ + i0 + c15)) * D_ + h * DK_ + g * 8;
  bf16x8 aQ0 = *(const bf16x8*)(qbase);
  bf16x8 aQ1 = *(const bf16x8*)(qbase + 32);
  const unsigned short* kbase = qkb + ((size_t)b * S_) * D_ + h * DK_ + g * 8;

  float gam = gammas[h];
  float gneg = -((gam > 20.f) ? gam : log1pf(__expf(gam)));   // -softplus < 0

  // ---- phase 1: QK once; f16 scores -> LDS; running m1 ----
  float m1[4] = {-1e30f, -1e30f, -1e30f, -1e30f};
  for (int kt = 0; kt <= qt; ++kt) {
    f32x4 c = qk_tile(kt, qt, i0, g, c15, maskType, kbase, aQ0, aQ1);
    int j = kt * 16 + c15;
    int lo = (int)f2h(c[0]) | ((int)f2h(c[1]) << 16);
    int hi = (int)f2h(c[2]) | ((int)f2h(c[3]) << 16);
    *(int2*)&scr[j][4 * g] = make_int2(lo, hi);
    #pragma unroll
    for (int r = 0; r < 4; ++r) m1[r] = fmaxf(m1[r], c[r]);
  }
  #pragma unroll
  for (int r = 0; r < 4; ++r)
    #pragma unroll
    for (int off = 1; off < 16; off <<= 1)
      m1[r] = fmaxf(m1[r], __shfl_xor(m1[r], off, 64));
  asm volatile("s_waitcnt lgkmcnt(0)" ::: "memory");
  __builtin_amdgcn_sched_barrier(0);

  // ---- phase 2: sum1 from LDS scores (fixed m1) ----
  float sum1[4] = {0.f, 0.f, 0.f, 0.f};
  for (int kt = 0; kt <= qt; ++kt) {
    int j = kt * 16 + c15;
    int2 d = *(const int2*)&scr[j][4 * g];
    float s0 = h2f((unsigned short)(d.x & 0xffff));
    float s1 = h2f((unsigned short)((unsigned)d.x >> 16));
    float s2_ = h2f((unsigned short)(d.y & 0xffff));
    float s3 = h2f((unsigned short)((unsigned)d.y >> 16));
    sum1[0] += __expf(s0 - m1[0]);
    sum1[1] += __expf(s1 - m1[1]);
    sum1[2] += __expf(s2_ - m1[2]);
    sum1[3] += __expf(s3 - m1[3]);
  }
  #pragma unroll
  for (int r = 0; r < 4; ++r)
    #pragma unroll
    for (int off = 1; off < 16; off <<= 1)
      sum1[r] += __shfl_xor(sum1[r], off, 64);
  float inv1[4], m2b[4];
  #pragma unroll
  for (int r = 0; r < 4; ++r) {
    inv1[r] = (sum1[r] > 0.f) ? 1.f / sum1[r] : 0.f;
    m2b[r] = fmaxf(m1[r], 0.f);
  }

  // ---- phase 3: cumsum + decay + rescore + P + fused PV (R7-verbatim math) ----
  f32x4 acc[4];
  #pragma unroll
  for (int dt = 0; dt < 4; ++dt) acc[dt] = (f32x4){0.f, 0.f, 0.f, 0.f};
  float sum2[4] = {0.f, 0.f, 0.f, 0.f};
  {
    float carry[4] = {0.f, 0.f, 0.f, 0.f};
    const unsigned short* vbase =
        vtb + (((size_t)(b * H_ + h) * DK_) + c15) * S_ + g * 8;

    #pragma unroll
    for (int jc = 0; jc < 16; ++jc) {
      if (jc * 2 <= qt) {
        #pragma unroll
        for (int t2 = 0; t2 < 2; ++t2) {
          int kt = jc * 2 + t2;
          if (kt <= qt) {
            int j = kt * 16 + c15;
            int2 d = *(const int2*)&scr[j][4 * g];
            float sv[4];
            sv[0] = h2f((unsigned short)(d.x & 0xffff));
            sv[1] = h2f((unsigned short)((unsigned)d.x >> 16));
            sv[2] = h2f((unsigned short)(d.y & 0xffff));
            sv[3] = h2f((unsigned short)((unsigned)d.y >> 16));
            #pragma unroll
            for (int r = 0; r < 4; ++r) {
              float e = __expf(sv[r] - m1[r]);
              float p = e;
              #pragma unroll
              for (int off = 1; off < 16; off <<= 1) {
                float t = __shfl_up(p, off, 16);
                if (c15 >= off) p += t;
              }
              float tot = __shfl(p, lane | 15, 64);
              float cum = carry[r] + p;
              carry[r] += tot;
              float suffix = sum1[r] - cum;
              int i = i0 + 4 * g + r;
              float pos = fabsf((float)(kt * 16 + c15 - i));
              float dist = sqrtf(fmaxf(suffix * inv1[r] * pos, 0.f));
              float te = fminf(fmaxf(__expf(dist * gneg), 1e-5f), 1e5f);
              float s2 = sv[r] * te;
              float e2 = __expf(s2 - m2b[r]);
              sum2[r] += e2;
              P_lds[4 * g + r][t2 * 16 + c15] = f2bf(e2);
            }
          } else {
            #pragma unroll
            for (int r = 0; r < 4; ++r) P_lds[4 * g + r][t2 * 16 + c15] = 0;
          }
        }
        asm volatile("s_waitcnt lgkmcnt(0)" ::: "memory");
        __builtin_amdgcn_sched_barrier(0);
        bf16x8 aP = *(const bf16x8*)&P_lds[c15][g * 8];
        const unsigned short* vr = vbase + (size_t)jc * 32;
        #pragma unroll
        for (int dt = 0; dt < 4; ++dt) {
          bf16x8 bV = *(const bf16x8*)(vr + (size_t)dt * 16 * S_);
          acc[dt] = __builtin_amdgcn_mfma_f32_16x16x32_bf16(aP, bV, acc[dt], 0, 0, 0);
        }
        asm volatile("s_waitcnt lgkmcnt(0)" ::: "memory");
        __builtin_amdgcn_sched_barrier(0);
      }
    }
  }
  #pragma unroll
  for (int r = 0; r < 4; ++r)
    #pragma unroll
    for (int off = 1; off < 16; off <<= 1)
      sum2[r] += __shfl_xor(sum2[r], off, 64);

  // ---- epilogue: normalize (guarded), zeroPad row0, store bf16 ----
  int zp = (maskType == 0 && qt == 0);
  #pragma unroll
  for (int dt = 0; dt < 4; ++dt) {
    #pragma unroll
    for (int r = 0; r < 4; ++r) {
      int i = i0 + 4 * g + r;
      float ns = (sum2[r] > 0.f) ? 1.f / sum2[r] : 0.f;
      float val = acc[dt][r] * ns;
      if (zp && (4 * g + r) == 0) val = 0.f;
      ao[((size_t)(b * S_ + i)) * D_ + h * DK_ + dt * 16 + c15] = f2bf(val);
    }
  }
}

// ---------- wave/block reduce + residual LN ----------
__device__ __forceinline__ float blockReduceSum256(float v, float* red) {
  #pragma unroll
  for (int off = 32; off > 0; off >>= 1) v += __shfl_down(v, off, 64);
  int lane = threadIdx.x & 63, wid = threadIdx.x >> 6;
  __syncthreads();
  if (lane == 0) red[wid] = v;
  __syncthreads();
  return red[0] + red[1] + red[2] + red[3];
}

__global__ __launch_bounds__(256) void add_ln(
    float* __restrict__ x, const float* __restrict__ r,
    const float* __restrict__ g, const float* __restrict__ b)
{
  int row = blockIdx.x;
  int t = threadIdx.x;
  float* xr = x + (size_t)row * D_;
  const float* rr = r + (size_t)row * D_;
  float v0 = xr[t] + rr[t];
  float v1 = xr[t + 256] + rr[t + 256];
  __shared__ float red[4];
  float s = blockReduceSum256(v0 + v1, red);
  float mu = s * (1.0f / 512.0f);
  float d0 = v0 - mu, d1 = v1 - mu;
  float sq = blockReduceSum256(d0 * d0 + d1 * d1, red);
  float rstd = rsqrtf(sq * (1.0f / 512.0f) + 1e-5f);
  xr[t] = d0 * rstd * g[t] + b[t];
  xr[t + 256] = d1 * rstd * g[t + 256] + b[t + 256];
}

static inline void cvt(const float* in, unsigned short* out, size_t n, hipStream_t s) {
  size_t n8 = n / 8;
  int blocks = (int)((n8 + 255) / 256);
  if (blocks > 2048) blocks = 2048;
  cvt_f32_bf16<<<blocks, 256, 0, s>>>(in, out, n8);
}

extern "C" void kernel_launch(void* const* d_in, const int* in_sizes, int n_in,
                              void* d_out, int out_size, void* d_ws, size_t ws_size,
                              hipStream_t stream) {
  const float* q_embed  = (const float*)d_in[0];
  const float* qa_embed = (const float*)d_in[1];
  const float* Wk = (const float*)d_in[2];
  const float* bk = (const float*)d_in[3];
  const float* Wv = (const float*)d_in[4];
  const float* bv = (const float*)d_in[5];
  const float* Wo = (const float*)d_in[6];
  const float* bo = (const float*)d_in[7];
  const float* gammas = (const float*)d_in[8];
  const float* ln1_g = (const float*)d_in[9];
  const float* ln1_b = (const float*)d_in[10];
  const float* W1 = (const float*)d_in[11];
  const float* b1 = (const float*)d_in[12];
  const float* W2 = (const float*)d_in[13];
  const float* b2 = (const float*)d_in[14];
  const float* ln2_g = (const float*)d_in[15];
  const float* ln2_b = (const float*)d_in[16];

  float* x = (float*)d_out;
  const size_t NTOK = (size_t)B_ * S_;      // 16384
  const size_t ND = NTOK * D_;

  float* qkf = (float*)d_ws;                               // f32 scratch [ND]
  unsigned short* xb    = (unsigned short*)(qkf + ND);     // bf16 [ND]
  unsigned short* valsb = xb + ND;
  unsigned short* qkb   = valsb + ND;
  unsigned short* vb    = qkb + ND;
  unsigned short* vtb   = vb + ND;
  unsigned short* aob   = vtb + ND;
  unsigned short* wkb   = aob + ND;
  unsigned short* wvb   = wkb + (size_t)L_ * D_ * D_;
  unsigned short* wob   = wvb + (size_t)L_ * D_ * D_;
  unsigned short* w1b   = wob + (size_t)L_ * D_ * D_;
  unsigned short* w2b   = w1b + (size_t)L_ * DFF_ * D_;
  unsigned short* ffnb  = qkb;   // [NTOK*DFF] aliases qkb+vb+vtb+aob (dead in FFN phase)

  hipMemcpyAsync(x, q_embed, ND * sizeof(float), hipMemcpyDeviceToDevice, stream);

  cvt(Wk, wkb, (size_t)L_ * D_ * D_, stream);
  cvt(Wv, wvb, (size_t)L_ * D_ * D_, stream);
  cvt(Wo, wob, (size_t)L_ * D_ * D_, stream);
  cvt(W1, w1b, (size_t)L_ * DFF_ * D_, stream);
  cvt(W2, w2b, (size_t)L_ * DFF_ * D_, stream);
  cvt(qa_embed, valsb, ND, stream);

  dim3 gproj(D_ / 128, NTOK / 128);
  dim3 gf1(DFF_ / 128, NTOK / 128);
  dim3 gf2(D_ / 128, NTOK / 128);
  dim3 gtr(S_ / 64, H_, B_);
  int gattn = B_ * H_ * (S_ / 16) / 4;   // 2048 blocks, 1 wave per q-tile

  for (int l = 0; l < L_; ++l) {
    int first = (l % 2 == 0);
    cvt(x, xb, ND, stream);
    const unsigned short* vA = first ? valsb : xb;

    gemm_bt_bf16<<<gproj, 256, 0, stream>>>(xb, wkb + (size_t)l * D_ * D_, bk + l * D_,
                                            nullptr, qkb, (int)NTOK, D_, D_, 0);
    gemm_bt_bf16<<<gproj, 256, 0, stream>>>(vA, wvb + (size_t)l * D_ * D_, bv + l * D_,
                                            nullptr, vb, (int)NTOK, D_, D_, 0);
    transpose_heads_bf16<<<gtr, 256, 0, stream>>>(vb, vtb);
    attn_mfma3<<<gattn, 256, 0, stream>>>(qkb, vtb, gammas + l * H_, aob, first ? 0 : 1);
    gemm_bt_bf16<<<gproj, 256, 0, stream>>>(aob, wob + (size_t)l * D_ * D_, bo + l * D_,
                                            qkf, nullptr, (int)NTOK, D_, D_, 0);
    add_ln<<<(int)NTOK, 256, 0, stream>>>(x, qkf, ln1_g + l * D_, ln1_b + l * D_);
    if (first) {
      cvt(x, xb, ND, stream);
      gemm_bt_bf16<<<gf1, 256, 0, stream>>>(xb, w1b + (size_t)l * DFF_ * D_, b1 + l * DFF_,
                                            nullptr, ffnb, (int)NTOK, DFF_, D_, 1);
      gemm_bt_bf16<<<gf2, 256, 0, stream>>>(ffnb, w2b + (size_t)l * D_ * DFF_, b2 + l * D_,
                                            qkf, nullptr, (int)NTOK, D_, DFF_, 0);
      add_ln<<<(int)NTOK, 256, 0, stream>>>(x, qkf, ln2_g + l * D_, ln2_b + l * D_);
    }
  }
}

// Round 10
// 1593.534 us; speedup vs baseline: 8.3370x; 1.0010x over previous
//
#include <hip/hip_runtime.h>
#include <hip/hip_bf16.h>
#include <math.h>

#define B_ 32
#define S_ 512
#define D_ 512
#define H_ 8
#define DK_ 64
#define DFF_ 2048
#define L_ 4

typedef __attribute__((ext_vector_type(8))) short bf16x8;
typedef __attribute__((ext_vector_type(4))) float f32x4;

__device__ __forceinline__ unsigned short f2bf(float x) {
  union { float f; unsigned u; } v; v.f = x;
  unsigned r = v.u + 0x7fff + ((v.u >> 16) & 1);   // round-nearest-even
  return (unsigned short)(r >> 16);
}

__device__ __forceinline__ unsigned short f2h(float x) {
  union { _Float16 h; unsigned short u; } v;
  v.h = (_Float16)x;
  return v.u;
}
__device__ __forceinline__ float h2f(unsigned short u) {
  union { _Float16 h; unsigned short u; } v;
  v.u = u;
  return (float)v.h;
}

__device__ __forceinline__ void load_lds16(const void* g, void* l) {
  __builtin_amdgcn_global_load_lds(
      (const __attribute__((address_space(1))) void*)g,
      (__attribute__((address_space(3))) void*)l, 16, 0, 0);
}

// ---------- f32 -> bf16 convert ----------
__global__ __launch_bounds__(256) void cvt_f32_bf16(
    const float* __restrict__ in, unsigned short* __restrict__ out, size_t n8)
{
  size_t idx = (size_t)blockIdx.x * 256 + threadIdx.x;
  size_t stride = (size_t)gridDim.x * 256;
  for (size_t i = idx; i < n8; i += stride) {
    const float4* p = (const float4*)(in + i * 8);
    float4 a = p[0], b = p[1];
    union { unsigned short u[8]; int4 v; } o;
    o.u[0] = f2bf(a.x); o.u[1] = f2bf(a.y); o.u[2] = f2bf(a.z); o.u[3] = f2bf(a.w);
    o.u[4] = f2bf(b.x); o.u[5] = f2bf(b.y); o.u[6] = f2bf(b.z); o.u[7] = f2bf(b.w);
    *(int4*)(out + i * 8) = o.v;
  }
}

// ---------- copy f32 + emit bf16 ----------
__global__ __launch_bounds__(256) void copy_cvt(
    const float* __restrict__ in, float* __restrict__ outf,
    unsigned short* __restrict__ outb, size_t n8)
{
  size_t idx = (size_t)blockIdx.x * 256 + threadIdx.x;
  size_t stride = (size_t)gridDim.x * 256;
  for (size_t i = idx; i < n8; i += stride) {
    const float4* p = (const float4*)(in + i * 8);
    float4 a = p[0], b = p[1];
    ((float4*)(outf + i * 8))[0] = a;
    ((float4*)(outf + i * 8))[1] = b;
    union { unsigned short u[8]; int4 v; } o;
    o.u[0] = f2bf(a.x); o.u[1] = f2bf(a.y); o.u[2] = f2bf(a.z); o.u[3] = f2bf(a.w);
    o.u[4] = f2bf(b.x); o.u[5] = f2bf(b.y); o.u[6] = f2bf(b.z); o.u[7] = f2bf(b.w);
    *(int4*)(outb + i * 8) = o.v;
  }
}

// ---------- bf16 MFMA GEMM: C[M,N] = A[M,K] @ W[N,K]^T + bias ----------
__global__ __launch_bounds__(256) void gemm_bt_bf16(
    const unsigned short* __restrict__ A, const unsigned short* __restrict__ W,
    const float* __restrict__ bias,
    float* __restrict__ Cf, unsigned short* __restrict__ Cb,
    int M, int N, int K, int relu)
{
  __shared__ __align__(16) short As[128 * 32];
  __shared__ __align__(16) short Ws[128 * 32];
  int tid = threadIdx.x;
  int lane = tid & 63, w = tid >> 6;
  int wr = w >> 1, wc = w & 1;
  int bm = blockIdx.y * 128, bn = blockIdx.x * 128;

  f32x4 acc[4][4];
  #pragma unroll
  for (int m = 0; m < 4; ++m)
    #pragma unroll
    for (int n = 0; n < 4; ++n) acc[m][n] = (f32x4){0.f, 0.f, 0.f, 0.f};

  int srow = tid >> 2;
  int skB  = (tid & 3) * 16;
  const char* pa0 = (const char*)(A + (size_t)(bm + srow) * K) + skB;
  const char* pa1 = (const char*)(A + (size_t)(bm + 64 + srow) * K) + skB;
  const char* pw0 = (const char*)(W + (size_t)(bn + srow) * K) + skB;
  const char* pw1 = (const char*)(W + (size_t)(bn + 64 + srow) * K) + skB;
  char* lA0 = (char*)As + w * 1024;
  char* lA1 = (char*)As + 4096 + w * 1024;
  char* lW0 = (char*)Ws + w * 1024;
  char* lW1 = (char*)Ws + 4096 + w * 1024;

  int r = lane & 15, k8 = lane >> 4;
  const bf16x8* Arow = (const bf16x8*)As;
  const bf16x8* Wrow = (const bf16x8*)Ws;

  for (int k0 = 0; k0 < K; k0 += 32) {
    load_lds16(pa0, lA0);
    load_lds16(pa1, lA1);
    load_lds16(pw0, lW0);
    load_lds16(pw1, lW1);
    pa0 += 64; pa1 += 64; pw0 += 64; pw1 += 64;
    __syncthreads();
    bf16x8 aF[4], bF[4];
    #pragma unroll
    for (int m = 0; m < 4; ++m) aF[m] = Arow[(wr * 64 + m * 16 + r) * 4 + k8];
    #pragma unroll
    for (int n = 0; n < 4; ++n) bF[n] = Wrow[(wc * 64 + n * 16 + r) * 4 + k8];
    #pragma unroll
    for (int m = 0; m < 4; ++m)
      #pragma unroll
      for (int n = 0; n < 4; ++n)
        acc[m][n] = __builtin_amdgcn_mfma_f32_16x16x32_bf16(aF[m], bF[n], acc[m][n], 0, 0, 0);
    __syncthreads();
  }

  int orow0 = bm + wr * 64 + (lane >> 4) * 4;
  int ocol0 = bn + wc * 64 + (lane & 15);
  #pragma unroll
  for (int n = 0; n < 4; ++n) {
    int col = ocol0 + n * 16;
    float bv = bias[col];
    #pragma unroll
    for (int m = 0; m < 4; ++m) {
      int row = orow0 + m * 16;
      #pragma unroll
      for (int j = 0; j < 4; ++j) {
        float val = acc[m][n][j] + bv;
        if (relu) val = fmaxf(val, 0.f);
        size_t off = (size_t)(row + j) * N + col;
        if (Cf) Cf[off] = val; else Cb[off] = f2bf(val);
      }
    }
  }
}

// ---------- per-head transpose (bf16): v[b][j][h*64+d] -> vt[b][h][d][j] ----------
__global__ __launch_bounds__(256) void transpose_heads_bf16(
    const unsigned short* __restrict__ v, unsigned short* __restrict__ vt)
{
  __shared__ unsigned short t[64][65];
  int jt = blockIdx.x, h = blockIdx.y, b = blockIdx.z;
  int lane = threadIdx.x & 63, w = threadIdx.x >> 6;
  #pragma unroll
  for (int r = 0; r < 16; ++r) {
    int j = w + r * 4;
    t[j][lane] = v[((size_t)(b * S_ + jt * 64 + j)) * D_ + h * DK_ + lane];
  }
  __syncthreads();
  #pragma unroll
  for (int r = 0; r < 16; ++r) {
    int d = w + r * 4;
    vt[((size_t)((b * H_ + h) * DK_ + d)) * S_ + jt * 64 + lane] = t[lane][d];
  }
}

// ---------- R4/R7-verbatim QK tile: scores scaled + boundary-masked ----------
__device__ __forceinline__ f32x4 qk_tile(
    int kt, int qt, int i0, int g, int c15, int maskType,
    const unsigned short* kbase, bf16x8 aQ0, bf16x8 aQ1)
{
  const unsigned short* kr = kbase + (size_t)(kt * 16 + c15) * D_;
  bf16x8 bK0 = *(const bf16x8*)(kr);
  bf16x8 bK1 = *(const bf16x8*)(kr + 32);
  f32x4 c = (f32x4){0.f, 0.f, 0.f, 0.f};
  c = __builtin_amdgcn_mfma_f32_16x16x32_bf16(aQ0, bK0, c, 0, 0, 0);
  c = __builtin_amdgcn_mfma_f32_16x16x32_bf16(aQ1, bK1, c, 0, 0, 0);
  #pragma unroll
  for (int r = 0; r < 4; ++r) c[r] *= 0.125f;
  if (kt == qt) {
    int j = kt * 16 + c15;
    #pragma unroll
    for (int r = 0; r < 4; ++r) {
      int i = i0 + 4 * g + r;
      bool valid = maskType ? (j <= i) : (j < i);
      if (!valid) c[r] = -1e30f;
    }
  }
  return c;
}

// ---------- MFMA attention: QK once + f16 score cache, 3 phases, 2 waves/block ----------
__global__ __launch_bounds__(128) void attn_mfma3(
    const unsigned short* __restrict__ qkb,   // q==k bf16 [b][s][D]
    const unsigned short* __restrict__ vtb,   // V^T bf16 [b][h][64][S]
    const float* __restrict__ gammas,
    unsigned short* __restrict__ ao,
    int maskType)
{
  __shared__ __align__(16) unsigned short scr_all[2][512][16];  // f16 scores [wave][j][row]
  __shared__ __align__(16) unsigned short P_all[2][16][48];
  int tid = threadIdx.x;
  int lane = tid & 63, w = tid >> 6;
  unsigned short (*scr)[16] = scr_all[w];
  unsigned short (*P_lds)[48] = P_all[w];
  int wid = blockIdx.x * 2 + w;
  int qt = wid & 31;
  int h = (wid >> 5) & (H_ - 1);
  int b = wid >> 8;
  int i0 = qt * 16;
  int c15 = lane & 15, g = lane >> 4;

  const unsigned short* qbase =
      qkb + ((size_t)(b * S_ + i0 + c15)) * D_ + h * DK_ + g * 8;
  bf16x8 aQ0 = *(const bf16x8*)(qbase);
  bf16x8 aQ1 = *(const bf16x8*)(qbase + 32);
  const unsigned short* kbase = qkb + ((size_t)b * S_) * D_ + h * DK_ + g * 8;

  float gam = gammas[h];
  float gneg = -((gam > 20.f) ? gam : log1pf(__expf(gam)));   // -softplus < 0

  // ---- phase 1: QK once; f16 scores -> LDS; running m1 ----
  float m1[4] = {-1e30f, -1e30f, -1e30f, -1e30f};
  for (int kt = 0; kt <= qt; ++kt) {
    f32x4 c = qk_tile(kt, qt, i0, g, c15, maskType, kbase, aQ0, aQ1);
    int j = kt * 16 + c15;
    int lo = (int)f2h(c[0]) | ((int)f2h(c[1]) << 16);
    int hi = (int)f2h(c[2]) | ((int)f2h(c[3]) << 16);
    *(int2*)&scr[j][4 * g] = make_int2(lo, hi);
    #pragma unroll
    for (int r = 0; r < 4; ++r) m1[r] = fmaxf(m1[r], c[r]);
  }
  #pragma unroll
  for (int r = 0; r < 4; ++r)
    #pragma unroll
    for (int off = 1; off < 16; off <<= 1)
      m1[r] = fmaxf(m1[r], __shfl_xor(m1[r], off, 64));
  asm volatile("s_waitcnt lgkmcnt(0)" ::: "memory");
  __builtin_amdgcn_sched_barrier(0);

  // ---- phase 2: sum1 from LDS scores (fixed m1) ----
  float sum1[4] = {0.f, 0.f, 0.f, 0.f};
  for (int kt = 0; kt <= qt; ++kt) {
    int j = kt * 16 + c15;
    int2 d = *(const int2*)&scr[j][4 * g];
    float s0 = h2f((unsigned short)(d.x & 0xffff));
    float s1 = h2f((unsigned short)((unsigned)d.x >> 16));
    float s2_ = h2f((unsigned short)(d.y & 0xffff));
    float s3 = h2f((unsigned short)((unsigned)d.y >> 16));
    sum1[0] += __expf(s0 - m1[0]);
    sum1[1] += __expf(s1 - m1[1]);
    sum1[2] += __expf(s2_ - m1[2]);
    sum1[3] += __expf(s3 - m1[3]);
  }
  #pragma unroll
  for (int r = 0; r < 4; ++r)
    #pragma unroll
    for (int off = 1; off < 16; off <<= 1)
      sum1[r] += __shfl_xor(sum1[r], off, 64);
  float inv1[4], m2b[4];
  #pragma unroll
  for (int r = 0; r < 4; ++r) {
    inv1[r] = (sum1[r] > 0.f) ? 1.f / sum1[r] : 0.f;
    m2b[r] = fmaxf(m1[r], 0.f);
  }

  // ---- phase 3: cumsum + decay + rescore + P + fused PV ----
  f32x4 acc[4];
  #pragma unroll
  for (int dt = 0; dt < 4; ++dt) acc[dt] = (f32x4){0.f, 0.f, 0.f, 0.f};
  float sum2[4] = {0.f, 0.f, 0.f, 0.f};
  {
    float carry[4] = {0.f, 0.f, 0.f, 0.f};
    const unsigned short* vbase =
        vtb + (((size_t)(b * H_ + h) * DK_) + c15) * S_ + g * 8;

    #pragma unroll
    for (int jc = 0; jc < 16; ++jc) {
      if (jc * 2 <= qt) {
        #pragma unroll
        for (int t2 = 0; t2 < 2; ++t2) {
          int kt = jc * 2 + t2;
          if (kt <= qt) {
            int j = kt * 16 + c15;
            int2 d = *(const int2*)&scr[j][4 * g];
            float sv[4];
            sv[0] = h2f((unsigned short)(d.x & 0xffff));
            sv[1] = h2f((unsigned short)((unsigned)d.x >> 16));
            sv[2] = h2f((unsigned short)(d.y & 0xffff));
            sv[3] = h2f((unsigned short)((unsigned)d.y >> 16));
            #pragma unroll
            for (int r = 0; r < 4; ++r) {
              float e = __expf(sv[r] - m1[r]);
              float p = e;
              #pragma unroll
              for (int off = 1; off < 16; off <<= 1) {
                float t = __shfl_up(p, off, 16);
                if (c15 >= off) p += t;
              }
              float tot = __shfl(p, lane | 15, 64);
              float cum = carry[r] + p;
              carry[r] += tot;
              float suffix = sum1[r] - cum;
              int i = i0 + 4 * g + r;
              float pos = fabsf((float)(kt * 16 + c15 - i));
              float dist = sqrtf(fmaxf(suffix * inv1[r] * pos, 0.f));
              float te = fminf(fmaxf(__expf(dist * gneg), 1e-5f), 1e5f);
              float s2 = sv[r] * te;
              float e2 = __expf(s2 - m2b[r]);
              sum2[r] += e2;
              P_lds[4 * g + r][t2 * 16 + c15] = f2bf(e2);
            }
          } else {
            #pragma unroll
            for (int r = 0; r < 4; ++r) P_lds[4 * g + r][t2 * 16 + c15] = 0;
          }
        }
        asm volatile("s_waitcnt lgkmcnt(0)" ::: "memory");
        __builtin_amdgcn_sched_barrier(0);
        bf16x8 aP = *(const bf16x8*)&P_lds[c15][g * 8];
        const unsigned short* vr = vbase + (size_t)jc * 32;
        #pragma unroll
        for (int dt = 0; dt < 4; ++dt) {
          bf16x8 bV = *(const bf16x8*)(vr + (size_t)dt * 16 * S_);
          acc[dt] = __builtin_amdgcn_mfma_f32_16x16x32_bf16(aP, bV, acc[dt], 0, 0, 0);
        }
        asm volatile("s_waitcnt lgkmcnt(0)" ::: "memory");
        __builtin_amdgcn_sched_barrier(0);
      }
    }
  }
  #pragma unroll
  for (int r = 0; r < 4; ++r)
    #pragma unroll
    for (int off = 1; off < 16; off <<= 1)
      sum2[r] += __shfl_xor(sum2[r], off, 64);

  // ---- epilogue: normalize (guarded), zeroPad row0, store bf16 ----
  int zp = (maskType == 0 && qt == 0);
  #pragma unroll
  for (int dt = 0; dt < 4; ++dt) {
    #pragma unroll
    for (int r = 0; r < 4; ++r) {
      int i = i0 + 4 * g + r;
      float ns = (sum2[r] > 0.f) ? 1.f / sum2[r] : 0.f;
      float val = acc[dt][r] * ns;
      if (zp && (4 * g + r) == 0) val = 0.f;
      ao[((size_t)(b * S_ + i)) * D_ + h * DK_ + dt * 16 + c15] = f2bf(val);
    }
  }
}

// ---------- wave/block reduce + residual LN (also emits bf16 x) ----------
__device__ __forceinline__ float blockReduceSum256(float v, float* red) {
  #pragma unroll
  for (int off = 32; off > 0; off >>= 1) v += __shfl_down(v, off, 64);
  int lane = threadIdx.x & 63, wid = threadIdx.x >> 6;
  __syncthreads();
  if (lane == 0) red[wid] = v;
  __syncthreads();
  return red[0] + red[1] + red[2] + red[3];
}

__global__ __launch_bounds__(256) void add_ln(
    float* __restrict__ x, unsigned short* __restrict__ xb,
    const float* __restrict__ r,
    const float* __restrict__ g, const float* __restrict__ b)
{
  int row = blockIdx.x;
  int t = threadIdx.x;
  float* xr = x + (size_t)row * D_;
  unsigned short* xbr = xb + (size_t)row * D_;
  const float* rr = r + (size_t)row * D_;
  float v0 = xr[t] + rr[t];
  float v1 = xr[t + 256] + rr[t + 256];
  __shared__ float red[4];
  float s = blockReduceSum256(v0 + v1, red);
  float mu = s * (1.0f / 512.0f);
  float d0 = v0 - mu, d1 = v1 - mu;
  float sq = blockReduceSum256(d0 * d0 + d1 * d1, red);
  float rstd = rsqrtf(sq * (1.0f / 512.0f) + 1e-5f);
  float o0 = d0 * rstd * g[t] + b[t];
  float o1 = d1 * rstd * g[t + 256] + b[t + 256];
  xr[t] = o0;
  xr[t + 256] = o1;
  xbr[t] = f2bf(o0);
  xbr[t + 256] = f2bf(o1);
}

static inline void cvt(const float* in, unsigned short* out, size_t n, hipStream_t s) {
  size_t n8 = n / 8;
  int blocks = (int)((n8 + 255) / 256);
  if (blocks > 2048) blocks = 2048;
  cvt_f32_bf16<<<blocks, 256, 0, s>>>(in, out, n8);
}

extern "C" void kernel_launch(void* const* d_in, const int* in_sizes, int n_in,
                              void* d_out, int out_size, void* d_ws, size_t ws_size,
                              hipStream_t stream) {
  const float* q_embed  = (const float*)d_in[0];
  const float* qa_embed = (const float*)d_in[1];
  const float* Wk = (const float*)d_in[2];
  const float* bk = (const float*)d_in[3];
  const float* Wv = (const float*)d_in[4];
  const float* bv = (const float*)d_in[5];
  const float* Wo = (const float*)d_in[6];
  const float* bo = (const float*)d_in[7];
  const float* gammas = (const float*)d_in[8];
  const float* ln1_g = (const float*)d_in[9];
  const float* ln1_b = (const float*)d_in[10];
  const float* W1 = (const float*)d_in[11];
  const float* b1 = (const float*)d_in[12];
  const float* W2 = (const float*)d_in[13];
  const float* b2 = (const float*)d_in[14];
  const float* ln2_g = (const float*)d_in[15];
  const float* ln2_b = (const float*)d_in[16];

  float* x = (float*)d_out;
  const size_t NTOK = (size_t)B_ * S_;      // 16384
  const size_t ND = NTOK * D_;

  float* qkf = (float*)d_ws;                               // f32 scratch [ND]
  unsigned short* xb    = (unsigned short*)(qkf + ND);     // bf16 [ND]
  unsigned short* valsb = xb + ND;
  unsigned short* qkb   = valsb + ND;
  unsigned short* vb    = qkb + ND;
  unsigned short* vtb   = vb + ND;
  unsigned short* aob   = vtb + ND;
  unsigned short* wkb   = aob + ND;
  unsigned short* wvb   = wkb + (size_t)L_ * D_ * D_;
  unsigned short* wob   = wvb + (size_t)L_ * D_ * D_;
  unsigned short* w1b   = wob + (size_t)L_ * D_ * D_;
  unsigned short* w2b   = w1b + (size_t)L_ * DFF_ * D_;
  unsigned short* ffnb  = qkb;   // [NTOK*DFF] aliases qkb+vb+vtb+aob (dead in FFN phase)

  // x (f32) + xb (bf16) from q_embed in one pass
  {
    size_t n8 = ND / 8;
    copy_cvt<<<2048, 256, 0, stream>>>(q_embed, x, xb, n8);
  }

  cvt(Wk, wkb, (size_t)L_ * D_ * D_, stream);
  cvt(Wv, wvb, (size_t)L_ * D_ * D_, stream);
  cvt(Wo, wob, (size_t)L_ * D_ * D_, stream);
  cvt(W1, w1b, (size_t)L_ * DFF_ * D_, stream);
  cvt(W2, w2b, (size_t)L_ * DFF_ * D_, stream);
  cvt(qa_embed, valsb, ND, stream);

  dim3 gproj(D_ / 128, NTOK / 128);
  dim3 gf1(DFF_ / 128, NTOK / 128);
  dim3 gf2(D_ / 128, NTOK / 128);
  dim3 gtr(S_ / 64, H_, B_);
  int gattn = B_ * H_ * (S_ / 16) / 2;   // 4096 blocks, 2 waves/block

  for (int l = 0; l < L_; ++l) {
    int first = (l % 2 == 0);
    const unsigned short* vA = first ? valsb : xb;

    gemm_bt_bf16<<<gproj, 256, 0, stream>>>(xb, wkb + (size_t)l * D_ * D_, bk + l * D_,
                                            nullptr, qkb, (int)NTOK, D_, D_, 0);
    gemm_bt_bf16<<<gproj, 256, 0, stream>>>(vA, wvb + (size_t)l * D_ * D_, bv + l * D_,
                                            nullptr, vb, (int)NTOK, D_, D_, 0);
    transpose_heads_bf16<<<gtr, 256, 0, stream>>>(vb, vtb);
    attn_mfma3<<<gattn, 128, 0, stream>>>(qkb, vtb, gammas + l * H_, aob, first ? 0 : 1);
    gemm_bt_bf16<<<gproj, 256, 0, stream>>>(aob, wob + (size_t)l * D_ * D_, bo + l * D_,
                                            qkf, nullptr, (int)NTOK, D_, D_, 0);
    add_ln<<<(int)NTOK, 256, 0, stream>>>(x, xb, qkf, ln1_g + l * D_, ln1_b + l * D_);
    if (first) {
      gemm_bt_bf16<<<gf1, 256, 0, stream>>>(xb, w1b + (size_t)l * DFF_ * D_, b1 + l * DFF_,
                                            nullptr, ffnb, (int)NTOK, DFF_, D_, 1);
      gemm_bt_bf16<<<gf2, 256, 0, stream>>>(ffnb, w2b + (size_t)l * D_ * DFF_, b2 + l * D_,
                                            qkf, nullptr, (int)NTOK, D_, DFF_, 0);
      add_ln<<<(int)NTOK, 256, 0, stream>>>(x, xb, qkf, ln2_g + l * D_, ln2_b + l * D_);
    }
  }
}

// Round 11
// 1209.523 us; speedup vs baseline: 10.9840x; 1.3175x over previous
//
#include <hip/hip_runtime.h>
#include <hip/hip_bf16.h>
#include <math.h>

#define B_ 32
#define S_ 512
#define D_ 512
#define H_ 8
#define DK_ 64
#define DFF_ 2048
#define L_ 4

typedef __attribute__((ext_vector_type(8))) short bf16x8;
typedef __attribute__((ext_vector_type(4))) float f32x4;

__device__ __forceinline__ unsigned short f2bf(float x) {
  union { float f; unsigned u; } v; v.f = x;
  unsigned r = v.u + 0x7fff + ((v.u >> 16) & 1);   // round-nearest-even
  return (unsigned short)(r >> 16);
}

__device__ __forceinline__ unsigned short f2h(float x) {
  union { _Float16 h; unsigned short u; } v;
  v.h = (_Float16)x;
  return v.u;
}
__device__ __forceinline__ float h2f(unsigned short u) {
  union { _Float16 h; unsigned short u; } v;
  v.u = u;
  return (float)v.h;
}

__device__ __forceinline__ void load_lds16(const void* g, void* l) {
  __builtin_amdgcn_global_load_lds(
      (const __attribute__((address_space(1))) void*)g,
      (__attribute__((address_space(3))) void*)l, 16, 0, 0);
}

// ---------- f32 -> bf16 convert ----------
__global__ __launch_bounds__(256) void cvt_f32_bf16(
    const float* __restrict__ in, unsigned short* __restrict__ out, size_t n8)
{
  size_t idx = (size_t)blockIdx.x * 256 + threadIdx.x;
  size_t stride = (size_t)gridDim.x * 256;
  for (size_t i = idx; i < n8; i += stride) {
    const float4* p = (const float4*)(in + i * 8);
    float4 a = p[0], b = p[1];
    union { unsigned short u[8]; int4 v; } o;
    o.u[0] = f2bf(a.x); o.u[1] = f2bf(a.y); o.u[2] = f2bf(a.z); o.u[3] = f2bf(a.w);
    o.u[4] = f2bf(b.x); o.u[5] = f2bf(b.y); o.u[6] = f2bf(b.z); o.u[7] = f2bf(b.w);
    *(int4*)(out + i * 8) = o.v;
  }
}

// ---------- copy f32 + emit bf16 ----------
__global__ __launch_bounds__(256) void copy_cvt(
    const float* __restrict__ in, float* __restrict__ outf,
    unsigned short* __restrict__ outb, size_t n8)
{
  size_t idx = (size_t)blockIdx.x * 256 + threadIdx.x;
  size_t stride = (size_t)gridDim.x * 256;
  for (size_t i = idx; i < n8; i += stride) {
    const float4* p = (const float4*)(in + i * 8);
    float4 a = p[0], b = p[1];
    ((float4*)(outf + i * 8))[0] = a;
    ((float4*)(outf + i * 8))[1] = b;
    union { unsigned short u[8]; int4 v; } o;
    o.u[0] = f2bf(a.x); o.u[1] = f2bf(a.y); o.u[2] = f2bf(a.z); o.u[3] = f2bf(a.w);
    o.u[4] = f2bf(b.x); o.u[5] = f2bf(b.y); o.u[6] = f2bf(b.z); o.u[7] = f2bf(b.w);
    *(int4*)(outb + i * 8) = o.v;
  }
}

// ---------- bf16 MFMA GEMM: C[M,N] = A[M,K] @ W[N,K]^T + bias ----------
__global__ __launch_bounds__(256) void gemm_bt_bf16(
    const unsigned short* __restrict__ A, const unsigned short* __restrict__ W,
    const float* __restrict__ bias,
    float* __restrict__ Cf, unsigned short* __restrict__ Cb,
    int M, int N, int K, int relu)
{
  __shared__ __align__(16) short As[128 * 32];
  __shared__ __align__(16) short Ws[128 * 32];
  int tid = threadIdx.x;
  int lane = tid & 63, w = tid >> 6;
  int wr = w >> 1, wc = w & 1;
  int bm = blockIdx.y * 128, bn = blockIdx.x * 128;

  f32x4 acc[4][4];
  #pragma unroll
  for (int m = 0; m < 4; ++m)
    #pragma unroll
    for (int n = 0; n < 4; ++n) acc[m][n] = (f32x4){0.f, 0.f, 0.f, 0.f};

  int srow = tid >> 2;
  int skB  = (tid & 3) * 16;
  const char* pa0 = (const char*)(A + (size_t)(bm + srow) * K) + skB;
  const char* pa1 = (const char*)(A + (size_t)(bm + 64 + srow) * K) + skB;
  const char* pw0 = (const char*)(W + (size_t)(bn + srow) * K) + skB;
  const char* pw1 = (const char*)(W + (size_t)(bn + 64 + srow) * K) + skB;
  char* lA0 = (char*)As + w * 1024;
  char* lA1 = (char*)As + 4096 + w * 1024;
  char* lW0 = (char*)Ws + w * 1024;
  char* lW1 = (char*)Ws + 4096 + w * 1024;

  int r = lane & 15, k8 = lane >> 4;
  const bf16x8* Arow = (const bf16x8*)As;
  const bf16x8* Wrow = (const bf16x8*)Ws;

  for (int k0 = 0; k0 < K; k0 += 32) {
    load_lds16(pa0, lA0);
    load_lds16(pa1, lA1);
    load_lds16(pw0, lW0);
    load_lds16(pw1, lW1);
    pa0 += 64; pa1 += 64; pw0 += 64; pw1 += 64;
    __syncthreads();
    bf16x8 aF[4], bF[4];
    #pragma unroll
    for (int m = 0; m < 4; ++m) aF[m] = Arow[(wr * 64 + m * 16 + r) * 4 + k8];
    #pragma unroll
    for (int n = 0; n < 4; ++n) bF[n] = Wrow[(wc * 64 + n * 16 + r) * 4 + k8];
    #pragma unroll
    for (int m = 0; m < 4; ++m)
      #pragma unroll
      for (int n = 0; n < 4; ++n)
        acc[m][n] = __builtin_amdgcn_mfma_f32_16x16x32_bf16(aF[m], bF[n], acc[m][n], 0, 0, 0);
    __syncthreads();
  }

  int orow0 = bm + wr * 64 + (lane >> 4) * 4;
  int ocol0 = bn + wc * 64 + (lane & 15);
  #pragma unroll
  for (int n = 0; n < 4; ++n) {
    int col = ocol0 + n * 16;
    float bv = bias[col];
    #pragma unroll
    for (int m = 0; m < 4; ++m) {
      int row = orow0 + m * 16;
      #pragma unroll
      for (int j = 0; j < 4; ++j) {
        float val = acc[m][n][j] + bv;
        if (relu) val = fmaxf(val, 0.f);
        size_t off = (size_t)(row + j) * N + col;
        if (Cf) Cf[off] = val; else Cb[off] = f2bf(val);
      }
    }
  }
}

// ---------- per-head transpose (bf16): v[b][j][h*64+d] -> vt[b][h][d][j] ----------
__global__ __launch_bounds__(256) void transpose_heads_bf16(
    const unsigned short* __restrict__ v, unsigned short* __restrict__ vt)
{
  __shared__ unsigned short t[64][65];
  int jt = blockIdx.x, h = blockIdx.y, b = blockIdx.z;
  int lane = threadIdx.x & 63, w = threadIdx.x >> 6;
  #pragma unroll
  for (int r = 0; r < 16; ++r) {
    int j = w + r * 4;
    t[j][lane] = v[((size_t)(b * S_ + jt * 64 + j)) * D_ + h * DK_ + lane];
  }
  __syncthreads();
  #pragma unroll
  for (int r = 0; r < 16; ++r) {
    int d = w + r * 4;
    vt[((size_t)((b * H_ + h) * DK_ + d)) * S_ + jt * 64 + lane] = t[lane][d];
  }
}

// ---------- R4/R7-verbatim QK tile: scores scaled + boundary-masked ----------
__device__ __forceinline__ f32x4 qk_tile(
    int kt, int qt, int i0, int g, int c15, int maskType,
    const unsigned short* kbase, bf16x8 aQ0, bf16x8 aQ1)
{
  const unsigned short* kr = kbase + (size_t)(kt * 16 + c15) * D_;
  bf16x8 bK0 = *(const bf16x8*)(kr);
  bf16x8 bK1 = *(const bf16x8*)(kr + 32);
  f32x4 c = (f32x4){0.f, 0.f, 0.f, 0.f};
  c = __builtin_amdgcn_mfma_f32_16x16x32_bf16(aQ0, bK0, c, 0, 0, 0);
  c = __builtin_amdgcn_mfma_f32_16x16x32_bf16(aQ1, bK1, c, 0, 0, 0);
  #pragma unroll
  for (int r = 0; r < 4; ++r) c[r] *= 0.125f;
  if (kt == qt) {
    int j = kt * 16 + c15;
    #pragma unroll
    for (int r = 0; r < 4; ++r) {
      int i = i0 + 4 * g + r;
      bool valid = maskType ? (j <= i) : (j < i);
      if (!valid) c[r] = -1e30f;
    }
  }
  return c;
}

// ---------- MFMA attention: complementary q-tile pairing, shared score cache ----------
// Block = 2 waves: wave0 qt=p, wave1 qt=31-p. Valid score rows total 33*16 =
// constant -> fixed 16.9KB cache per block, uniform work per block (no tail).
__global__ __launch_bounds__(128) void attn_mfma3(
    const unsigned short* __restrict__ qkb,   // q==k bf16 [b][s][D]
    const unsigned short* __restrict__ vtb,   // V^T bf16 [b][h][64][S]
    const float* __restrict__ gammas,
    unsigned short* __restrict__ ao,
    int maskType)
{
  __shared__ __align__(16) unsigned short scr_all[33 * 16][16];  // f16 scores, split by wave
  __shared__ __align__(16) unsigned short P_all[2][16][48];
  int tid = threadIdx.x;
  int lane = tid & 63, w = tid >> 6;
  int bid = blockIdx.x;
  int p = bid & 15;
  int h = (bid >> 4) & (H_ - 1);
  int b = bid >> 7;
  int qt = w ? (31 - p) : p;                    // complementary pair
  int rowbase = w ? (p + 1) * 16 : 0;           // wave's scr region offset
  unsigned short (*scr)[16] = &scr_all[rowbase];
  unsigned short (*P_lds)[48] = P_all[w];
  int i0 = qt * 16;
  int c15 = lane & 15, g = lane >> 4;

  const unsigned short* qbase =
      qkb + ((size_t)(b * S_ + i0 + c15)) * D_ + h * DK_ + g * 8;
  bf16x8 aQ0 = *(const bf16x8*)(qbase);
  bf16x8 aQ1 = *(const bf16x8*)(qbase + 32);
  const unsigned short* kbase = qkb + ((size_t)b * S_) * D_ + h * DK_ + g * 8;

  float gam = gammas[h];
  float gneg = -((gam > 20.f) ? gam : log1pf(__expf(gam)));   // -softplus < 0

  // ---- phase 1: QK once; f16 scores -> LDS; running m1 ----
  float m1[4] = {-1e30f, -1e30f, -1e30f, -1e30f};
  for (int kt = 0; kt <= qt; ++kt) {
    f32x4 c = qk_tile(kt, qt, i0, g, c15, maskType, kbase, aQ0, aQ1);
    int j = kt * 16 + c15;
    int lo = (int)f2h(c[0]) | ((int)f2h(c[1]) << 16);
    int hi = (int)f2h(c[2]) | ((int)f2h(c[3]) << 16);
    *(int2*)&scr[j][4 * g] = make_int2(lo, hi);
    #pragma unroll
    for (int r = 0; r < 4; ++r) m1[r] = fmaxf(m1[r], c[r]);
  }
  #pragma unroll
  for (int r = 0; r < 4; ++r)
    #pragma unroll
    for (int off = 1; off < 16; off <<= 1)
      m1[r] = fmaxf(m1[r], __shfl_xor(m1[r], off, 64));
  asm volatile("s_waitcnt lgkmcnt(0)" ::: "memory");
  __builtin_amdgcn_sched_barrier(0);

  // ---- phase 2: sum1 from LDS scores (fixed m1) ----
  float sum1[4] = {0.f, 0.f, 0.f, 0.f};
  for (int kt = 0; kt <= qt; ++kt) {
    int j = kt * 16 + c15;
    int2 d = *(const int2*)&scr[j][4 * g];
    float s0 = h2f((unsigned short)(d.x & 0xffff));
    float s1 = h2f((unsigned short)((unsigned)d.x >> 16));
    float s2_ = h2f((unsigned short)(d.y & 0xffff));
    float s3 = h2f((unsigned short)((unsigned)d.y >> 16));
    sum1[0] += __expf(s0 - m1[0]);
    sum1[1] += __expf(s1 - m1[1]);
    sum1[2] += __expf(s2_ - m1[2]);
    sum1[3] += __expf(s3 - m1[3]);
  }
  #pragma unroll
  for (int r = 0; r < 4; ++r)
    #pragma unroll
    for (int off = 1; off < 16; off <<= 1)
      sum1[r] += __shfl_xor(sum1[r], off, 64);
  float inv1[4], m2b[4];
  #pragma unroll
  for (int r = 0; r < 4; ++r) {
    inv1[r] = (sum1[r] > 0.f) ? 1.f / sum1[r] : 0.f;
    m2b[r] = fmaxf(m1[r], 0.f);
  }

  // ---- phase 3: cumsum + decay + rescore + P + fused PV ----
  f32x4 acc[4];
  #pragma unroll
  for (int dt = 0; dt < 4; ++dt) acc[dt] = (f32x4){0.f, 0.f, 0.f, 0.f};
  float sum2[4] = {0.f, 0.f, 0.f, 0.f};
  {
    float carry[4] = {0.f, 0.f, 0.f, 0.f};
    const unsigned short* vbase =
        vtb + (((size_t)(b * H_ + h) * DK_) + c15) * S_ + g * 8;

    #pragma unroll
    for (int jc = 0; jc < 16; ++jc) {
      if (jc * 2 <= qt) {
        #pragma unroll
        for (int t2 = 0; t2 < 2; ++t2) {
          int kt = jc * 2 + t2;
          if (kt <= qt) {
            int j = kt * 16 + c15;
            int2 d = *(const int2*)&scr[j][4 * g];
            float sv[4];
            sv[0] = h2f((unsigned short)(d.x & 0xffff));
            sv[1] = h2f((unsigned short)((unsigned)d.x >> 16));
            sv[2] = h2f((unsigned short)(d.y & 0xffff));
            sv[3] = h2f((unsigned short)((unsigned)d.y >> 16));
            #pragma unroll
            for (int r = 0; r < 4; ++r) {
              float e = __expf(sv[r] - m1[r]);
              float p2 = e;
              #pragma unroll
              for (int off = 1; off < 16; off <<= 1) {
                float t = __shfl_up(p2, off, 16);
                if (c15 >= off) p2 += t;
              }
              float tot = __shfl(p2, lane | 15, 64);
              float cum = carry[r] + p2;
              carry[r] += tot;
              float suffix = sum1[r] - cum;
              int i = i0 + 4 * g + r;
              float pos = fabsf((float)(kt * 16 + c15 - i));
              float dist = sqrtf(fmaxf(suffix * inv1[r] * pos, 0.f));
              float te = fminf(fmaxf(__expf(dist * gneg), 1e-5f), 1e5f);
              float s2 = sv[r] * te;
              float e2 = __expf(s2 - m2b[r]);
              sum2[r] += e2;
              P_lds[4 * g + r][t2 * 16 + c15] = f2bf(e2);
            }
          } else {
            #pragma unroll
            for (int r = 0; r < 4; ++r) P_lds[4 * g + r][t2 * 16 + c15] = 0;
          }
        }
        asm volatile("s_waitcnt lgkmcnt(0)" ::: "memory");
        __builtin_amdgcn_sched_barrier(0);
        bf16x8 aP = *(const bf16x8*)&P_lds[c15][g * 8];
        const unsigned short* vr = vbase + (size_t)jc * 32;
        #pragma unroll
        for (int dt = 0; dt < 4; ++dt) {
          bf16x8 bV = *(const bf16x8*)(vr + (size_t)dt * 16 * S_);
          acc[dt] = __builtin_amdgcn_mfma_f32_16x16x32_bf16(aP, bV, acc[dt], 0, 0, 0);
        }
        asm volatile("s_waitcnt lgkmcnt(0)" ::: "memory");
        __builtin_amdgcn_sched_barrier(0);
      }
    }
  }
  #pragma unroll
  for (int r = 0; r < 4; ++r)
    #pragma unroll
    for (int off = 1; off < 16; off <<= 1)
      sum2[r] += __shfl_xor(sum2[r], off, 64);

  // ---- epilogue: normalize (guarded), zeroPad row0, store bf16 ----
  int zp = (maskType == 0 && qt == 0);
  #pragma unroll
  for (int dt = 0; dt < 4; ++dt) {
    #pragma unroll
    for (int r = 0; r < 4; ++r) {
      int i = i0 + 4 * g + r;
      float ns = (sum2[r] > 0.f) ? 1.f / sum2[r] : 0.f;
      float val = acc[dt][r] * ns;
      if (zp && (4 * g + r) == 0) val = 0.f;
      ao[((size_t)(b * S_ + i)) * D_ + h * DK_ + dt * 16 + c15] = f2bf(val);
    }
  }
}

// ---------- wave/block reduce + residual LN (also emits bf16 x) ----------
__device__ __forceinline__ float blockReduceSum256(float v, float* red) {
  #pragma unroll
  for (int off = 32; off > 0; off >>= 1) v += __shfl_down(v, off, 64);
  int lane = threadIdx.x & 63, wid = threadIdx.x >> 6;
  __syncthreads();
  if (lane == 0) red[wid] = v;
  __syncthreads();
  return red[0] + red[1] + red[2] + red[3];
}

__global__ __launch_bounds__(256) void add_ln(
    float* __restrict__ x, unsigned short* __restrict__ xb,
    const float* __restrict__ r,
    const float* __restrict__ g, const float* __restrict__ b)
{
  int row = blockIdx.x;
  int t = threadIdx.x;
  float* xr = x + (size_t)row * D_;
  unsigned short* xbr = xb + (size_t)row * D_;
  const float* rr = r + (size_t)row * D_;
  float v0 = xr[t] + rr[t];
  float v1 = xr[t + 256] + rr[t + 256];
  __shared__ float red[4];
  float s = blockReduceSum256(v0 + v1, red);
  float mu = s * (1.0f / 512.0f);
  float d0 = v0 - mu, d1 = v1 - mu;
  float sq = blockReduceSum256(d0 * d0 + d1 * d1, red);
  float rstd = rsqrtf(sq * (1.0f / 512.0f) + 1e-5f);
  float o0 = d0 * rstd * g[t] + b[t];
  float o1 = d1 * rstd * g[t + 256] + b[t + 256];
  xr[t] = o0;
  xr[t + 256] = o1;
  xbr[t] = f2bf(o0);
  xbr[t + 256] = f2bf(o1);
}

static inline void cvt(const float* in, unsigned short* out, size_t n, hipStream_t s) {
  size_t n8 = n / 8;
  int blocks = (int)((n8 + 255) / 256);
  if (blocks > 2048) blocks = 2048;
  cvt_f32_bf16<<<blocks, 256, 0, s>>>(in, out, n8);
}

extern "C" void kernel_launch(void* const* d_in, const int* in_sizes, int n_in,
                              void* d_out, int out_size, void* d_ws, size_t ws_size,
                              hipStream_t stream) {
  const float* q_embed  = (const float*)d_in[0];
  const float* qa_embed = (const float*)d_in[1];
  const float* Wk = (const float*)d_in[2];
  const float* bk = (const float*)d_in[3];
  const float* Wv = (const float*)d_in[4];
  const float* bv = (const float*)d_in[5];
  const float* Wo = (const float*)d_in[6];
  const float* bo = (const float*)d_in[7];
  const float* gammas = (const float*)d_in[8];
  const float* ln1_g = (const float*)d_in[9];
  const float* ln1_b = (const float*)d_in[10];
  const float* W1 = (const float*)d_in[11];
  const float* b1 = (const float*)d_in[12];
  const float* W2 = (const float*)d_in[13];
  const float* b2 = (const float*)d_in[14];
  const float* ln2_g = (const float*)d_in[15];
  const float* ln2_b = (const float*)d_in[16];

  float* x = (float*)d_out;
  const size_t NTOK = (size_t)B_ * S_;      // 16384
  const size_t ND = NTOK * D_;

  float* qkf = (float*)d_ws;                               // f32 scratch [ND]
  unsigned short* xb    = (unsigned short*)(qkf + ND);     // bf16 [ND]
  unsigned short* valsb = xb + ND;
  unsigned short* qkb   = valsb + ND;
  unsigned short* vb    = qkb + ND;
  unsigned short* vtb   = vb + ND;
  unsigned short* aob   = vtb + ND;
  unsigned short* wkb   = aob + ND;
  unsigned short* wvb   = wkb + (size_t)L_ * D_ * D_;
  unsigned short* wob   = wvb + (size_t)L_ * D_ * D_;
  unsigned short* w1b   = wob + (size_t)L_ * D_ * D_;
  unsigned short* w2b   = w1b + (size_t)L_ * DFF_ * D_;
  unsigned short* ffnb  = qkb;   // [NTOK*DFF] aliases qkb+vb+vtb+aob (dead in FFN phase)

  // x (f32) + xb (bf16) from q_embed in one pass
  {
    size_t n8 = ND / 8;
    copy_cvt<<<2048, 256, 0, stream>>>(q_embed, x, xb, n8);
  }

  cvt(Wk, wkb, (size_t)L_ * D_ * D_, stream);
  cvt(Wv, wvb, (size_t)L_ * D_ * D_, stream);
  cvt(Wo, wob, (size_t)L_ * D_ * D_, stream);
  cvt(W1, w1b, (size_t)L_ * DFF_ * D_, stream);
  cvt(W2, w2b, (size_t)L_ * DFF_ * D_, stream);
  cvt(qa_embed, valsb, ND, stream);

  dim3 gproj(D_ / 128, NTOK / 128);
  dim3 gf1(DFF_ / 128, NTOK / 128);
  dim3 gf2(D_ / 128, NTOK / 128);
  dim3 gtr(S_ / 64, H_, B_);
  int gattn = B_ * H_ * 16;   // 4096 blocks, 2 complementary q-tiles each

  for (int l = 0; l < L_; ++l) {
    int first = (l % 2 == 0);
    const unsigned short* vA = first ? valsb : xb;

    gemm_bt_bf16<<<gproj, 256, 0, stream>>>(xb, wkb + (size_t)l * D_ * D_, bk + l * D_,
                                            nullptr, qkb, (int)NTOK, D_, D_, 0);
    gemm_bt_bf16<<<gproj, 256, 0, stream>>>(vA, wvb + (size_t)l * D_ * D_, bv + l * D_,
                                            nullptr, vb, (int)NTOK, D_, D_, 0);
    transpose_heads_bf16<<<gtr, 256, 0, stream>>>(vb, vtb);
    attn_mfma3<<<gattn, 128, 0, stream>>>(qkb, vtb, gammas + l * H_, aob, first ? 0 : 1);
    gemm_bt_bf16<<<gproj, 256, 0, stream>>>(aob, wob + (size_t)l * D_ * D_, bo + l * D_,
                                            qkf, nullptr, (int)NTOK, D_, D_, 0);
    add_ln<<<(int)NTOK, 256, 0, stream>>>(x, xb, qkf, ln1_g + l * D_, ln1_b + l * D_);
    if (first) {
      gemm_bt_bf16<<<gf1, 256, 0, stream>>>(xb, w1b + (size_t)l * DFF_ * D_, b1 + l * DFF_,
                                            nullptr, ffnb, (int)NTOK, DFF_, D_, 1);
      gemm_bt_bf16<<<gf2, 256, 0, stream>>>(ffnb, w2b + (size_t)l * D_ * DFF_, b2 + l * D_,
                                            qkf, nullptr, (int)NTOK, D_, DFF_, 0);
      add_ln<<<(int)NTOK, 256, 0, stream>>>(x, xb, qkf, ln2_g + l * D_, ln2_b + l * D_);
    }
  }
}

// Round 12
// 1183.645 us; speedup vs baseline: 11.2241x; 1.0219x over previous
//
#include <hip/hip_runtime.h>
#include <hip/hip_bf16.h>
#include <math.h>

#define B_ 32
#define S_ 512
#define D_ 512
#define H_ 8
#define DK_ 64
#define DFF_ 2048
#define L_ 4

typedef __attribute__((ext_vector_type(8))) short bf16x8;
typedef __attribute__((ext_vector_type(4))) float f32x4;

__device__ __forceinline__ unsigned short f2bf(float x) {
  union { float f; unsigned u; } v; v.f = x;
  unsigned r = v.u + 0x7fff + ((v.u >> 16) & 1);   // round-nearest-even
  return (unsigned short)(r >> 16);
}

__device__ __forceinline__ unsigned short f2h(float x) {
  union { _Float16 h; unsigned short u; } v;
  v.h = (_Float16)x;
  return v.u;
}
__device__ __forceinline__ float h2f(unsigned short u) {
  union { _Float16 h; unsigned short u; } v;
  v.u = u;
  return (float)v.h;
}

// inclusive 16-lane prefix sum via DPP row_shr (VALU only, bit-identical to
// the Hillis-Steele shfl_up version). bound_ctrl=true -> 0-fill at row edge.
#define DPP_ADD_SHR(x, N)                                                       \
  {                                                                             \
    int _t = __builtin_amdgcn_update_dpp(0, __float_as_int(x), 0x110 + (N),     \
                                         0xf, 0xf, true);                       \
    (x) += __int_as_float(_t);                                                  \
  }
__device__ __forceinline__ float scan16_dpp(float x) {
  DPP_ADD_SHR(x, 1);
  DPP_ADD_SHR(x, 2);
  DPP_ADD_SHR(x, 4);
  DPP_ADD_SHR(x, 8);
  return x;
}
// broadcast lane (id|15)'s value to all lanes of each 16-lane row
__device__ __forceinline__ float bcast15(float x) {
  return __int_as_float(__builtin_amdgcn_ds_swizzle(__float_as_int(x), 0x1FF));
}

__device__ __forceinline__ void load_lds16(const void* g, void* l) {
  __builtin_amdgcn_global_load_lds(
      (const __attribute__((address_space(1))) void*)g,
      (__attribute__((address_space(3))) void*)l, 16, 0, 0);
}

// ---------- f32 -> bf16 convert ----------
__global__ __launch_bounds__(256) void cvt_f32_bf16(
    const float* __restrict__ in, unsigned short* __restrict__ out, size_t n8)
{
  size_t idx = (size_t)blockIdx.x * 256 + threadIdx.x;
  size_t stride = (size_t)gridDim.x * 256;
  for (size_t i = idx; i < n8; i += stride) {
    const float4* p = (const float4*)(in + i * 8);
    float4 a = p[0], b = p[1];
    union { unsigned short u[8]; int4 v; } o;
    o.u[0] = f2bf(a.x); o.u[1] = f2bf(a.y); o.u[2] = f2bf(a.z); o.u[3] = f2bf(a.w);
    o.u[4] = f2bf(b.x); o.u[5] = f2bf(b.y); o.u[6] = f2bf(b.z); o.u[7] = f2bf(b.w);
    *(int4*)(out + i * 8) = o.v;
  }
}

// ---------- copy f32 + emit bf16 ----------
__global__ __launch_bounds__(256) void copy_cvt(
    const float* __restrict__ in, float* __restrict__ outf,
    unsigned short* __restrict__ outb, size_t n8)
{
  size_t idx = (size_t)blockIdx.x * 256 + threadIdx.x;
  size_t stride = (size_t)gridDim.x * 256;
  for (size_t i = idx; i < n8; i += stride) {
    const float4* p = (const float4*)(in + i * 8);
    float4 a = p[0], b = p[1];
    ((float4*)(outf + i * 8))[0] = a;
    ((float4*)(outf + i * 8))[1] = b;
    union { unsigned short u[8]; int4 v; } o;
    o.u[0] = f2bf(a.x); o.u[1] = f2bf(a.y); o.u[2] = f2bf(a.z); o.u[3] = f2bf(a.w);
    o.u[4] = f2bf(b.x); o.u[5] = f2bf(b.y); o.u[6] = f2bf(b.z); o.u[7] = f2bf(b.w);
    *(int4*)(outb + i * 8) = o.v;
  }
}

// ---------- bf16 MFMA GEMM: C[M,N] = A[M,K] @ W[N,K]^T + bias ----------
__global__ __launch_bounds__(256) void gemm_bt_bf16(
    const unsigned short* __restrict__ A, const unsigned short* __restrict__ W,
    const float* __restrict__ bias,
    float* __restrict__ Cf, unsigned short* __restrict__ Cb,
    int M, int N, int K, int relu)
{
  __shared__ __align__(16) short As[128 * 32];
  __shared__ __align__(16) short Ws[128 * 32];
  int tid = threadIdx.x;
  int lane = tid & 63, w = tid >> 6;
  int wr = w >> 1, wc = w & 1;
  int bm = blockIdx.y * 128, bn = blockIdx.x * 128;

  f32x4 acc[4][4];
  #pragma unroll
  for (int m = 0; m < 4; ++m)
    #pragma unroll
    for (int n = 0; n < 4; ++n) acc[m][n] = (f32x4){0.f, 0.f, 0.f, 0.f};

  int srow = tid >> 2;
  int skB  = (tid & 3) * 16;
  const char* pa0 = (const char*)(A + (size_t)(bm + srow) * K) + skB;
  const char* pa1 = (const char*)(A + (size_t)(bm + 64 + srow) * K) + skB;
  const char* pw0 = (const char*)(W + (size_t)(bn + srow) * K) + skB;
  const char* pw1 = (const char*)(W + (size_t)(bn + 64 + srow) * K) + skB;
  char* lA0 = (char*)As + w * 1024;
  char* lA1 = (char*)As + 4096 + w * 1024;
  char* lW0 = (char*)Ws + w * 1024;
  char* lW1 = (char*)Ws + 4096 + w * 1024;

  int r = lane & 15, k8 = lane >> 4;
  const bf16x8* Arow = (const bf16x8*)As;
  const bf16x8* Wrow = (const bf16x8*)Ws;

  for (int k0 = 0; k0 < K; k0 += 32) {
    load_lds16(pa0, lA0);
    load_lds16(pa1, lA1);
    load_lds16(pw0, lW0);
    load_lds16(pw1, lW1);
    pa0 += 64; pa1 += 64; pw0 += 64; pw1 += 64;
    __syncthreads();
    bf16x8 aF[4], bF[4];
    #pragma unroll
    for (int m = 0; m < 4; ++m) aF[m] = Arow[(wr * 64 + m * 16 + r) * 4 + k8];
    #pragma unroll
    for (int n = 0; n < 4; ++n) bF[n] = Wrow[(wc * 64 + n * 16 + r) * 4 + k8];
    #pragma unroll
    for (int m = 0; m < 4; ++m)
      #pragma unroll
      for (int n = 0; n < 4; ++n)
        acc[m][n] = __builtin_amdgcn_mfma_f32_16x16x32_bf16(aF[m], bF[n], acc[m][n], 0, 0, 0);
    __syncthreads();
  }

  int orow0 = bm + wr * 64 + (lane >> 4) * 4;
  int ocol0 = bn + wc * 64 + (lane & 15);
  #pragma unroll
  for (int n = 0; n < 4; ++n) {
    int col = ocol0 + n * 16;
    float bv = bias[col];
    #pragma unroll
    for (int m = 0; m < 4; ++m) {
      int row = orow0 + m * 16;
      #pragma unroll
      for (int j = 0; j < 4; ++j) {
        float val = acc[m][n][j] + bv;
        if (relu) val = fmaxf(val, 0.f);
        size_t off = (size_t)(row + j) * N + col;
        if (Cf) Cf[off] = val; else Cb[off] = f2bf(val);
      }
    }
  }
}

// ---------- per-head transpose (bf16): v[b][j][h*64+d] -> vt[b][h][d][j] ----------
__global__ __launch_bounds__(256) void transpose_heads_bf16(
    const unsigned short* __restrict__ v, unsigned short* __restrict__ vt)
{
  __shared__ unsigned short t[64][65];
  int jt = blockIdx.x, h = blockIdx.y, b = blockIdx.z;
  int lane = threadIdx.x & 63, w = threadIdx.x >> 6;
  #pragma unroll
  for (int r = 0; r < 16; ++r) {
    int j = w + r * 4;
    t[j][lane] = v[((size_t)(b * S_ + jt * 64 + j)) * D_ + h * DK_ + lane];
  }
  __syncthreads();
  #pragma unroll
  for (int r = 0; r < 16; ++r) {
    int d = w + r * 4;
    vt[((size_t)((b * H_ + h) * DK_ + d)) * S_ + jt * 64 + lane] = t[lane][d];
  }
}

// ---------- R4/R7-verbatim QK tile: scores scaled + boundary-masked ----------
__device__ __forceinline__ f32x4 qk_tile(
    int kt, int qt, int i0, int g, int c15, int maskType,
    const unsigned short* kbase, bf16x8 aQ0, bf16x8 aQ1)
{
  const unsigned short* kr = kbase + (size_t)(kt * 16 + c15) * D_;
  bf16x8 bK0 = *(const bf16x8*)(kr);
  bf16x8 bK1 = *(const bf16x8*)(kr + 32);
  f32x4 c = (f32x4){0.f, 0.f, 0.f, 0.f};
  c = __builtin_amdgcn_mfma_f32_16x16x32_bf16(aQ0, bK0, c, 0, 0, 0);
  c = __builtin_amdgcn_mfma_f32_16x16x32_bf16(aQ1, bK1, c, 0, 0, 0);
  #pragma unroll
  for (int r = 0; r < 4; ++r) c[r] *= 0.125f;
  if (kt == qt) {
    int j = kt * 16 + c15;
    #pragma unroll
    for (int r = 0; r < 4; ++r) {
      int i = i0 + 4 * g + r;
      bool valid = maskType ? (j <= i) : (j < i);
      if (!valid) c[r] = -1e30f;
    }
  }
  return c;
}

// ---------- MFMA attention: 2 complementary pairs per block (4 waves), DPP scan ----------
__global__ __launch_bounds__(256) void attn_mfma3(
    const unsigned short* __restrict__ qkb,   // q==k bf16 [b][s][D]
    const unsigned short* __restrict__ vtb,   // V^T bf16 [b][h][64][S]
    const float* __restrict__ gammas,
    unsigned short* __restrict__ ao,
    int maskType)
{
  __shared__ __align__(16) unsigned short scr_all[2][33 * 16][16];  // per-pair score cache
  __shared__ __align__(16) unsigned short P_all[4][16][48];
  int tid = threadIdx.x;
  int lane = tid & 63, w = tid >> 6;
  int bid = blockIdx.x;
  int pp = bid & 7;
  int h = (bid >> 3) & (H_ - 1);
  int b = bid >> 6;
  int pairIdx = w >> 1, wp = w & 1;
  int p = pp * 2 + pairIdx;                     // 0..15
  int qt = wp ? (31 - p) : p;                   // complementary pair
  int rowbase = wp ? (p + 1) * 16 : 0;
  unsigned short (*scr)[16] = &scr_all[pairIdx][rowbase];
  unsigned short (*P_lds)[48] = P_all[w];
  int i0 = qt * 16;
  int c15 = lane & 15, g = lane >> 4;

  const unsigned short* qbase =
      qkb + ((size_t)(b * S_ + i0 + c15)) * D_ + h * DK_ + g * 8;
  bf16x8 aQ0 = *(const bf16x8*)(qbase);
  bf16x8 aQ1 = *(const bf16x8*)(qbase + 32);
  const unsigned short* kbase = qkb + ((size_t)b * S_) * D_ + h * DK_ + g * 8;

  float gam = gammas[h];
  float gneg = -((gam > 20.f) ? gam : log1pf(__expf(gam)));   // -softplus < 0

  // ---- phase 1: QK once; f16 scores -> LDS; running m1 ----
  float m1[4] = {-1e30f, -1e30f, -1e30f, -1e30f};
  for (int kt = 0; kt <= qt; ++kt) {
    f32x4 c = qk_tile(kt, qt, i0, g, c15, maskType, kbase, aQ0, aQ1);
    int j = kt * 16 + c15;
    int lo = (int)f2h(c[0]) | ((int)f2h(c[1]) << 16);
    int hi = (int)f2h(c[2]) | ((int)f2h(c[3]) << 16);
    *(int2*)&scr[j][4 * g] = make_int2(lo, hi);
    #pragma unroll
    for (int r = 0; r < 4; ++r) m1[r] = fmaxf(m1[r], c[r]);
  }
  #pragma unroll
  for (int r = 0; r < 4; ++r)
    #pragma unroll
    for (int off = 1; off < 16; off <<= 1)
      m1[r] = fmaxf(m1[r], __shfl_xor(m1[r], off, 64));
  asm volatile("s_waitcnt lgkmcnt(0)" ::: "memory");
  __builtin_amdgcn_sched_barrier(0);

  // ---- phase 2: sum1 from LDS scores (fixed m1) ----
  float sum1[4] = {0.f, 0.f, 0.f, 0.f};
  for (int kt = 0; kt <= qt; ++kt) {
    int j = kt * 16 + c15;
    int2 d = *(const int2*)&scr[j][4 * g];
    float s0 = h2f((unsigned short)(d.x & 0xffff));
    float s1 = h2f((unsigned short)((unsigned)d.x >> 16));
    float s2_ = h2f((unsigned short)(d.y & 0xffff));
    float s3 = h2f((unsigned short)((unsigned)d.y >> 16));
    sum1[0] += __expf(s0 - m1[0]);
    sum1[1] += __expf(s1 - m1[1]);
    sum1[2] += __expf(s2_ - m1[2]);
    sum1[3] += __expf(s3 - m1[3]);
  }
  #pragma unroll
  for (int r = 0; r < 4; ++r)
    #pragma unroll
    for (int off = 1; off < 16; off <<= 1)
      sum1[r] += __shfl_xor(sum1[r], off, 64);
  float inv1[4], m2b[4];
  #pragma unroll
  for (int r = 0; r < 4; ++r) {
    inv1[r] = (sum1[r] > 0.f) ? 1.f / sum1[r] : 0.f;
    m2b[r] = fmaxf(m1[r], 0.f);
  }

  // ---- phase 3: DPP cumsum + decay + rescore + P + fused PV ----
  f32x4 acc[4];
  #pragma unroll
  for (int dt = 0; dt < 4; ++dt) acc[dt] = (f32x4){0.f, 0.f, 0.f, 0.f};
  float sum2[4] = {0.f, 0.f, 0.f, 0.f};
  {
    float carry[4] = {0.f, 0.f, 0.f, 0.f};
    const unsigned short* vbase =
        vtb + (((size_t)(b * H_ + h) * DK_) + c15) * S_ + g * 8;

    #pragma unroll
    for (int jc = 0; jc < 16; ++jc) {
      if (jc * 2 <= qt) {
        #pragma unroll
        for (int t2 = 0; t2 < 2; ++t2) {
          int kt = jc * 2 + t2;
          if (kt <= qt) {
            int j = kt * 16 + c15;
            int2 d = *(const int2*)&scr[j][4 * g];
            float sv[4];
            sv[0] = h2f((unsigned short)(d.x & 0xffff));
            sv[1] = h2f((unsigned short)((unsigned)d.x >> 16));
            sv[2] = h2f((unsigned short)(d.y & 0xffff));
            sv[3] = h2f((unsigned short)((unsigned)d.y >> 16));
            #pragma unroll
            for (int r = 0; r < 4; ++r) {
              float e = __expf(sv[r] - m1[r]);
              float p2 = scan16_dpp(e);           // inclusive scan over c15
              float tot = bcast15(p2);            // row total (lane|15)
              float cum = carry[r] + p2;
              carry[r] += tot;
              float suffix = sum1[r] - cum;
              int i = i0 + 4 * g + r;
              float pos = fabsf((float)(kt * 16 + c15 - i));
              float dist = sqrtf(fmaxf(suffix * inv1[r] * pos, 0.f));
              float te = fminf(fmaxf(__expf(dist * gneg), 1e-5f), 1e5f);
              float s2 = sv[r] * te;
              float e2 = __expf(s2 - m2b[r]);
              sum2[r] += e2;
              P_lds[4 * g + r][t2 * 16 + c15] = f2bf(e2);
            }
          } else {
            #pragma unroll
            for (int r = 0; r < 4; ++r) P_lds[4 * g + r][t2 * 16 + c15] = 0;
          }
        }
        asm volatile("s_waitcnt lgkmcnt(0)" ::: "memory");
        __builtin_amdgcn_sched_barrier(0);
        bf16x8 aP = *(const bf16x8*)&P_lds[c15][g * 8];
        const unsigned short* vr = vbase + (size_t)jc * 32;
        #pragma unroll
        for (int dt = 0; dt < 4; ++dt) {
          bf16x8 bV = *(const bf16x8*)(vr + (size_t)dt * 16 * S_);
          acc[dt] = __builtin_amdgcn_mfma_f32_16x16x32_bf16(aP, bV, acc[dt], 0, 0, 0);
        }
        asm volatile("s_waitcnt lgkmcnt(0)" ::: "memory");
        __builtin_amdgcn_sched_barrier(0);
      }
    }
  }
  #pragma unroll
  for (int r = 0; r < 4; ++r)
    #pragma unroll
    for (int off = 1; off < 16; off <<= 1)
      sum2[r] += __shfl_xor(sum2[r], off, 64);

  // ---- epilogue: normalize (guarded), zeroPad row0, store bf16 ----
  int zp = (maskType == 0 && qt == 0);
  #pragma unroll
  for (int dt = 0; dt < 4; ++dt) {
    #pragma unroll
    for (int r = 0; r < 4; ++r) {
      int i = i0 + 4 * g + r;
      float ns = (sum2[r] > 0.f) ? 1.f / sum2[r] : 0.f;
      float val = acc[dt][r] * ns;
      if (zp && (4 * g + r) == 0) val = 0.f;
      ao[((size_t)(b * S_ + i)) * D_ + h * DK_ + dt * 16 + c15] = f2bf(val);
    }
  }
}

// ---------- wave/block reduce + residual LN (also emits bf16 x) ----------
__device__ __forceinline__ float blockReduceSum256(float v, float* red) {
  #pragma unroll
  for (int off = 32; off > 0; off >>= 1) v += __shfl_down(v, off, 64);
  int lane = threadIdx.x & 63, wid = threadIdx.x >> 6;
  __syncthreads();
  if (lane == 0) red[wid] = v;
  __syncthreads();
  return red[0] + red[1] + red[2] + red[3];
}

__global__ __launch_bounds__(256) void add_ln(
    float* __restrict__ x, unsigned short* __restrict__ xb,
    const float* __restrict__ r,
    const float* __restrict__ g, const float* __restrict__ b)
{
  int row = blockIdx.x;
  int t = threadIdx.x;
  float* xr = x + (size_t)row * D_;
  unsigned short* xbr = xb + (size_t)row * D_;
  const float* rr = r + (size_t)row * D_;
  float v0 = xr[t] + rr[t];
  float v1 = xr[t + 256] + rr[t + 256];
  __shared__ float red[4];
  float s = blockReduceSum256(v0 + v1, red);
  float mu = s * (1.0f / 512.0f);
  float d0 = v0 - mu, d1 = v1 - mu;
  float sq = blockReduceSum256(d0 * d0 + d1 * d1, red);
  float rstd = rsqrtf(sq * (1.0f / 512.0f) + 1e-5f);
  float o0 = d0 * rstd * g[t] + b[t];
  float o1 = d1 * rstd * g[t + 256] + b[t + 256];
  xr[t] = o0;
  xr[t + 256] = o1;
  xbr[t] = f2bf(o0);
  xbr[t + 256] = f2bf(o1);
}

static inline void cvt(const float* in, unsigned short* out, size_t n, hipStream_t s) {
  size_t n8 = n / 8;
  int blocks = (int)((n8 + 255) / 256);
  if (blocks > 2048) blocks = 2048;
  cvt_f32_bf16<<<blocks, 256, 0, s>>>(in, out, n8);
}

extern "C" void kernel_launch(void* const* d_in, const int* in_sizes, int n_in,
                              void* d_out, int out_size, void* d_ws, size_t ws_size,
                              hipStream_t stream) {
  const float* q_embed  = (const float*)d_in[0];
  const float* qa_embed = (const float*)d_in[1];
  const float* Wk = (const float*)d_in[2];
  const float* bk = (const float*)d_in[3];
  const float* Wv = (const float*)d_in[4];
  const float* bv = (const float*)d_in[5];
  const float* Wo = (const float*)d_in[6];
  const float* bo = (const float*)d_in[7];
  const float* gammas = (const float*)d_in[8];
  const float* ln1_g = (const float*)d_in[9];
  const float* ln1_b = (const float*)d_in[10];
  const float* W1 = (const float*)d_in[11];
  const float* b1 = (const float*)d_in[12];
  const float* W2 = (const float*)d_in[13];
  const float* b2 = (const float*)d_in[14];
  const float* ln2_g = (const float*)d_in[15];
  const float* ln2_b = (const float*)d_in[16];

  float* x = (float*)d_out;
  const size_t NTOK = (size_t)B_ * S_;      // 16384
  const size_t ND = NTOK * D_;

  float* qkf = (float*)d_ws;                               // f32 scratch [ND]
  unsigned short* xb    = (unsigned short*)(qkf + ND);     // bf16 [ND]
  unsigned short* valsb = xb + ND;
  unsigned short* qkb   = valsb + ND;
  unsigned short* vb    = qkb + ND;
  unsigned short* vtb   = vb + ND;
  unsigned short* aob   = vtb + ND;
  unsigned short* wkb   = aob + ND;
  unsigned short* wvb   = wkb + (size_t)L_ * D_ * D_;
  unsigned short* wob   = wvb + (size_t)L_ * D_ * D_;
  unsigned short* w1b   = wob + (size_t)L_ * D_ * D_;
  unsigned short* w2b   = w1b + (size_t)L_ * DFF_ * D_;
  unsigned short* ffnb  = qkb;   // [NTOK*DFF] aliases qkb+vb+vtb+aob (dead in FFN phase)

  // x (f32) + xb (bf16) from q_embed in one pass
  {
    size_t n8 = ND / 8;
    copy_cvt<<<2048, 256, 0, stream>>>(q_embed, x, xb, n8);
  }

  cvt(Wk, wkb, (size_t)L_ * D_ * D_, stream);
  cvt(Wv, wvb, (size_t)L_ * D_ * D_, stream);
  cvt(Wo, wob, (size_t)L_ * D_ * D_, stream);
  cvt(W1, w1b, (size_t)L_ * DFF_ * D_, stream);
  cvt(W2, w2b, (size_t)L_ * DFF_ * D_, stream);
  cvt(qa_embed, valsb, ND, stream);

  dim3 gproj(D_ / 128, NTOK / 128);
  dim3 gf1(DFF_ / 128, NTOK / 128);
  dim3 gf2(D_ / 128, NTOK / 128);
  dim3 gtr(S_ / 64, H_, B_);
  int gattn = B_ * H_ * 8;   // 2048 blocks, 2 complementary pairs (4 waves) each

  for (int l = 0; l < L_; ++l) {
    int first = (l % 2 == 0);
    const unsigned short* vA = first ? valsb : xb;

    gemm_bt_bf16<<<gproj, 256, 0, stream>>>(xb, wkb + (size_t)l * D_ * D_, bk + l * D_,
                                            nullptr, qkb, (int)NTOK, D_, D_, 0);
    gemm_bt_bf16<<<gproj, 256, 0, stream>>>(vA, wvb + (size_t)l * D_ * D_, bv + l * D_,
                                            nullptr, vb, (int)NTOK, D_, D_, 0);
    transpose_heads_bf16<<<gtr, 256, 0, stream>>>(vb, vtb);
    attn_mfma3<<<gattn, 256, 0, stream>>>(qkb, vtb, gammas + l * H_, aob, first ? 0 : 1);
    gemm_bt_bf16<<<gproj, 256, 0, stream>>>(aob, wob + (size_t)l * D_ * D_, bo + l * D_,
                                            qkf, nullptr, (int)NTOK, D_, D_, 0);
    add_ln<<<(int)NTOK, 256, 0, stream>>>(x, xb, qkf, ln1_g + l * D_, ln1_b + l * D_);
    if (first) {
      gemm_bt_bf16<<<gf1, 256, 0, stream>>>(xb, w1b + (size_t)l * DFF_ * D_, b1 + l * DFF_,
                                            nullptr, ffnb, (int)NTOK, DFF_, D_, 1);
      gemm_bt_bf16<<<gf2, 256, 0, stream>>>(ffnb, w2b + (size_t)l * D_ * DFF_, b2 + l * D_,
                                            qkf, nullptr, (int)NTOK, D_, DFF_, 0);
      add_ln<<<(int)NTOK, 256, 0, stream>>>(x, xb, qkf, ln2_g + l * D_, ln2_b + l * D_);
    }
  }
}

// Round 13
// 1147.125 us; speedup vs baseline: 11.5814x; 1.0318x over previous
//
#include <hip/hip_runtime.h>
#include <hip/hip_bf16.h>
#include <math.h>

#define B_ 32
#define S_ 512
#define D_ 512
#define H_ 8
#define DK_ 64
#define DFF_ 2048
#define L_ 4

typedef __attribute__((ext_vector_type(8))) short bf16x8;
typedef __attribute__((ext_vector_type(4))) float f32x4;

__device__ __forceinline__ unsigned short f2bf(float x) {
  union { float f; unsigned u; } v; v.f = x;
  unsigned r = v.u + 0x7fff + ((v.u >> 16) & 1);   // round-nearest-even
  return (unsigned short)(r >> 16);
}

__device__ __forceinline__ unsigned short f2h(float x) {
  union { _Float16 h; unsigned short u; } v;
  v.h = (_Float16)x;
  return v.u;
}
__device__ __forceinline__ float h2f(unsigned short u) {
  union { _Float16 h; unsigned short u; } v;
  v.u = u;
  return (float)v.h;
}

// inclusive 16-lane prefix sum via DPP row_shr (VALU only). bound_ctrl -> 0-fill.
#define DPP_ADD_SHR(x, N)                                                       \
  {                                                                             \
    int _t = __builtin_amdgcn_update_dpp(0, __float_as_int(x), 0x110 + (N),     \
                                         0xf, 0xf, true);                       \
    (x) += __int_as_float(_t);                                                  \
  }
__device__ __forceinline__ float scan16_dpp(float x) {
  DPP_ADD_SHR(x, 1);
  DPP_ADD_SHR(x, 2);
  DPP_ADD_SHR(x, 4);
  DPP_ADD_SHR(x, 8);
  return x;
}
// broadcast lane (id|15)'s value to all lanes of each 16-lane row
__device__ __forceinline__ float bcast15(float x) {
  return __int_as_float(__builtin_amdgcn_ds_swizzle(__float_as_int(x), 0x1FF));
}

__device__ __forceinline__ void load_lds16(const void* g, void* l) {
  __builtin_amdgcn_global_load_lds(
      (const __attribute__((address_space(1))) void*)g,
      (__attribute__((address_space(3))) void*)l, 16, 0, 0);
}

// ---------- f32 -> bf16 convert ----------
__global__ __launch_bounds__(256) void cvt_f32_bf16(
    const float* __restrict__ in, unsigned short* __restrict__ out, size_t n8)
{
  size_t idx = (size_t)blockIdx.x * 256 + threadIdx.x;
  size_t stride = (size_t)gridDim.x * 256;
  for (size_t i = idx; i < n8; i += stride) {
    const float4* p = (const float4*)(in + i * 8);
    float4 a = p[0], b = p[1];
    union { unsigned short u[8]; int4 v; } o;
    o.u[0] = f2bf(a.x); o.u[1] = f2bf(a.y); o.u[2] = f2bf(a.z); o.u[3] = f2bf(a.w);
    o.u[4] = f2bf(b.x); o.u[5] = f2bf(b.y); o.u[6] = f2bf(b.z); o.u[7] = f2bf(b.w);
    *(int4*)(out + i * 8) = o.v;
  }
}

// ---------- copy f32 + emit bf16 ----------
__global__ __launch_bounds__(256) void copy_cvt(
    const float* __restrict__ in, float* __restrict__ outf,
    unsigned short* __restrict__ outb, size_t n8)
{
  size_t idx = (size_t)blockIdx.x * 256 + threadIdx.x;
  size_t stride = (size_t)gridDim.x * 256;
  for (size_t i = idx; i < n8; i += stride) {
    const float4* p = (const float4*)(in + i * 8);
    float4 a = p[0], b = p[1];
    ((float4*)(outf + i * 8))[0] = a;
    ((float4*)(outf + i * 8))[1] = b;
    union { unsigned short u[8]; int4 v; } o;
    o.u[0] = f2bf(a.x); o.u[1] = f2bf(a.y); o.u[2] = f2bf(a.z); o.u[3] = f2bf(a.w);
    o.u[4] = f2bf(b.x); o.u[5] = f2bf(b.y); o.u[6] = f2bf(b.z); o.u[7] = f2bf(b.w);
    *(int4*)(outb + i * 8) = o.v;
  }
}

// ---------- bf16 MFMA GEMM: C[M,N] = A[M,K] @ W[N,K]^T + bias ----------
__global__ __launch_bounds__(256) void gemm_bt_bf16(
    const unsigned short* __restrict__ A, const unsigned short* __restrict__ W,
    const float* __restrict__ bias,
    float* __restrict__ Cf, unsigned short* __restrict__ Cb,
    int M, int N, int K, int relu)
{
  __shared__ __align__(16) short As[128 * 32];
  __shared__ __align__(16) short Ws[128 * 32];
  int tid = threadIdx.x;
  int lane = tid & 63, w = tid >> 6;
  int wr = w >> 1, wc = w & 1;
  int bm = blockIdx.y * 128, bn = blockIdx.x * 128;

  f32x4 acc[4][4];
  #pragma unroll
  for (int m = 0; m < 4; ++m)
    #pragma unroll
    for (int n = 0; n < 4; ++n) acc[m][n] = (f32x4){0.f, 0.f, 0.f, 0.f};

  int srow = tid >> 2;
  int skB  = (tid & 3) * 16;
  const char* pa0 = (const char*)(A + (size_t)(bm + srow) * K) + skB;
  const char* pa1 = (const char*)(A + (size_t)(bm + 64 + srow) * K) + skB;
  const char* pw0 = (const char*)(W + (size_t)(bn + srow) * K) + skB;
  const char* pw1 = (const char*)(W + (size_t)(bn + 64 + srow) * K) + skB;
  char* lA0 = (char*)As + w * 1024;
  char* lA1 = (char*)As + 4096 + w * 1024;
  char* lW0 = (char*)Ws + w * 1024;
  char* lW1 = (char*)Ws + 4096 + w * 1024;

  int r = lane & 15, k8 = lane >> 4;
  const bf16x8* Arow = (const bf16x8*)As;
  const bf16x8* Wrow = (const bf16x8*)Ws;

  for (int k0 = 0; k0 < K; k0 += 32) {
    load_lds16(pa0, lA0);
    load_lds16(pa1, lA1);
    load_lds16(pw0, lW0);
    load_lds16(pw1, lW1);
    pa0 += 64; pa1 += 64; pw0 += 64; pw1 += 64;
    __syncthreads();
    bf16x8 aF[4], bF[4];
    #pragma unroll
    for (int m = 0; m < 4; ++m) aF[m] = Arow[(wr * 64 + m * 16 + r) * 4 + k8];
    #pragma unroll
    for (int n = 0; n < 4; ++n) bF[n] = Wrow[(wc * 64 + n * 16 + r) * 4 + k8];
    #pragma unroll
    for (int m = 0; m < 4; ++m)
      #pragma unroll
      for (int n = 0; n < 4; ++n)
        acc[m][n] = __builtin_amdgcn_mfma_f32_16x16x32_bf16(aF[m], bF[n], acc[m][n], 0, 0, 0);
    __syncthreads();
  }

  int orow0 = bm + wr * 64 + (lane >> 4) * 4;
  int ocol0 = bn + wc * 64 + (lane & 15);
  #pragma unroll
  for (int n = 0; n < 4; ++n) {
    int col = ocol0 + n * 16;
    float bv = bias[col];
    #pragma unroll
    for (int m = 0; m < 4; ++m) {
      int row = orow0 + m * 16;
      #pragma unroll
      for (int j = 0; j < 4; ++j) {
        float val = acc[m][n][j] + bv;
        if (relu) val = fmaxf(val, 0.f);
        size_t off = (size_t)(row + j) * N + col;
        if (Cf) Cf[off] = val; else Cb[off] = f2bf(val);
      }
    }
  }
}

// ---------- per-head transpose (bf16): v[b][j][h*64+d] -> vt[b][h][d][j] ----------
__global__ __launch_bounds__(256) void transpose_heads_bf16(
    const unsigned short* __restrict__ v, unsigned short* __restrict__ vt)
{
  __shared__ unsigned short t[64][65];
  int jt = blockIdx.x, h = blockIdx.y, b = blockIdx.z;
  int lane = threadIdx.x & 63, w = threadIdx.x >> 6;
  #pragma unroll
  for (int r = 0; r < 16; ++r) {
    int j = w + r * 4;
    t[j][lane] = v[((size_t)(b * S_ + jt * 64 + j)) * D_ + h * DK_ + lane];
  }
  __syncthreads();
  #pragma unroll
  for (int r = 0; r < 16; ++r) {
    int d = w + r * 4;
    vt[((size_t)((b * H_ + h) * DK_ + d)) * S_ + jt * 64 + lane] = t[lane][d];
  }
}

// ---------- R4/R7-verbatim QK tile: scores scaled + boundary-masked ----------
__device__ __forceinline__ f32x4 qk_tile(
    int kt, int qt, int i0, int g, int c15, int maskType,
    const unsigned short* kbase, bf16x8 aQ0, bf16x8 aQ1)
{
  const unsigned short* kr = kbase + (size_t)(kt * 16 + c15) * D_;
  bf16x8 bK0 = *(const bf16x8*)(kr);
  bf16x8 bK1 = *(const bf16x8*)(kr + 32);
  f32x4 c = (f32x4){0.f, 0.f, 0.f, 0.f};
  c = __builtin_amdgcn_mfma_f32_16x16x32_bf16(aQ0, bK0, c, 0, 0, 0);
  c = __builtin_amdgcn_mfma_f32_16x16x32_bf16(aQ1, bK1, c, 0, 0, 0);
  #pragma unroll
  for (int r = 0; r < 4; ++r) c[r] *= 0.125f;
  if (kt == qt) {
    int j = kt * 16 + c15;
    #pragma unroll
    for (int r = 0; r < 4; ++r) {
      int i = i0 + 4 * g + r;
      bool valid = maskType ? (j <= i) : (j < i);
      if (!valid) c[r] = -1e30f;
    }
  }
  return c;
}

// ---------- MFMA attention: complementary pairs, DPP scan, swizzled caches ----------
#define PSTRIDE 40
__global__ __launch_bounds__(256) void attn_mfma3(
    const unsigned short* __restrict__ qkb,   // q==k bf16 [b][s][D]
    const unsigned short* __restrict__ vtb,   // V^T bf16 [b][h][64][S]
    const float* __restrict__ gammas,
    unsigned short* __restrict__ ao,
    int maskType)
{
  __shared__ __align__(16) unsigned short scr_all[2][33 * 16][16];  // per-pair score cache
  __shared__ __align__(16) unsigned short P_all[4][16][PSTRIDE];
  int tid = threadIdx.x;
  int lane = tid & 63, w = tid >> 6;
  int bid = blockIdx.x;
  int pp = bid & 7;
  int h = (bid >> 3) & (H_ - 1);
  int b = bid >> 6;
  int pairIdx = w >> 1, wp = w & 1;
  int p = pp * 2 + pairIdx;                     // 0..15
  int qt = wp ? (31 - p) : p;                   // complementary pair
  int rowbase = wp ? (p + 1) * 16 : 0;
  unsigned short (*scr)[16] = &scr_all[pairIdx][rowbase];
  unsigned short (*P_lds)[PSTRIDE] = P_all[w];
  int i0 = qt * 16;
  int c15 = lane & 15, g = lane >> 4;
  int scol = 4 * ((g + (c15 >> 2)) & 3);        // bank-swizzled scr column

  const unsigned short* qbase =
      qkb + ((size_t)(b * S_ + i0 + c15)) * D_ + h * DK_ + g * 8;
  bf16x8 aQ0 = *(const bf16x8*)(qbase);
  bf16x8 aQ1 = *(const bf16x8*)(qbase + 32);
  const unsigned short* kbase = qkb + ((size_t)b * S_) * D_ + h * DK_ + g * 8;

  float gam = gammas[h];
  float gneg = -((gam > 20.f) ? gam : log1pf(__expf(gam)));   // -softplus < 0

  // ---- phase 1: QK once; f16 scores -> LDS (swizzled); running m1 ----
  float m1[4] = {-1e30f, -1e30f, -1e30f, -1e30f};
  for (int kt = 0; kt <= qt; ++kt) {
    f32x4 c = qk_tile(kt, qt, i0, g, c15, maskType, kbase, aQ0, aQ1);
    int j = kt * 16 + c15;
    int lo = (int)f2h(c[0]) | ((int)f2h(c[1]) << 16);
    int hi = (int)f2h(c[2]) | ((int)f2h(c[3]) << 16);
    *(int2*)&scr[j][scol] = make_int2(lo, hi);
    #pragma unroll
    for (int r = 0; r < 4; ++r) m1[r] = fmaxf(m1[r], c[r]);
  }
  #pragma unroll
  for (int r = 0; r < 4; ++r)
    #pragma unroll
    for (int off = 1; off < 16; off <<= 1)
      m1[r] = fmaxf(m1[r], __shfl_xor(m1[r], off, 64));
  asm volatile("s_waitcnt lgkmcnt(0)" ::: "memory");
  __builtin_amdgcn_sched_barrier(0);

  // ---- phase 2: sum1 from LDS scores (fixed m1) ----
  float sum1[4] = {0.f, 0.f, 0.f, 0.f};
  for (int kt = 0; kt <= qt; ++kt) {
    int j = kt * 16 + c15;
    int2 d = *(const int2*)&scr[j][scol];
    float s0 = h2f((unsigned short)(d.x & 0xffff));
    float s1 = h2f((unsigned short)((unsigned)d.x >> 16));
    float s2_ = h2f((unsigned short)(d.y & 0xffff));
    float s3 = h2f((unsigned short)((unsigned)d.y >> 16));
    sum1[0] += __expf(s0 - m1[0]);
    sum1[1] += __expf(s1 - m1[1]);
    sum1[2] += __expf(s2_ - m1[2]);
    sum1[3] += __expf(s3 - m1[3]);
  }
  #pragma unroll
  for (int r = 0; r < 4; ++r)
    #pragma unroll
    for (int off = 1; off < 16; off <<= 1)
      sum1[r] += __shfl_xor(sum1[r], off, 64);
  float inv1[4], m2b[4];
  #pragma unroll
  for (int r = 0; r < 4; ++r) {
    inv1[r] = (sum1[r] > 0.f) ? 1.f / sum1[r] : 0.f;
    m2b[r] = fmaxf(m1[r], 0.f);
  }

  // ---- phase 3: DPP cumsum + decay + rescore + P + fused PV ----
  f32x4 acc[4];
  #pragma unroll
  for (int dt = 0; dt < 4; ++dt) acc[dt] = (f32x4){0.f, 0.f, 0.f, 0.f};
  float sum2[4] = {0.f, 0.f, 0.f, 0.f};
  {
    float carry[4] = {0.f, 0.f, 0.f, 0.f};
    const unsigned short* vbase =
        vtb + (((size_t)(b * H_ + h) * DK_) + c15) * S_ + g * 8;

    #pragma unroll
    for (int jc = 0; jc < 16; ++jc) {
      if (jc * 2 <= qt) {
        #pragma unroll
        for (int t2 = 0; t2 < 2; ++t2) {
          int kt = jc * 2 + t2;
          if (kt <= qt) {
            int j = kt * 16 + c15;
            int2 d = *(const int2*)&scr[j][scol];
            float sv[4];
            sv[0] = h2f((unsigned short)(d.x & 0xffff));
            sv[1] = h2f((unsigned short)((unsigned)d.x >> 16));
            sv[2] = h2f((unsigned short)(d.y & 0xffff));
            sv[3] = h2f((unsigned short)((unsigned)d.y >> 16));
            #pragma unroll
            for (int r = 0; r < 4; ++r) {
              float e = __expf(sv[r] - m1[r]);
              float p2 = scan16_dpp(e);           // inclusive scan over c15
              float tot = bcast15(p2);            // row total (lane|15)
              float cum = carry[r] + p2;
              carry[r] += tot;
              float suffix = sum1[r] - cum;
              int i = i0 + 4 * g + r;
              float pos = fabsf((float)(kt * 16 + c15 - i));
              float dist = sqrtf(fmaxf(suffix * inv1[r] * pos, 0.f));
              float te = fminf(fmaxf(__expf(dist * gneg), 1e-5f), 1e5f);
              float s2 = sv[r] * te;
              float e2 = __expf(s2 - m2b[r]);
              sum2[r] += e2;
              P_lds[4 * g + r][t2 * 16 + c15] = f2bf(e2);
            }
          } else {
            #pragma unroll
            for (int r = 0; r < 4; ++r) P_lds[4 * g + r][t2 * 16 + c15] = 0;
          }
        }
        asm volatile("s_waitcnt lgkmcnt(0)" ::: "memory");
        __builtin_amdgcn_sched_barrier(0);
        bf16x8 aP = *(const bf16x8*)&P_lds[c15][g * 8];
        const unsigned short* vr = vbase + (size_t)jc * 32;
        #pragma unroll
        for (int dt = 0; dt < 4; ++dt) {
          bf16x8 bV = *(const bf16x8*)(vr + (size_t)dt * 16 * S_);
          acc[dt] = __builtin_amdgcn_mfma_f32_16x16x32_bf16(aP, bV, acc[dt], 0, 0, 0);
        }
        // post-MFMA fence removed: aP ds_read->MFMA dependency is compiler-
        // tracked; LDS ops within a wave are in-order; may-alias store/load
        // ordering keeps next-iter P writes after this aP read.
      }
    }
  }
  #pragma unroll
  for (int r = 0; r < 4; ++r)
    #pragma unroll
    for (int off = 1; off < 16; off <<= 1)
      sum2[r] += __shfl_xor(sum2[r], off, 64);

  // ---- epilogue: normalize (guarded), zeroPad row0, store bf16 ----
  int zp = (maskType == 0 && qt == 0);
  #pragma unroll
  for (int dt = 0; dt < 4; ++dt) {
    #pragma unroll
    for (int r = 0; r < 4; ++r) {
      int i = i0 + 4 * g + r;
      float ns = (sum2[r] > 0.f) ? 1.f / sum2[r] : 0.f;
      float val = acc[dt][r] * ns;
      if (zp && (4 * g + r) == 0) val = 0.f;
      ao[((size_t)(b * S_ + i)) * D_ + h * DK_ + dt * 16 + c15] = f2bf(val);
    }
  }
}

// ---------- wave/block reduce + residual LN (also emits bf16 x) ----------
__device__ __forceinline__ float blockReduceSum256(float v, float* red) {
  #pragma unroll
  for (int off = 32; off > 0; off >>= 1) v += __shfl_down(v, off, 64);
  int lane = threadIdx.x & 63, wid = threadIdx.x >> 6;
  __syncthreads();
  if (lane == 0) red[wid] = v;
  __syncthreads();
  return red[0] + red[1] + red[2] + red[3];
}

__global__ __launch_bounds__(256) void add_ln(
    float* __restrict__ x, unsigned short* __restrict__ xb,
    const float* __restrict__ r,
    const float* __restrict__ g, const float* __restrict__ b)
{
  int row = blockIdx.x;
  int t = threadIdx.x;
  float* xr = x + (size_t)row * D_;
  unsigned short* xbr = xb + (size_t)row * D_;
  const float* rr = r + (size_t)row * D_;
  float v0 = xr[t] + rr[t];
  float v1 = xr[t + 256] + rr[t + 256];
  __shared__ float red[4];
  float s = blockReduceSum256(v0 + v1, red);
  float mu = s * (1.0f / 512.0f);
  float d0 = v0 - mu, d1 = v1 - mu;
  float sq = blockReduceSum256(d0 * d0 + d1 * d1, red);
  float rstd = rsqrtf(sq * (1.0f / 512.0f) + 1e-5f);
  float o0 = d0 * rstd * g[t] + b[t];
  float o1 = d1 * rstd * g[t + 256] + b[t + 256];
  xr[t] = o0;
  xr[t + 256] = o1;
  xbr[t] = f2bf(o0);
  xbr[t + 256] = f2bf(o1);
}

static inline void cvt(const float* in, unsigned short* out, size_t n, hipStream_t s) {
  size_t n8 = n / 8;
  int blocks = (int)((n8 + 255) / 256);
  if (blocks > 2048) blocks = 2048;
  cvt_f32_bf16<<<blocks, 256, 0, s>>>(in, out, n8);
}

extern "C" void kernel_launch(void* const* d_in, const int* in_sizes, int n_in,
                              void* d_out, int out_size, void* d_ws, size_t ws_size,
                              hipStream_t stream) {
  const float* q_embed  = (const float*)d_in[0];
  const float* qa_embed = (const float*)d_in[1];
  const float* Wk = (const float*)d_in[2];
  const float* bk = (const float*)d_in[3];
  const float* Wv = (const float*)d_in[4];
  const float* bv = (const float*)d_in[5];
  const float* Wo = (const float*)d_in[6];
  const float* bo = (const float*)d_in[7];
  const float* gammas = (const float*)d_in[8];
  const float* ln1_g = (const float*)d_in[9];
  const float* ln1_b = (const float*)d_in[10];
  const float* W1 = (const float*)d_in[11];
  const float* b1 = (const float*)d_in[12];
  const float* W2 = (const float*)d_in[13];
  const float* b2 = (const float*)d_in[14];
  const float* ln2_g = (const float*)d_in[15];
  const float* ln2_b = (const float*)d_in[16];

  float* x = (float*)d_out;
  const size_t NTOK = (size_t)B_ * S_;      // 16384
  const size_t ND = NTOK * D_;

  float* qkf = (float*)d_ws;                               // f32 scratch [ND]
  unsigned short* xb    = (unsigned short*)(qkf + ND);     // bf16 [ND]
  unsigned short* valsb = xb + ND;
  unsigned short* qkb   = valsb + ND;
  unsigned short* vb    = qkb + ND;
  unsigned short* vtb   = vb + ND;
  unsigned short* aob   = vtb + ND;
  unsigned short* wkb   = aob + ND;
  unsigned short* wvb   = wkb + (size_t)L_ * D_ * D_;
  unsigned short* wob   = wvb + (size_t)L_ * D_ * D_;
  unsigned short* w1b   = wob + (size_t)L_ * D_ * D_;
  unsigned short* w2b   = w1b + (size_t)L_ * DFF_ * D_;
  unsigned short* ffnb  = qkb;   // [NTOK*DFF] aliases qkb+vb+vtb+aob (dead in FFN phase)

  // x (f32) + xb (bf16) from q_embed in one pass
  {
    size_t n8 = ND / 8;
    copy_cvt<<<2048, 256, 0, stream>>>(q_embed, x, xb, n8);
  }

  cvt(Wk, wkb, (size_t)L_ * D_ * D_, stream);
  cvt(Wv, wvb, (size_t)L_ * D_ * D_, stream);
  cvt(Wo, wob, (size_t)L_ * D_ * D_, stream);
  cvt(W1, w1b, (size_t)L_ * DFF_ * D_, stream);
  cvt(W2, w2b, (size_t)L_ * DFF_ * D_, stream);
  cvt(qa_embed, valsb, ND, stream);

  dim3 gproj(D_ / 128, NTOK / 128);
  dim3 gf1(DFF_ / 128, NTOK / 128);
  dim3 gf2(D_ / 128, NTOK / 128);
  dim3 gtr(S_ / 64, H_, B_);
  int gattn = B_ * H_ * 8;   // 2048 blocks, 2 complementary pairs (4 waves) each

  for (int l = 0; l < L_; ++l) {
    int first = (l % 2 == 0);
    const unsigned short* vA = first ? valsb : xb;

    gemm_bt_bf16<<<gproj, 256, 0, stream>>>(xb, wkb + (size_t)l * D_ * D_, bk + l * D_,
                                            nullptr, qkb, (int)NTOK, D_, D_, 0);
    gemm_bt_bf16<<<gproj, 256, 0, stream>>>(vA, wvb + (size_t)l * D_ * D_, bv + l * D_,
                                            nullptr, vb, (int)NTOK, D_, D_, 0);
    transpose_heads_bf16<<<gtr, 256, 0, stream>>>(vb, vtb);
    attn_mfma3<<<gattn, 256, 0, stream>>>(qkb, vtb, gammas + l * H_, aob, first ? 0 : 1);
    gemm_bt_bf16<<<gproj, 256, 0, stream>>>(aob, wob + (size_t)l * D_ * D_, bo + l * D_,
                                            qkf, nullptr, (int)NTOK, D_, D_, 0);
    add_ln<<<(int)NTOK, 256, 0, stream>>>(x, xb, qkf, ln1_g + l * D_, ln1_b + l * D_);
    if (first) {
      gemm_bt_bf16<<<gf1, 256, 0, stream>>>(xb, w1b + (size_t)l * DFF_ * D_, b1 + l * DFF_,
                                            nullptr, ffnb, (int)NTOK, DFF_, D_, 1);
      gemm_bt_bf16<<<gf2, 256, 0, stream>>>(ffnb, w2b + (size_t)l * D_ * DFF_, b2 + l * D_,
                                            qkf, nullptr, (int)NTOK, D_, DFF_, 0);
      add_ln<<<(int)NTOK, 256, 0, stream>>>(x, xb, qkf, ln2_g + l * D_, ln2_b + l * D_);
    }
  }
}